// Round 1
// baseline (11757.908 us; speedup 1.0000x reference)
//
#include <hip/hip_runtime.h>
#include <math.h>

// ---- problem constants ----
constexpr int BATCH  = 2;
constexpr int SEQ    = 1024;
constexpr int DIM    = 768;
constexpr int NLAYER = 4;
constexpr int NHEAD  = 12;
constexpr int HDIM   = 64;
constexpr int NEXP   = 4;
constexpr int FFDIM  = 3072;
constexpr int VOCAB  = 50257;
constexpr int NDIM   = NEXP * DIM;   // 3072
constexpr int NC     = NEXP*NEXP + 2*NEXP; // 24
constexpr int NTOK   = BATCH * SEQ;  // 2048

// ---- workspace layout (floats) ----
constexpr size_t SZ_X  = (size_t)NTOK * NEXP * DIM;  // 6291456
constexpr size_t SZ_T  = (size_t)NTOK * DIM;         // 1572864
constexpr size_t O_X   = 0;
constexpr size_t O_X2  = O_X  + SZ_X;
constexpr size_t O_H   = O_X2 + SZ_X;
constexpr size_t O_LN  = O_H  + SZ_T;
constexpr size_t O_BIG = O_LN + SZ_T;                 // NTOK*FFDIM (covers qkv 2304 & ff 3072)
constexpr size_t O_T1  = O_BIG + (size_t)NTOK*FFDIM;
constexpr size_t O_Y   = O_T1 + SZ_T;
constexpr size_t O_CF  = O_Y  + SZ_T;                 // NTOK*NC

// ============================ embed ============================
__global__ void k_embed(const int* __restrict__ ids, const float* __restrict__ tok,
                        const float* __restrict__ pos, float* __restrict__ x4) {
  int idx = blockIdx.x*blockDim.x + threadIdx.x;
  if (idx >= NTOK*DIM) return;
  int t = idx / DIM, d = idx - t*DIM;
  int s = t % SEQ;
  float v = tok[(size_t)ids[t]*DIM + d] + pos[(size_t)s*DIM + d];
#pragma unroll
  for (int n=0;n<NEXP;n++) x4[((size_t)t*NEXP+n)*DIM + d] = v;
}

// ============================ mhc coef (RMS + logits + sinkhorn) ============================
__global__ __launch_bounds__(256) void k_coef(const float* __restrict__ x4,
                                              const float* __restrict__ W,
                                              const float* __restrict__ bb,
                                              const float* __restrict__ alpha_p,
                                              float* __restrict__ coef) {
  int t = blockIdx.x;
  int tid = threadIdx.x;
  const float* xt = x4 + (size_t)t*NDIM;
  __shared__ float red[256];
  float ss = 0.f;
  for (int i=tid;i<NDIM;i+=256){ float v=xt[i]; ss += v*v; }
  red[tid]=ss; __syncthreads();
  for (int st=128; st>0; st>>=1){ if (tid<st) red[tid]+=red[tid+st]; __syncthreads(); }
  float rfac = rsqrtf(red[0]/(float)NDIM + 1e-6f);

  float acc[NC];
#pragma unroll
  for (int j=0;j<NC;j++) acc[j]=0.f;
  for (int i=tid;i<NDIM;i+=256){
    float v = xt[i];
    const float* wr = W + (size_t)i*NC;
#pragma unroll
    for (int j=0;j<NC;j++) acc[j] += v*wr[j];
  }
  __shared__ float accs[256][NC+1];
#pragma unroll
  for (int j=0;j<NC;j++) accs[tid][j]=acc[j];
  __syncthreads();
  for (int st=128; st>0; st>>=1){
    if (tid<st){
      for (int j=0;j<NC;j++) accs[tid][j]+=accs[tid+st][j];
    }
    __syncthreads();
  }
  if (tid==0){
    float alpha = alpha_p[0];
    float lg[NC];
    for (int j=0;j<NC;j++) lg[j] = accs[0][j]*rfac*alpha + bb[j];
    // sinkhorn on lg[0:16] (4x4, row-major [n][m])
    float lm[16];
    for (int j=0;j<16;j++) lm[j]=lg[j];
    for (int it=0; it<10; ++it){
      for (int n=0;n<4;n++){
        float m0 = fmaxf(fmaxf(lm[n*4],lm[n*4+1]),fmaxf(lm[n*4+2],lm[n*4+3]));
        float se = expf(lm[n*4]-m0)+expf(lm[n*4+1]-m0)+expf(lm[n*4+2]-m0)+expf(lm[n*4+3]-m0);
        float l  = m0 + logf(se);
        for (int m=0;m<4;m++) lm[n*4+m]-=l;
      }
      for (int m=0;m<4;m++){
        float m0 = fmaxf(fmaxf(lm[m],lm[4+m]),fmaxf(lm[8+m],lm[12+m]));
        float se = expf(lm[m]-m0)+expf(lm[4+m]-m0)+expf(lm[8+m]-m0)+expf(lm[12+m]-m0);
        float l  = m0 + logf(se);
        for (int n=0;n<4;n++) lm[n*4+m]-=l;
      }
    }
    float* cf = coef + (size_t)t*NC;
    for (int j=0;j<16;j++) cf[j]=expf(lm[j]);
    float pm = fmaxf(fmaxf(lg[16],lg[17]),fmaxf(lg[18],lg[19]));
    float e0=expf(lg[16]-pm), e1=expf(lg[17]-pm), e2=expf(lg[18]-pm), e3=expf(lg[19]-pm);
    float es=e0+e1+e2+e3;
    cf[16]=e0/es; cf[17]=e1/es; cf[18]=e2/es; cf[19]=e3/es;
    for (int j=20;j<24;j++) cf[j]=1.f/(1.f+expf(-lg[j]));
  }
}

// ============================ h = sum_n pre[n]*x[n] ============================
__global__ void k_hmix(const float* __restrict__ x4, const float* __restrict__ coef,
                       float* __restrict__ h){
  int idx = blockIdx.x*blockDim.x + threadIdx.x;
  if (idx >= NTOK*DIM) return;
  int t = idx / DIM, d = idx - t*DIM;
  const float* cf = coef + (size_t)t*NC + 16;
  const float* xt = x4 + (size_t)t*NEXP*DIM + d;
  h[idx] = cf[0]*xt[0] + cf[1]*xt[DIM] + cf[2]*xt[2*DIM] + cf[3]*xt[3*DIM];
}

// ============================ layernorm ============================
__global__ __launch_bounds__(256) void k_ln(const float* __restrict__ in, const float* __restrict__ g,
                                            const float* __restrict__ bb, float* __restrict__ out){
  int t = blockIdx.x, tid = threadIdx.x;
  const float* xt = in + (size_t)t*DIM;
  __shared__ float r1[256], r2[256];
  float s=0.f, s2=0.f;
  for (int i=tid;i<DIM;i+=256){ float v=xt[i]; s+=v; s2+=v*v; }
  r1[tid]=s; r2[tid]=s2; __syncthreads();
  for (int st=128; st>0; st>>=1){ if (tid<st){ r1[tid]+=r1[tid+st]; r2[tid]+=r2[tid+st]; } __syncthreads(); }
  float mu  = r1[0]/(float)DIM;
  float var = r2[0]/(float)DIM - mu*mu;
  float inv = rsqrtf(var + 1e-5f);
  for (int i=tid;i<DIM;i+=256) out[(size_t)t*DIM+i] = (xt[i]-mu)*inv*g[i] + bb[i];
}

// ============================ sum streams + final layernorm ============================
__global__ __launch_bounds__(256) void k_sumln(const float* __restrict__ x4, const float* __restrict__ g,
                                               const float* __restrict__ bb, float* __restrict__ out){
  int t = blockIdx.x, tid = threadIdx.x;
  const float* xt = x4 + (size_t)t*NEXP*DIM;
  __shared__ float xs[DIM];
  __shared__ float r1[256], r2[256];
  float s=0.f, s2=0.f;
  for (int i=tid;i<DIM;i+=256){
    float v = xt[i] + xt[DIM+i] + xt[2*DIM+i] + xt[3*DIM+i];
    xs[i]=v; s+=v; s2+=v*v;
  }
  r1[tid]=s; r2[tid]=s2; __syncthreads();
  for (int st=128; st>0; st>>=1){ if (tid<st){ r1[tid]+=r1[tid+st]; r2[tid]+=r2[tid+st]; } __syncthreads(); }
  float mu  = r1[0]/(float)DIM;
  float var = r2[0]/(float)DIM - mu*mu;
  float inv = rsqrtf(var + 1e-5f);
  for (int i=tid;i<DIM;i+=256) out[(size_t)t*DIM+i] = (xs[i]-mu)*inv*g[i] + bb[i];
}

// ============================ attention (one block per (b,h,q)) ============================
__global__ __launch_bounds__(256) void k_attn(const float* __restrict__ qkv, float* __restrict__ out){
  int blk = blockIdx.x;
  int q = blk % SEQ;
  int h = (blk / SEQ) % NHEAD;
  int b = blk / (SEQ*NHEAD);
  int tid = threadIdx.x;
  __shared__ float sc[SEQ];
  __shared__ float qv[HDIM];
  __shared__ float red[256];
  const float scale = 0.125f; // 1/sqrt(64)
  const float* base = qkv + (size_t)b*SEQ*(3*DIM);
  if (tid < HDIM) qv[tid] = base[(size_t)q*(3*DIM) + h*HDIM + tid];
  __syncthreads();
  for (int k=tid; k<=q; k+=256){
    const float* kv = base + (size_t)k*(3*DIM) + DIM + h*HDIM;
    float s=0.f;
#pragma unroll
    for (int d=0; d<HDIM; d++) s += qv[d]*kv[d];
    sc[k] = s*scale;
  }
  __syncthreads();
  float m = -1e30f;
  for (int k=tid;k<=q;k+=256) m = fmaxf(m, sc[k]);
  red[tid]=m; __syncthreads();
  for (int st=128; st>0; st>>=1){ if (tid<st) red[tid]=fmaxf(red[tid],red[tid+st]); __syncthreads(); }
  m = red[0]; __syncthreads();
  float se=0.f;
  for (int k=tid;k<=q;k+=256){ float e=expf(sc[k]-m); sc[k]=e; se+=e; }
  red[tid]=se; __syncthreads();
  for (int st=128; st>0; st>>=1){ if (tid<st) red[tid]+=red[tid+st]; __syncthreads(); }
  float inv = 1.f/red[0];
  __syncthreads();
  int dd = tid & 63, part = tid >> 6;
  float acc=0.f;
  for (int k=part; k<=q; k+=4) acc += sc[k]*base[(size_t)k*(3*DIM) + 2*DIM + h*HDIM + dd];
  red[tid]=acc; __syncthreads();
  if (part==0){
    float o = (red[dd]+red[64+dd]+red[128+dd]+red[192+dd])*inv;
    out[((size_t)b*SEQ+q)*DIM + h*HDIM + dd] = o;
  }
}

// ============================ combine: xo[n] = Hm[n][m]x[m] + post[n]*y ============================
__global__ void k_combine(const float* __restrict__ x4, const float* __restrict__ coef,
                          const float* __restrict__ y, float* __restrict__ xo){
  int idx = blockIdx.x*blockDim.x + threadIdx.x;
  if (idx >= NTOK*DIM) return;
  int t = idx / DIM, d = idx - t*DIM;
  const float* cf = coef + (size_t)t*NC;
  float xv[4];
#pragma unroll
  for (int m=0;m<4;m++) xv[m] = x4[((size_t)t*NEXP+m)*DIM + d];
  float yv = y[idx];
#pragma unroll
  for (int n=0;n<4;n++){
    float o = cf[20+n]*yv;
#pragma unroll
    for (int m=0;m<4;m++) o += cf[n*4+m]*xv[m];
    xo[((size_t)t*NEXP+n)*DIM + d] = o;
  }
}

// ============================ tiled f32 GEMM ============================
// C(MxN) = A(MxK,row) * B ; TRANSB=false: B is KxN row-major; TRANSB=true: B is NxK row-major.
// ACT: 0=none, 1=exact gelu
template<int ACT, bool TRANSB>
__global__ __launch_bounds__(256) void k_gemm(const float* __restrict__ A,
                                              const float* __restrict__ Bm,
                                              float* __restrict__ C,
                                              int M, int N, int K)
{
  constexpr int BM=128, BN=64, BK=16, PAD=4;
  __shared__ __align__(16) float As[BK][BM+PAD];
  __shared__ __align__(16) float Bs[BK][BN+PAD];
  const int bm = blockIdx.y*BM, bn = blockIdx.x*BN;
  const int tid = threadIdx.x;
  const int tx = tid & 15;   // -> n (4 cols)
  const int ty = tid >> 4;   // -> m (8 rows)
  float acc[8][4];
#pragma unroll
  for (int i=0;i<8;i++)
#pragma unroll
    for (int j=0;j<4;j++) acc[i][j]=0.f;

  for (int k0=0; k0<K; k0+=BK){
#pragma unroll
    for (int r=0; r<(BM*BK)/256; r++){
      int i = tid + r*256;
      int m = i >> 4, kk = i & 15;
      int gm = bm + m;
      As[kk][m] = (gm < M) ? A[(size_t)gm*K + k0 + kk] : 0.f;
    }
    if (!TRANSB){
#pragma unroll
      for (int r=0; r<(BN*BK)/256; r++){
        int i = tid + r*256;
        int kk = i >> 6, n = i & 63;
        int gn = bn + n;
        Bs[kk][n] = (gn < N) ? Bm[(size_t)(k0+kk)*N + gn] : 0.f;
      }
    } else {
#pragma unroll
      for (int r=0; r<(BN*BK)/256; r++){
        int i = tid + r*256;
        int n = i >> 4, kk = i & 15;
        int gn = bn + n;
        Bs[kk][n] = (gn < N) ? Bm[(size_t)gn*K + k0 + kk] : 0.f;
      }
    }
    __syncthreads();
#pragma unroll
    for (int kk=0; kk<BK; kk++){
      float4 a0 = *(const float4*)&As[kk][ty*8];
      float4 a1 = *(const float4*)&As[kk][ty*8+4];
      float4 b0 = *(const float4*)&Bs[kk][tx*4];
      float ra[8] = {a0.x,a0.y,a0.z,a0.w,a1.x,a1.y,a1.z,a1.w};
      float rb[4] = {b0.x,b0.y,b0.z,b0.w};
#pragma unroll
      for (int i=0;i<8;i++)
#pragma unroll
        for (int j=0;j<4;j++) acc[i][j] += ra[i]*rb[j];
    }
    __syncthreads();
  }
#pragma unroll
  for (int i=0;i<8;i++){
    int gm = bm + ty*8 + i;
    if (gm >= M) continue;
#pragma unroll
    for (int j=0;j<4;j++){
      int gn = bn + tx*4 + j;
      if (gn >= N) continue;
      float v = acc[i][j];
      if (ACT==1) v = 0.5f*v*(1.f + erff(v*0.70710678118654752f));
      C[(size_t)gm*N + gn] = v;
    }
  }
}

// ============================ host launch ============================
extern "C" void kernel_launch(void* const* d_in, const int* in_sizes, int n_in,
                              void* d_out, int out_size, void* d_ws, size_t ws_size,
                              hipStream_t stream) {
  const int*   ids   = (const int*)  d_in[0];
  const float* tok   = (const float*)d_in[1];
  const float* pos   = (const float*)d_in[2];
  const float* ln1g  = (const float*)d_in[3];
  const float* ln1b  = (const float*)d_in[4];
  const float* ln2g  = (const float*)d_in[5];
  const float* ln2b  = (const float*)d_in[6];
  const float* Wqkv  = (const float*)d_in[7];
  const float* Wproj = (const float*)d_in[8];
  const float* Wfc1  = (const float*)d_in[9];
  const float* Wfc2  = (const float*)d_in[10];
  const float* mAW   = (const float*)d_in[11];
  const float* mAb   = (const float*)d_in[12];
  const float* mAal  = (const float*)d_in[13];
  const float* mFW   = (const float*)d_in[14];
  const float* mFb   = (const float*)d_in[15];
  const float* mFal  = (const float*)d_in[16];
  const float* lnfg  = (const float*)d_in[17];
  const float* lnfb  = (const float*)d_in[18];
  float* out = (float*)d_out;

  float* ws   = (float*)d_ws;
  float* xA   = ws + O_X;
  float* xB   = ws + O_X2;
  float* hbuf = ws + O_H;
  float* lnb  = ws + O_LN;
  float* big  = ws + O_BIG;
  float* t1   = ws + O_T1;
  float* ybuf = ws + O_Y;
  float* coef = ws + O_CF;

  const int ETHREADS = 256;
  const int EGRID = (NTOK*DIM + ETHREADS-1)/ETHREADS;

  k_embed<<<EGRID, ETHREADS, 0, stream>>>(ids, tok, pos, xA);

  float* xc = xA; float* xn = xB;
  for (int l=0; l<NLAYER; l++){
    // ---- attention mhc ----
    k_coef<<<NTOK, 256, 0, stream>>>(xc, mAW + (size_t)l*NDIM*NC, mAb + (size_t)l*NC, mAal + l, coef);
    k_hmix<<<EGRID, ETHREADS, 0, stream>>>(xc, coef, hbuf);
    k_ln  <<<NTOK, 256, 0, stream>>>(hbuf, ln1g + (size_t)l*DIM, ln1b + (size_t)l*DIM, lnb);
    k_gemm<0,false><<<dim3((3*DIM)/64, NTOK/128), 256, 0, stream>>>(lnb, Wqkv + (size_t)l*DIM*3*DIM, big, NTOK, 3*DIM, DIM);
    k_attn<<<BATCH*NHEAD*SEQ, 256, 0, stream>>>(big, t1);
    k_gemm<0,false><<<dim3(DIM/64, NTOK/128), 256, 0, stream>>>(t1, Wproj + (size_t)l*DIM*DIM, ybuf, NTOK, DIM, DIM);
    k_combine<<<EGRID, ETHREADS, 0, stream>>>(xc, coef, ybuf, xn);
    { float* tmp = xc; xc = xn; xn = tmp; }
    // ---- ffn mhc ----
    k_coef<<<NTOK, 256, 0, stream>>>(xc, mFW + (size_t)l*NDIM*NC, mFb + (size_t)l*NC, mFal + l, coef);
    k_hmix<<<EGRID, ETHREADS, 0, stream>>>(xc, coef, hbuf);
    k_ln  <<<NTOK, 256, 0, stream>>>(hbuf, ln2g + (size_t)l*DIM, ln2b + (size_t)l*DIM, lnb);
    k_gemm<1,false><<<dim3(FFDIM/64, NTOK/128), 256, 0, stream>>>(lnb, Wfc1 + (size_t)l*DIM*FFDIM, big, NTOK, FFDIM, DIM);
    k_gemm<0,false><<<dim3(DIM/64, NTOK/128), 256, 0, stream>>>(big, Wfc2 + (size_t)l*FFDIM*DIM, ybuf, NTOK, DIM, FFDIM);
    k_combine<<<EGRID, ETHREADS, 0, stream>>>(xc, coef, ybuf, xn);
    { float* tmp = xc; xc = xn; xn = tmp; }
  }

  k_sumln<<<NTOK, 256, 0, stream>>>(xc, lnfg, lnfb, lnb);
  k_gemm<0,true><<<dim3((VOCAB+63)/64, NTOK/128), 256, 0, stream>>>(lnb, tok, out, NTOK, VOCAB, DIM);
}

// Round 2
// 4517.341 us; speedup vs baseline: 2.6028x; 2.6028x over previous
//
#include <hip/hip_runtime.h>
#include <math.h>

// ---- problem constants ----
constexpr int BATCH  = 2;
constexpr int SEQ    = 1024;
constexpr int DIM    = 768;
constexpr int NLAYER = 4;
constexpr int NHEAD  = 12;
constexpr int HDIM   = 64;
constexpr int NEXP   = 4;
constexpr int FFDIM  = 3072;
constexpr int VOCAB  = 50257;
constexpr int NDIM   = NEXP * DIM;   // 3072
constexpr int NC     = NEXP*NEXP + 2*NEXP; // 24
constexpr int NTOK   = BATCH * SEQ;  // 2048

using bf16x8 = __attribute__((ext_vector_type(8))) __bf16;
using f32x4  = __attribute__((ext_vector_type(4))) float;
using u16x8  = __attribute__((ext_vector_type(8))) unsigned short;

__device__ inline unsigned short f2bf(float f){
  unsigned u = __builtin_bit_cast(unsigned, f);
  u += 0x7fffu + ((u >> 16) & 1u);      // round-to-nearest-even
  return (unsigned short)(u >> 16);
}

// ---- workspace layout (float units) ----
constexpr size_t SZ_X   = (size_t)NTOK * NEXP * DIM;   // 6291456
constexpr size_t SZ_T   = (size_t)NTOK * DIM;          // 1572864
constexpr size_t O_X    = 0;
constexpr size_t O_X2   = O_X  + SZ_X;
constexpr size_t O_TMP  = O_X2 + SZ_X;                 // h / y (f32, SZ_T)
constexpr size_t O_BIG  = O_TMP + SZ_T;                // qkv f32 (NTOK*2304) or fc1-out bf16 (NTOK*3072 u16)
constexpr size_t O_LNB  = O_BIG + (size_t)NTOK*2304;   // bf16 NTOK*DIM -> SZ_T/2 floats
constexpr size_t O_T1B  = O_LNB + SZ_T/2;
constexpr size_t O_COEF = O_T1B + SZ_T/2;              // NTOK*NC f32
constexpr size_t O_WT   = O_COEF + (size_t)NTOK*NC;    // bf16 transposed weights (7077888 u16)
// end = ~24.04M floats = 96.2 MB

// ============================ embed ============================
__global__ void k_embed(const int* __restrict__ ids, const float* __restrict__ tok,
                        const float* __restrict__ pos, float* __restrict__ x4) {
  int idx = blockIdx.x*blockDim.x + threadIdx.x;
  if (idx >= NTOK*DIM) return;
  int t = idx / DIM, d = idx - t*DIM;
  int s = t % SEQ;
  float v = tok[(size_t)ids[t]*DIM + d] + pos[(size_t)s*DIM + d];
#pragma unroll
  for (int n=0;n<NEXP;n++) x4[((size_t)t*NEXP+n)*DIM + d] = v;
}

// ============================ mhc coef (RMS + logits + sinkhorn) ============================
__global__ __launch_bounds__(256) void k_coef(const float* __restrict__ x4,
                                              const float* __restrict__ W,
                                              const float* __restrict__ bb,
                                              const float* __restrict__ alpha_p,
                                              float* __restrict__ coef) {
  int t = blockIdx.x;
  int tid = threadIdx.x;
  const float* xt = x4 + (size_t)t*NDIM;
  __shared__ float red[256];
  float ss = 0.f;
  for (int i=tid;i<NDIM;i+=256){ float v=xt[i]; ss += v*v; }
  red[tid]=ss; __syncthreads();
  for (int st=128; st>0; st>>=1){ if (tid<st) red[tid]+=red[tid+st]; __syncthreads(); }
  float rfac = rsqrtf(red[0]/(float)NDIM + 1e-6f);

  float acc[NC];
#pragma unroll
  for (int j=0;j<NC;j++) acc[j]=0.f;
  for (int i=tid;i<NDIM;i+=256){
    float v = xt[i];
    const float* wr = W + (size_t)i*NC;
#pragma unroll
    for (int j=0;j<NC;j++) acc[j] += v*wr[j];
  }
  __shared__ float accs[256][NC+1];
#pragma unroll
  for (int j=0;j<NC;j++) accs[tid][j]=acc[j];
  __syncthreads();
  for (int st=128; st>0; st>>=1){
    if (tid<st){
      for (int j=0;j<NC;j++) accs[tid][j]+=accs[tid+st][j];
    }
    __syncthreads();
  }
  if (tid==0){
    float alpha = alpha_p[0];
    float lg[NC];
    for (int j=0;j<NC;j++) lg[j] = accs[0][j]*rfac*alpha + bb[j];
    float lm[16];
    for (int j=0;j<16;j++) lm[j]=lg[j];
    for (int it=0; it<10; ++it){
      for (int n=0;n<4;n++){
        float m0 = fmaxf(fmaxf(lm[n*4],lm[n*4+1]),fmaxf(lm[n*4+2],lm[n*4+3]));
        float se = expf(lm[n*4]-m0)+expf(lm[n*4+1]-m0)+expf(lm[n*4+2]-m0)+expf(lm[n*4+3]-m0);
        float l  = m0 + logf(se);
        for (int m=0;m<4;m++) lm[n*4+m]-=l;
      }
      for (int m=0;m<4;m++){
        float m0 = fmaxf(fmaxf(lm[m],lm[4+m]),fmaxf(lm[8+m],lm[12+m]));
        float se = expf(lm[m]-m0)+expf(lm[4+m]-m0)+expf(lm[8+m]-m0)+expf(lm[12+m]-m0);
        float l  = m0 + logf(se);
        for (int n=0;n<4;n++) lm[n*4+m]-=l;
      }
    }
    float* cf = coef + (size_t)t*NC;
    for (int j=0;j<16;j++) cf[j]=expf(lm[j]);
    float pm = fmaxf(fmaxf(lg[16],lg[17]),fmaxf(lg[18],lg[19]));
    float e0=expf(lg[16]-pm), e1=expf(lg[17]-pm), e2=expf(lg[18]-pm), e3=expf(lg[19]-pm);
    float es=e0+e1+e2+e3;
    cf[16]=e0/es; cf[17]=e1/es; cf[18]=e2/es; cf[19]=e3/es;
    for (int j=20;j<24;j++) cf[j]=1.f/(1.f+expf(-lg[j]));
  }
}

// ============================ h = sum_n pre[n]*x[n] ============================
__global__ void k_hmix(const float* __restrict__ x4, const float* __restrict__ coef,
                       float* __restrict__ h){
  int idx = blockIdx.x*blockDim.x + threadIdx.x;
  if (idx >= NTOK*DIM) return;
  int t = idx / DIM, d = idx - t*DIM;
  const float* cf = coef + (size_t)t*NC + 16;
  const float* xt = x4 + (size_t)t*NEXP*DIM + d;
  h[idx] = cf[0]*xt[0] + cf[1]*xt[DIM] + cf[2]*xt[2*DIM] + cf[3]*xt[3*DIM];
}

// ============================ layernorm -> bf16 ============================
__global__ __launch_bounds__(256) void k_ln(const float* __restrict__ in, const float* __restrict__ g,
                                            const float* __restrict__ bb, unsigned short* __restrict__ out){
  int t = blockIdx.x, tid = threadIdx.x;
  const float* xt = in + (size_t)t*DIM;
  __shared__ float r1[256], r2[256];
  float s=0.f, s2=0.f;
  for (int i=tid;i<DIM;i+=256){ float v=xt[i]; s+=v; s2+=v*v; }
  r1[tid]=s; r2[tid]=s2; __syncthreads();
  for (int st=128; st>0; st>>=1){ if (tid<st){ r1[tid]+=r1[tid+st]; r2[tid]+=r2[tid+st]; } __syncthreads(); }
  float mu  = r1[0]/(float)DIM;
  float var = r2[0]/(float)DIM - mu*mu;
  float inv = rsqrtf(var + 1e-5f);
  for (int i=tid;i<DIM;i+=256) out[(size_t)t*DIM+i] = f2bf((xt[i]-mu)*inv*g[i] + bb[i]);
}

// ============================ sum streams + final layernorm -> bf16 ============================
__global__ __launch_bounds__(256) void k_sumln(const float* __restrict__ x4, const float* __restrict__ g,
                                               const float* __restrict__ bb, unsigned short* __restrict__ out){
  int t = blockIdx.x, tid = threadIdx.x;
  const float* xt = x4 + (size_t)t*NEXP*DIM;
  __shared__ float xs[DIM];
  __shared__ float r1[256], r2[256];
  float s=0.f, s2=0.f;
  for (int i=tid;i<DIM;i+=256){
    float v = xt[i] + xt[DIM+i] + xt[2*DIM+i] + xt[3*DIM+i];
    xs[i]=v; s+=v; s2+=v*v;
  }
  r1[tid]=s; r2[tid]=s2; __syncthreads();
  for (int st=128; st>0; st>>=1){ if (tid<st){ r1[tid]+=r1[tid+st]; r2[tid]+=r2[tid+st]; } __syncthreads(); }
  float mu  = r1[0]/(float)DIM;
  float var = r2[0]/(float)DIM - mu*mu;
  float inv = rsqrtf(var + 1e-5f);
  for (int i=tid;i<DIM;i+=256) out[(size_t)t*DIM+i] = f2bf((xs[i]-mu)*inv*g[i] + bb[i]);
}

// ============================ attention (one block per (b,h,q)), bf16 out ============================
__global__ __launch_bounds__(256) void k_attn(const float* __restrict__ qkv, unsigned short* __restrict__ out){
  int blk = blockIdx.x;
  int q = blk % SEQ;
  int h = (blk / SEQ) % NHEAD;
  int b = blk / (SEQ*NHEAD);
  int tid = threadIdx.x;
  __shared__ float sc[SEQ];
  __shared__ float qv[HDIM];
  __shared__ float red[256];
  const float scale = 0.125f; // 1/sqrt(64)
  const float* base = qkv + (size_t)b*SEQ*(3*DIM);
  if (tid < HDIM) qv[tid] = base[(size_t)q*(3*DIM) + h*HDIM + tid];
  __syncthreads();
  for (int k=tid; k<=q; k+=256){
    const float4* kv = (const float4*)(base + (size_t)k*(3*DIM) + DIM + h*HDIM);
    float s=0.f;
#pragma unroll
    for (int d4=0; d4<HDIM/4; d4++){
      float4 kk = kv[d4];
      float4 qq = *(const float4*)&qv[d4*4];
      s += qq.x*kk.x + qq.y*kk.y + qq.z*kk.z + qq.w*kk.w;
    }
    sc[k] = s*scale;
  }
  __syncthreads();
  float m = -1e30f;
  for (int k=tid;k<=q;k+=256) m = fmaxf(m, sc[k]);
  red[tid]=m; __syncthreads();
  for (int st=128; st>0; st>>=1){ if (tid<st) red[tid]=fmaxf(red[tid],red[tid+st]); __syncthreads(); }
  m = red[0]; __syncthreads();
  float se=0.f;
  for (int k=tid;k<=q;k+=256){ float e=expf(sc[k]-m); sc[k]=e; se+=e; }
  red[tid]=se; __syncthreads();
  for (int st=128; st>0; st>>=1){ if (tid<st) red[tid]+=red[tid+st]; __syncthreads(); }
  float inv = 1.f/red[0];
  __syncthreads();
  int dd = tid & 63, part = tid >> 6;
  float acc=0.f;
  for (int k=part; k<=q; k+=4) acc += sc[k]*base[(size_t)k*(3*DIM) + 2*DIM + h*HDIM + dd];
  red[tid]=acc; __syncthreads();
  if (part==0){
    float o = (red[dd]+red[64+dd]+red[128+dd]+red[192+dd])*inv;
    out[((size_t)b*SEQ+q)*DIM + h*HDIM + dd] = f2bf(o);
  }
}

// ============================ combine: xo[n] = Hm[n][m]x[m] + post[n]*y ============================
__global__ void k_combine(const float* __restrict__ x4, const float* __restrict__ coef,
                          const float* __restrict__ y, float* __restrict__ xo){
  int idx = blockIdx.x*blockDim.x + threadIdx.x;
  if (idx >= NTOK*DIM) return;
  int t = idx / DIM, d = idx - t*DIM;
  const float* cf = coef + (size_t)t*NC;
  float xv[4];
#pragma unroll
  for (int m=0;m<4;m++) xv[m] = x4[((size_t)t*NEXP+m)*DIM + d];
  float yv = y[idx];
#pragma unroll
  for (int n=0;n<4;n++){
    float o = cf[20+n]*yv;
#pragma unroll
    for (int m=0;m<4;m++) o += cf[n*4+m]*xv[m];
    xo[((size_t)t*NEXP+n)*DIM + d] = o;
  }
}

// ============================ weight transpose+convert: f32 [K][N] -> bf16 [N][K] ============================
__global__ __launch_bounds__(256) void k_wtrans(const float* __restrict__ src,
                                                unsigned short* __restrict__ dst, int K, int N){
  __shared__ float tile[32][33];
  int n0 = blockIdx.x*32, k0 = blockIdx.y*32;
  int tx = threadIdx.x & 31, ty = threadIdx.x >> 5; // 32x8
#pragma unroll
  for (int r=0;r<32;r+=8)
    tile[ty+r][tx] = src[(size_t)(k0+ty+r)*N + n0+tx];
  __syncthreads();
#pragma unroll
  for (int r=0;r<32;r+=8)
    dst[(size_t)(n0+ty+r)*K + k0+tx] = f2bf(tile[tx][ty+r]);
}

// ============================ MFMA bf16 GEMM (m97 structure) ============================
// C(MxN) = A(MxK bf16, row) * B^T(NxK, row).  BF32B: B source is f32 (reg-staged convert).
// ACT: 0=none, 1=exact gelu.  OUTBF: write bf16 instead of f32.
// grid: x = M/128 (M-fastest for B-panel L2 reuse), y = ceil(N/128); nwg % 8 == 0 required.
template<int ACT, bool OUTBF, bool BF32B>
__global__ __launch_bounds__(256) void k_mgemm(const unsigned short* __restrict__ A,
                                               const void* __restrict__ Bsrc,
                                               void* __restrict__ Cout,
                                               int M, int N, int K)
{
  __shared__ __align__(16) unsigned short As[128*32];
  __shared__ __align__(16) unsigned short Bs[128*32];
  const int tid = threadIdx.x;
  const int l = tid & 63, w = tid >> 6;
  const int wr = w >> 1, wc = w & 1;

  // bijective XCD-chunked swizzle (nwg % 8 == 0 by construction)
  const int nwg  = gridDim.x * gridDim.y;
  const int flat = blockIdx.y * gridDim.x + blockIdx.x;
  const int q8   = nwg >> 3;
  const int wk   = (flat & 7) * q8 + (flat >> 3);
  const int bm = (wk % gridDim.x) * 128;
  const int bn = (wk / gridDim.x) * 128;

  const int srow = tid >> 2;        // 0..63
  const int scol = (tid & 3) * 8;   // k offset in elems

  f32x4 acc[4][4];
#pragma unroll
  for (int i=0;i<4;i++)
#pragma unroll
    for (int j=0;j<4;j++) acc[i][j] = (f32x4){0.f,0.f,0.f,0.f};

  for (int k0 = 0; k0 < K; k0 += 32){
    // ---- stage A tile (128x32 bf16) via global_load_lds, linear LDS ----
#pragma unroll
    for (int c=0;c<2;++c){
      const unsigned short* ga = A + (size_t)(bm + c*64 + srow)*K + (k0 + scol);
      __builtin_amdgcn_global_load_lds(
          (const __attribute__((address_space(1))) void*)ga,
          (__attribute__((address_space(3))) void*)(As + c*2048 + w*512),
          16, 0, 0);
    }
    // ---- stage B^T tile ----
    if constexpr (!BF32B){
      const unsigned short* B = (const unsigned short*)Bsrc;
#pragma unroll
      for (int c=0;c<2;++c){
        int gn = bn + c*64 + srow; if (gn >= N) gn = N-1;
        const unsigned short* gb = B + (size_t)gn*K + (k0 + scol);
        __builtin_amdgcn_global_load_lds(
            (const __attribute__((address_space(1))) void*)gb,
            (__attribute__((address_space(3))) void*)(Bs + c*2048 + w*512),
            16, 0, 0);
      }
    } else {
      const float* B = (const float*)Bsrc;
#pragma unroll
      for (int c=0;c<2;++c){
        int gn = bn + c*64 + srow; if (gn >= N) gn = N-1;
        const float* gb = B + (size_t)gn*K + (k0 + scol);
        float4 f0 = *(const float4*)gb;
        float4 f1 = *(const float4*)(gb+4);
        u16x8 v;
        v[0]=f2bf(f0.x); v[1]=f2bf(f0.y); v[2]=f2bf(f0.z); v[3]=f2bf(f0.w);
        v[4]=f2bf(f1.x); v[5]=f2bf(f1.y); v[6]=f2bf(f1.z); v[7]=f2bf(f1.w);
        *(u16x8*)(Bs + c*2048 + (size_t)tid*8) = v;
      }
    }
    __syncthreads();

    bf16x8 af[4], bfr[4];
#pragma unroll
    for (int i=0;i<4;i++){
      af[i]  = *(const bf16x8*)(As + ((wr*64 + i*16 + (l&15))*32 + (l>>4)*8));
      bfr[i] = *(const bf16x8*)(Bs + ((wc*64 + i*16 + (l&15))*32 + (l>>4)*8));
    }
#pragma unroll
    for (int mi=0;mi<4;mi++)
#pragma unroll
      for (int ni=0;ni<4;ni++)
        acc[mi][ni] = __builtin_amdgcn_mfma_f32_16x16x32_bf16(af[mi], bfr[ni], acc[mi][ni], 0,0,0);
    __syncthreads();
  }

  // ---- epilogue: D row=(l>>4)*4+r, col=l&15 (m89 verified mapping) ----
#pragma unroll
  for (int mi=0;mi<4;mi++){
    const int gm0 = bm + wr*64 + mi*16 + (l>>4)*4;
#pragma unroll
    for (int ni=0;ni<4;ni++){
      const int gn = bn + wc*64 + ni*16 + (l&15);
      if (gn < N){
#pragma unroll
        for (int r=0;r<4;r++){
          float v = acc[mi][ni][r];
          if constexpr (ACT==1) v = 0.5f*v*(1.f + erff(v*0.70710678118654752f));
          if constexpr (OUTBF) ((unsigned short*)Cout)[(size_t)(gm0+r)*N + gn] = f2bf(v);
          else                 ((float*)Cout)[(size_t)(gm0+r)*N + gn] = v;
        }
      }
    }
  }
}

// ============================ host launch ============================
extern "C" void kernel_launch(void* const* d_in, const int* in_sizes, int n_in,
                              void* d_out, int out_size, void* d_ws, size_t ws_size,
                              hipStream_t stream) {
  const int*   ids   = (const int*)  d_in[0];
  const float* tok   = (const float*)d_in[1];
  const float* pos   = (const float*)d_in[2];
  const float* ln1g  = (const float*)d_in[3];
  const float* ln1b  = (const float*)d_in[4];
  const float* ln2g  = (const float*)d_in[5];
  const float* ln2b  = (const float*)d_in[6];
  const float* Wqkv  = (const float*)d_in[7];
  const float* Wproj = (const float*)d_in[8];
  const float* Wfc1  = (const float*)d_in[9];
  const float* Wfc2  = (const float*)d_in[10];
  const float* mAW   = (const float*)d_in[11];
  const float* mAb   = (const float*)d_in[12];
  const float* mAal  = (const float*)d_in[13];
  const float* mFW   = (const float*)d_in[14];
  const float* mFb   = (const float*)d_in[15];
  const float* mFal  = (const float*)d_in[16];
  const float* lnfg  = (const float*)d_in[17];
  const float* lnfb  = (const float*)d_in[18];
  float* out = (float*)d_out;

  float* ws    = (float*)d_ws;
  float* xA    = ws + O_X;
  float* xB    = ws + O_X2;
  float* tmpF  = ws + O_TMP;                       // h then y
  float* bigF  = ws + O_BIG;                       // qkv f32
  unsigned short* bigBF = (unsigned short*)(ws + O_BIG);   // fc1-out bf16
  unsigned short* lnbf  = (unsigned short*)(ws + O_LNB);
  unsigned short* t1bf  = (unsigned short*)(ws + O_T1B);
  float* coef  = ws + O_COEF;
  unsigned short* wT    = (unsigned short*)(ws + O_WT);
  unsigned short* wqkvT  = wT;
  unsigned short* wprojT = wT + (size_t)2304*768;
  unsigned short* wfc1T  = wprojT + (size_t)768*768;
  unsigned short* wfc2T  = wfc1T + (size_t)3072*768;

  const int ETHREADS = 256;
  const int EGRID = (NTOK*DIM + ETHREADS-1)/ETHREADS;

  k_embed<<<EGRID, ETHREADS, 0, stream>>>(ids, tok, pos, xA);

  float* xc = xA; float* xn = xB;
  for (int l=0; l<NLAYER; l++){
    // per-layer weight transpose+convert to bf16 [N][K]
    k_wtrans<<<dim3(2304/32, 768/32), 256, 0, stream>>>(Wqkv + (size_t)l*DIM*3*DIM, wqkvT, 768, 2304);
    k_wtrans<<<dim3( 768/32, 768/32), 256, 0, stream>>>(Wproj + (size_t)l*DIM*DIM,  wprojT, 768, 768);
    k_wtrans<<<dim3(3072/32, 768/32), 256, 0, stream>>>(Wfc1 + (size_t)l*DIM*FFDIM, wfc1T, 768, 3072);
    k_wtrans<<<dim3( 768/32,3072/32), 256, 0, stream>>>(Wfc2 + (size_t)l*FFDIM*DIM, wfc2T, 3072, 768);

    // ---- attention mhc ----
    k_coef<<<NTOK, 256, 0, stream>>>(xc, mAW + (size_t)l*NDIM*NC, mAb + (size_t)l*NC, mAal + l, coef);
    k_hmix<<<EGRID, ETHREADS, 0, stream>>>(xc, coef, tmpF);
    k_ln  <<<NTOK, 256, 0, stream>>>(tmpF, ln1g + (size_t)l*DIM, ln1b + (size_t)l*DIM, lnbf);
    k_mgemm<0,false,false><<<dim3(16, 2304/128), 256, 0, stream>>>(lnbf, wqkvT, bigF, NTOK, 2304, 768);
    k_attn<<<BATCH*NHEAD*SEQ, 256, 0, stream>>>(bigF, t1bf);
    k_mgemm<0,false,false><<<dim3(16, 768/128), 256, 0, stream>>>(t1bf, wprojT, tmpF, NTOK, 768, 768);
    k_combine<<<EGRID, ETHREADS, 0, stream>>>(xc, coef, tmpF, xn);
    { float* tmp = xc; xc = xn; xn = tmp; }

    // ---- ffn mhc ----
    k_coef<<<NTOK, 256, 0, stream>>>(xc, mFW + (size_t)l*NDIM*NC, mFb + (size_t)l*NC, mFal + l, coef);
    k_hmix<<<EGRID, ETHREADS, 0, stream>>>(xc, coef, tmpF);
    k_ln  <<<NTOK, 256, 0, stream>>>(tmpF, ln2g + (size_t)l*DIM, ln2b + (size_t)l*DIM, lnbf);
    k_mgemm<1,true ,false><<<dim3(16, 3072/128), 256, 0, stream>>>(lnbf, wfc1T, (void*)bigBF, NTOK, 3072, 768);
    k_mgemm<0,false,false><<<dim3(16, 768/128), 256, 0, stream>>>(bigBF, wfc2T, tmpF, NTOK, 768, 3072);
    k_combine<<<EGRID, ETHREADS, 0, stream>>>(xc, coef, tmpF, xn);
    { float* tmp = xc; xc = xn; xn = tmp; }
  }

  k_sumln<<<NTOK, 256, 0, stream>>>(xc, lnfg, lnfb, lnbf);
  // lm_head: A = ln_f(x) bf16, B = tok_emb f32 [V][D] (reg-staged convert), C = f32 logits
  k_mgemm<0,false,true><<<dim3(16, (VOCAB+127)/128), 256, 0, stream>>>(lnbf, tok, out, NTOK, VOCAB, 768);
}

// Round 3
// 2076.128 us; speedup vs baseline: 5.6634x; 2.1758x over previous
//
#include <hip/hip_runtime.h>
#include <math.h>

// ---- problem constants ----
constexpr int BATCH  = 2;
constexpr int SEQ    = 1024;
constexpr int DIM    = 768;
constexpr int NLAYER = 4;
constexpr int NHEAD  = 12;
constexpr int HDIM   = 64;
constexpr int NEXP   = 4;
constexpr int FFDIM  = 3072;
constexpr int VOCAB  = 50257;
constexpr int NDIM   = NEXP * DIM;   // 3072
constexpr int NC     = NEXP*NEXP + 2*NEXP; // 24
constexpr int NTOK   = BATCH * SEQ;  // 2048

using bf16x8 = __attribute__((ext_vector_type(8))) __bf16;
using f32x4  = __attribute__((ext_vector_type(4))) float;
using u16x8  = __attribute__((ext_vector_type(8))) unsigned short;

__device__ inline unsigned short f2bf(float f){
  unsigned u = __builtin_bit_cast(unsigned, f);
  u += 0x7fffu + ((u >> 16) & 1u);      // round-to-nearest-even
  return (unsigned short)(u >> 16);
}
__device__ inline bf16x8 as_bf(u16x8 v){ return __builtin_bit_cast(bf16x8, v); }

// ---- workspace layout (float units) ----
constexpr size_t SZ_X   = (size_t)NTOK * NEXP * DIM;   // 6291456
constexpr size_t SZ_T   = (size_t)NTOK * DIM;          // 1572864
constexpr size_t O_X    = 0;
constexpr size_t O_X2   = O_X  + SZ_X;
constexpr size_t O_TMP  = O_X2 + SZ_X;                 // y (f32, SZ_T)
constexpr size_t O_BIG  = O_TMP + SZ_T;                // qkv bf16 (NTOK*2304 u16) / fc1-out bf16 (NTOK*3072 u16)
constexpr size_t O_LNB  = O_BIG + (size_t)NTOK*2304;   // bf16 NTOK*DIM
constexpr size_t O_T1B  = O_LNB + SZ_T/2;
constexpr size_t O_COEF = O_T1B + SZ_T/2;              // NTOK*NC f32
constexpr size_t O_WT   = O_COEF + (size_t)NTOK*NC;    // bf16 transposed weights

// ============================ embed ============================
__global__ void k_embed(const int* __restrict__ ids, const float* __restrict__ tok,
                        const float* __restrict__ pos, float* __restrict__ x4) {
  int idx = blockIdx.x*blockDim.x + threadIdx.x;
  if (idx >= NTOK*DIM) return;
  int t = idx / DIM, d = idx - t*DIM;
  int s = t % SEQ;
  float v = tok[(size_t)ids[t]*DIM + d] + pos[(size_t)s*DIM + d];
#pragma unroll
  for (int n=0;n<NEXP;n++) x4[((size_t)t*NEXP+n)*DIM + d] = v;
}

// ============================ mhc coef (RMS + logits + sinkhorn) ============================
__global__ __launch_bounds__(256) void k_coef(const float* __restrict__ x4,
                                              const float* __restrict__ W,
                                              const float* __restrict__ bb,
                                              const float* __restrict__ alpha_p,
                                              float* __restrict__ coef) {
  int t = blockIdx.x;
  int tid = threadIdx.x;
  const float* xt = x4 + (size_t)t*NDIM;
  __shared__ float red[256];
  float ss = 0.f;
  for (int i=tid;i<NDIM;i+=256){ float v=xt[i]; ss += v*v; }
  red[tid]=ss; __syncthreads();
  for (int st=128; st>0; st>>=1){ if (tid<st) red[tid]+=red[tid+st]; __syncthreads(); }
  float rfac = rsqrtf(red[0]/(float)NDIM + 1e-6f);

  float acc[NC];
#pragma unroll
  for (int j=0;j<NC;j++) acc[j]=0.f;
  for (int i=tid;i<NDIM;i+=256){
    float v = xt[i];
    const float* wr = W + (size_t)i*NC;
#pragma unroll
    for (int j=0;j<NC;j++) acc[j] += v*wr[j];
  }
  __shared__ float accs[256][NC+1];
#pragma unroll
  for (int j=0;j<NC;j++) accs[tid][j]=acc[j];
  __syncthreads();
  for (int st=128; st>0; st>>=1){
    if (tid<st){
      for (int j=0;j<NC;j++) accs[tid][j]+=accs[tid+st][j];
    }
    __syncthreads();
  }
  if (tid==0){
    float alpha = alpha_p[0];
    float lg[NC];
    for (int j=0;j<NC;j++) lg[j] = accs[0][j]*rfac*alpha + bb[j];
    float lm[16];
    for (int j=0;j<16;j++) lm[j]=lg[j];
    for (int it=0; it<10; ++it){
      for (int n=0;n<4;n++){
        float m0 = fmaxf(fmaxf(lm[n*4],lm[n*4+1]),fmaxf(lm[n*4+2],lm[n*4+3]));
        float se = expf(lm[n*4]-m0)+expf(lm[n*4+1]-m0)+expf(lm[n*4+2]-m0)+expf(lm[n*4+3]-m0);
        float l  = m0 + logf(se);
        for (int m=0;m<4;m++) lm[n*4+m]-=l;
      }
      for (int m=0;m<4;m++){
        float m0 = fmaxf(fmaxf(lm[m],lm[4+m]),fmaxf(lm[8+m],lm[12+m]));
        float se = expf(lm[m]-m0)+expf(lm[4+m]-m0)+expf(lm[8+m]-m0)+expf(lm[12+m]-m0);
        float l  = m0 + logf(se);
        for (int n=0;n<4;n++) lm[n*4+m]-=l;
      }
    }
    float* cf = coef + (size_t)t*NC;
    for (int j=0;j<16;j++) cf[j]=expf(lm[j]);
    float pm = fmaxf(fmaxf(lg[16],lg[17]),fmaxf(lg[18],lg[19]));
    float e0=expf(lg[16]-pm), e1=expf(lg[17]-pm), e2=expf(lg[18]-pm), e3=expf(lg[19]-pm);
    float es=e0+e1+e2+e3;
    cf[16]=e0/es; cf[17]=e1/es; cf[18]=e2/es; cf[19]=e3/es;
    for (int j=20;j<24;j++) cf[j]=1.f/(1.f+expf(-lg[j]));
  }
}

// ============================ fused h-mix + layernorm -> bf16 ============================
__global__ __launch_bounds__(256) void k_hmixln(const float* __restrict__ x4, const float* __restrict__ coef,
                                                const float* __restrict__ g, const float* __restrict__ bb,
                                                unsigned short* __restrict__ out){
  int t = blockIdx.x, tid = threadIdx.x;
  const float* cf = coef + (size_t)t*NC + 16;
  const float* xt = x4 + (size_t)t*NEXP*DIM;
  float c0=cf[0], c1=cf[1], c2=cf[2], c3=cf[3];
  float h[3];
  float s=0.f, s2=0.f;
#pragma unroll
  for (int ii=0; ii<3; ii++){
    int i = tid + ii*256;
    float v = c0*xt[i] + c1*xt[DIM+i] + c2*xt[2*DIM+i] + c3*xt[3*DIM+i];
    h[ii]=v; s+=v; s2+=v*v;
  }
  __shared__ float r1[256], r2[256];
  r1[tid]=s; r2[tid]=s2; __syncthreads();
  for (int st=128; st>0; st>>=1){ if (tid<st){ r1[tid]+=r1[tid+st]; r2[tid]+=r2[tid+st]; } __syncthreads(); }
  float mu  = r1[0]/(float)DIM;
  float var = r2[0]/(float)DIM - mu*mu;
  float inv = rsqrtf(var + 1e-5f);
#pragma unroll
  for (int ii=0; ii<3; ii++){
    int i = tid + ii*256;
    out[(size_t)t*DIM+i] = f2bf((h[ii]-mu)*inv*g[i] + bb[i]);
  }
}

// ============================ sum streams + final layernorm -> bf16 ============================
__global__ __launch_bounds__(256) void k_sumln(const float* __restrict__ x4, const float* __restrict__ g,
                                               const float* __restrict__ bb, unsigned short* __restrict__ out){
  int t = blockIdx.x, tid = threadIdx.x;
  const float* xt = x4 + (size_t)t*NEXP*DIM;
  __shared__ float xs[DIM];
  __shared__ float r1[256], r2[256];
  float s=0.f, s2=0.f;
  for (int i=tid;i<DIM;i+=256){
    float v = xt[i] + xt[DIM+i] + xt[2*DIM+i] + xt[3*DIM+i];
    xs[i]=v; s+=v; s2+=v*v;
  }
  r1[tid]=s; r2[tid]=s2; __syncthreads();
  for (int st=128; st>0; st>>=1){ if (tid<st){ r1[tid]+=r1[tid+st]; r2[tid]+=r2[tid+st]; } __syncthreads(); }
  float mu  = r1[0]/(float)DIM;
  float var = r2[0]/(float)DIM - mu*mu;
  float inv = rsqrtf(var + 1e-5f);
  for (int i=tid;i<DIM;i+=256) out[(size_t)t*DIM+i] = f2bf((xs[i]-mu)*inv*g[i] + bb[i]);
}

// ============================ flash attention (MFMA, bf16 qkv in, bf16 out) ============================
// grid: (SEQ/64, NHEAD, BATCH), 256 threads = 4 waves; wave owns 16 q rows.
__global__ __launch_bounds__(256) void k_fattn(const unsigned short* __restrict__ qkv,
                                               unsigned short* __restrict__ out){
  const int qb = blockIdx.x, h = blockIdx.y, b = blockIdx.z;
  const int tid = threadIdx.x;
  const int l = tid & 63, w = tid >> 6;
  const int lr = l & 15, lh = l >> 4;
  const int qw = qb*64 + w*16;         // wave's first q row
  constexpr int LDV = 68;              // padded row stride (elems)
  __shared__ unsigned short Vt[64*LDV];        // V^T [d][k]
  __shared__ unsigned short Pl[4*16*LDV];      // per-wave P [q][k]
  unsigned short* Pw = Pl + w*16*LDV;

  const unsigned short* base = qkv + (size_t)b*SEQ*2304;

  // hoist Q fragments: A[q=lr][d = ks*32 + lh*8 + j]
  u16x8 qa[2];
  {
    const unsigned short* qp = base + (size_t)(qw + lr)*2304 + h*64 + lh*8;
    qa[0] = *(const u16x8*)qp;
    qa[1] = *(const u16x8*)(qp + 32);
  }

  f32x4 o[4];
#pragma unroll
  for (int df=0; df<4; df++) o[df] = (f32x4){0.f,0.f,0.f,0.f};
  float m_run[4], l_run[4];
#pragma unroll
  for (int r=0;r<4;r++){ m_run[r] = -1e30f; l_run[r] = 0.f; }

  const int kTiles = qb + 1;
  for (int t=0; t<kTiles; ++t){
    const int k0 = t*64;
    __syncthreads();   // previous tile's Vt reads complete
    // ---- stage V^T (cooperative, 256 threads) ----
#pragma unroll
    for (int i=0;i<2;i++){
      int f = tid + i*256;             // 0..511
      int k = f >> 3;
      int d0 = (f & 7) * 8;
      u16x8 v = *(const u16x8*)(base + (size_t)(k0+k)*2304 + 1536 + h*64 + d0);
#pragma unroll
      for (int j=0;j<8;j++) Vt[(d0+j)*LDV + k] = v[j];
    }
    __syncthreads();

    // ---- QK^T: s[kf] C-layout row=q_local=(lh*4+r), col=k_local=lr ----
    f32x4 s[4];
#pragma unroll
    for (int kf=0;kf<4;kf++) s[kf] = (f32x4){0.f,0.f,0.f,0.f};
#pragma unroll
    for (int ks=0;ks<2;ks++){
#pragma unroll
      for (int kf=0;kf<4;kf++){
        u16x8 kb = *(const u16x8*)(base + (size_t)(k0 + kf*16 + lr)*2304 + 768 + h*64 + ks*32 + lh*8);
        s[kf] = __builtin_amdgcn_mfma_f32_16x16x32_bf16(as_bf(qa[ks]), as_bf(kb), s[kf], 0,0,0);
      }
    }

    // ---- mask + scale ----
    float sc[4][4];
#pragma unroll
    for (int kf=0;kf<4;kf++){
      int kg = k0 + kf*16 + lr;
#pragma unroll
      for (int r=0;r<4;r++){
        int qg = qw + lh*4 + r;
        sc[kf][r] = (kg <= qg) ? s[kf][r]*0.125f : -1e30f;
      }
    }
    // ---- online softmax (row reduce over 16 lanes, masks 1,2,4,8) ----
    float mt[4];
#pragma unroll
    for (int r=0;r<4;r++)
      mt[r] = fmaxf(fmaxf(sc[0][r],sc[1][r]), fmaxf(sc[2][r],sc[3][r]));
#pragma unroll
    for (int msk=1; msk<16; msk<<=1)
#pragma unroll
      for (int r=0;r<4;r++) mt[r] = fmaxf(mt[r], __shfl_xor(mt[r], msk));
    float c[4], rs[4];
#pragma unroll
    for (int r=0;r<4;r++){
      float mn = fmaxf(m_run[r], mt[r]);
      c[r] = expf(m_run[r] - mn);
      m_run[r] = mn;
      rs[r] = 0.f;
    }
#pragma unroll
    for (int kf=0;kf<4;kf++)
#pragma unroll
      for (int r=0;r<4;r++){
        float p = expf(sc[kf][r] - m_run[r]);
        rs[r] += p;
        Pw[(lh*4+r)*LDV + kf*16 + lr] = f2bf(p);
      }
#pragma unroll
    for (int msk=1; msk<16; msk<<=1)
#pragma unroll
      for (int r=0;r<4;r++) rs[r] += __shfl_xor(rs[r], msk);
#pragma unroll
    for (int r=0;r<4;r++) l_run[r] = l_run[r]*c[r] + rs[r];
#pragma unroll
    for (int df=0;df<4;df++)
#pragma unroll
      for (int r=0;r<4;r++) o[df][r] *= c[r];

    // ---- PV: O[q][d] += P[q][k] * V^T[d][k] ----
#pragma unroll
    for (int ks=0;ks<2;ks++){
      u16x8 pa = *(const u16x8*)&Pw[lr*LDV + ks*32 + lh*8];
#pragma unroll
      for (int df=0;df<4;df++){
        u16x8 vb = *(const u16x8*)&Vt[(df*16 + lr)*LDV + ks*32 + lh*8];
        o[df] = __builtin_amdgcn_mfma_f32_16x16x32_bf16(as_bf(pa), as_bf(vb), o[df], 0,0,0);
      }
    }
  }

  // ---- epilogue ----
  float inv[4];
#pragma unroll
  for (int r=0;r<4;r++) inv[r] = 1.f/l_run[r];
#pragma unroll
  for (int df=0;df<4;df++)
#pragma unroll
    for (int r=0;r<4;r++){
      int qg = qw + lh*4 + r;
      out[((size_t)b*SEQ + qg)*DIM + h*64 + df*16 + lr] = f2bf(o[df][r]*inv[r]);
    }
}

// ============================ combine: xo[n] = Hm[n][m]x[m] + post[n]*y ============================
__global__ void k_combine(const float* __restrict__ x4, const float* __restrict__ coef,
                          const float* __restrict__ y, float* __restrict__ xo){
  int idx = blockIdx.x*blockDim.x + threadIdx.x;
  if (idx >= NTOK*DIM) return;
  int t = idx / DIM, d = idx - t*DIM;
  const float* cf = coef + (size_t)t*NC;
  float xv[4];
#pragma unroll
  for (int m=0;m<4;m++) xv[m] = x4[((size_t)t*NEXP+m)*DIM + d];
  float yv = y[idx];
#pragma unroll
  for (int n=0;n<4;n++){
    float o = cf[20+n]*yv;
#pragma unroll
    for (int m=0;m<4;m++) o += cf[n*4+m]*xv[m];
    xo[((size_t)t*NEXP+n)*DIM + d] = o;
  }
}

// ============================ weight transpose+convert: f32 [K][N] -> bf16 [N][K] ============================
__global__ __launch_bounds__(256) void k_wtrans(const float* __restrict__ src,
                                                unsigned short* __restrict__ dst, int K, int N){
  __shared__ float tile[32][33];
  int n0 = blockIdx.x*32, k0 = blockIdx.y*32;
  int tx = threadIdx.x & 31, ty = threadIdx.x >> 5; // 32x8
#pragma unroll
  for (int r=0;r<32;r+=8)
    tile[ty+r][tx] = src[(size_t)(k0+ty+r)*N + n0+tx];
  __syncthreads();
#pragma unroll
  for (int r=0;r<32;r+=8)
    dst[(size_t)(n0+ty+r)*K + k0+tx] = f2bf(tile[tx][ty+r]);
}

// ============================ MFMA bf16 GEMM (m97 structure) ============================
template<int ACT, bool OUTBF, bool BF32B>
__global__ __launch_bounds__(256) void k_mgemm(const unsigned short* __restrict__ A,
                                               const void* __restrict__ Bsrc,
                                               void* __restrict__ Cout,
                                               int M, int N, int K)
{
  __shared__ __align__(16) unsigned short As[128*32];
  __shared__ __align__(16) unsigned short Bs[128*32];
  const int tid = threadIdx.x;
  const int l = tid & 63, w = tid >> 6;
  const int wr = w >> 1, wc = w & 1;

  const int nwg  = gridDim.x * gridDim.y;
  const int flat = blockIdx.y * gridDim.x + blockIdx.x;
  const int q8   = nwg >> 3;
  const int wk   = (flat & 7) * q8 + (flat >> 3);
  const int bm = (wk % gridDim.x) * 128;
  const int bn = (wk / gridDim.x) * 128;

  const int srow = tid >> 2;
  const int scol = (tid & 3) * 8;

  f32x4 acc[4][4];
#pragma unroll
  for (int i=0;i<4;i++)
#pragma unroll
    for (int j=0;j<4;j++) acc[i][j] = (f32x4){0.f,0.f,0.f,0.f};

  for (int k0 = 0; k0 < K; k0 += 32){
#pragma unroll
    for (int c=0;c<2;++c){
      const unsigned short* ga = A + (size_t)(bm + c*64 + srow)*K + (k0 + scol);
      __builtin_amdgcn_global_load_lds(
          (const __attribute__((address_space(1))) void*)ga,
          (__attribute__((address_space(3))) void*)(As + c*2048 + w*512),
          16, 0, 0);
    }
    if constexpr (!BF32B){
      const unsigned short* B = (const unsigned short*)Bsrc;
#pragma unroll
      for (int c=0;c<2;++c){
        int gn = bn + c*64 + srow; if (gn >= N) gn = N-1;
        const unsigned short* gb = B + (size_t)gn*K + (k0 + scol);
        __builtin_amdgcn_global_load_lds(
            (const __attribute__((address_space(1))) void*)gb,
            (__attribute__((address_space(3))) void*)(Bs + c*2048 + w*512),
            16, 0, 0);
      }
    } else {
      const float* B = (const float*)Bsrc;
#pragma unroll
      for (int c=0;c<2;++c){
        int gn = bn + c*64 + srow; if (gn >= N) gn = N-1;
        const float* gb = B + (size_t)gn*K + (k0 + scol);
        float4 f0 = *(const float4*)gb;
        float4 f1 = *(const float4*)(gb+4);
        u16x8 v;
        v[0]=f2bf(f0.x); v[1]=f2bf(f0.y); v[2]=f2bf(f0.z); v[3]=f2bf(f0.w);
        v[4]=f2bf(f1.x); v[5]=f2bf(f1.y); v[6]=f2bf(f1.z); v[7]=f2bf(f1.w);
        *(u16x8*)(Bs + c*2048 + (size_t)tid*8) = v;
      }
    }
    __syncthreads();

    bf16x8 af[4], bfr[4];
#pragma unroll
    for (int i=0;i<4;i++){
      af[i]  = *(const bf16x8*)(As + ((wr*64 + i*16 + (l&15))*32 + (l>>4)*8));
      bfr[i] = *(const bf16x8*)(Bs + ((wc*64 + i*16 + (l&15))*32 + (l>>4)*8));
    }
#pragma unroll
    for (int mi=0;mi<4;mi++)
#pragma unroll
      for (int ni=0;ni<4;ni++)
        acc[mi][ni] = __builtin_amdgcn_mfma_f32_16x16x32_bf16(af[mi], bfr[ni], acc[mi][ni], 0,0,0);
    __syncthreads();
  }

#pragma unroll
  for (int mi=0;mi<4;mi++){
    const int gm0 = bm + wr*64 + mi*16 + (l>>4)*4;
#pragma unroll
    for (int ni=0;ni<4;ni++){
      const int gn = bn + wc*64 + ni*16 + (l&15);
      if (gn < N){
#pragma unroll
        for (int r=0;r<4;r++){
          float v = acc[mi][ni][r];
          if constexpr (ACT==1) v = 0.5f*v*(1.f + erff(v*0.70710678118654752f));
          if constexpr (OUTBF) ((unsigned short*)Cout)[(size_t)(gm0+r)*N + gn] = f2bf(v);
          else                 ((float*)Cout)[(size_t)(gm0+r)*N + gn] = v;
        }
      }
    }
  }
}

// ============================ host launch ============================
extern "C" void kernel_launch(void* const* d_in, const int* in_sizes, int n_in,
                              void* d_out, int out_size, void* d_ws, size_t ws_size,
                              hipStream_t stream) {
  const int*   ids   = (const int*)  d_in[0];
  const float* tok   = (const float*)d_in[1];
  const float* pos   = (const float*)d_in[2];
  const float* ln1g  = (const float*)d_in[3];
  const float* ln1b  = (const float*)d_in[4];
  const float* ln2g  = (const float*)d_in[5];
  const float* ln2b  = (const float*)d_in[6];
  const float* Wqkv  = (const float*)d_in[7];
  const float* Wproj = (const float*)d_in[8];
  const float* Wfc1  = (const float*)d_in[9];
  const float* Wfc2  = (const float*)d_in[10];
  const float* mAW   = (const float*)d_in[11];
  const float* mAb   = (const float*)d_in[12];
  const float* mAal  = (const float*)d_in[13];
  const float* mFW   = (const float*)d_in[14];
  const float* mFb   = (const float*)d_in[15];
  const float* mFal  = (const float*)d_in[16];
  const float* lnfg  = (const float*)d_in[17];
  const float* lnfb  = (const float*)d_in[18];
  float* out = (float*)d_out;

  float* ws    = (float*)d_ws;
  float* xA    = ws + O_X;
  float* xB    = ws + O_X2;
  float* tmpF  = ws + O_TMP;                       // y f32
  unsigned short* bigBF = (unsigned short*)(ws + O_BIG);   // qkv / fc1-out bf16
  unsigned short* lnbf  = (unsigned short*)(ws + O_LNB);
  unsigned short* t1bf  = (unsigned short*)(ws + O_T1B);
  float* coef  = ws + O_COEF;
  unsigned short* wT    = (unsigned short*)(ws + O_WT);
  unsigned short* wqkvT  = wT;
  unsigned short* wprojT = wT + (size_t)2304*768;
  unsigned short* wfc1T  = wprojT + (size_t)768*768;
  unsigned short* wfc2T  = wfc1T + (size_t)3072*768;

  const int ETHREADS = 256;
  const int EGRID = (NTOK*DIM + ETHREADS-1)/ETHREADS;

  k_embed<<<EGRID, ETHREADS, 0, stream>>>(ids, tok, pos, xA);

  float* xc = xA; float* xn = xB;
  for (int l=0; l<NLAYER; l++){
    k_wtrans<<<dim3(2304/32, 768/32), 256, 0, stream>>>(Wqkv + (size_t)l*DIM*3*DIM, wqkvT, 768, 2304);
    k_wtrans<<<dim3( 768/32, 768/32), 256, 0, stream>>>(Wproj + (size_t)l*DIM*DIM,  wprojT, 768, 768);
    k_wtrans<<<dim3(3072/32, 768/32), 256, 0, stream>>>(Wfc1 + (size_t)l*DIM*FFDIM, wfc1T, 768, 3072);
    k_wtrans<<<dim3( 768/32,3072/32), 256, 0, stream>>>(Wfc2 + (size_t)l*FFDIM*DIM, wfc2T, 3072, 768);

    // ---- attention mhc ----
    k_coef<<<NTOK, 256, 0, stream>>>(xc, mAW + (size_t)l*NDIM*NC, mAb + (size_t)l*NC, mAal + l, coef);
    k_hmixln<<<NTOK, 256, 0, stream>>>(xc, coef, ln1g + (size_t)l*DIM, ln1b + (size_t)l*DIM, lnbf);
    k_mgemm<0,true ,false><<<dim3(16, 2304/128), 256, 0, stream>>>(lnbf, wqkvT, (void*)bigBF, NTOK, 2304, 768);
    k_fattn<<<dim3(SEQ/64, NHEAD, BATCH), 256, 0, stream>>>(bigBF, t1bf);
    k_mgemm<0,false,false><<<dim3(16, 768/128), 256, 0, stream>>>(t1bf, wprojT, tmpF, NTOK, 768, 768);
    k_combine<<<EGRID, ETHREADS, 0, stream>>>(xc, coef, tmpF, xn);
    { float* tmp = xc; xc = xn; xn = tmp; }

    // ---- ffn mhc ----
    k_coef<<<NTOK, 256, 0, stream>>>(xc, mFW + (size_t)l*NDIM*NC, mFb + (size_t)l*NC, mFal + l, coef);
    k_hmixln<<<NTOK, 256, 0, stream>>>(xc, coef, ln2g + (size_t)l*DIM, ln2b + (size_t)l*DIM, lnbf);
    k_mgemm<1,true ,false><<<dim3(16, 3072/128), 256, 0, stream>>>(lnbf, wfc1T, (void*)bigBF, NTOK, 3072, 768);
    k_mgemm<0,false,false><<<dim3(16, 768/128), 256, 0, stream>>>(bigBF, wfc2T, tmpF, NTOK, 768, 3072);
    k_combine<<<EGRID, ETHREADS, 0, stream>>>(xc, coef, tmpF, xn);
    { float* tmp = xc; xc = xn; xn = tmp; }
  }

  k_sumln<<<NTOK, 256, 0, stream>>>(xc, lnfg, lnfb, lnbf);
  k_mgemm<0,false,true><<<dim3(16, (VOCAB+127)/128), 256, 0, stream>>>(lnbf, tok, out, NTOK, VOCAB, 768);
}

// Round 4
// 2046.372 us; speedup vs baseline: 5.7457x; 1.0145x over previous
//
#include <hip/hip_runtime.h>
#include <math.h>

// ---- problem constants ----
constexpr int BATCH  = 2;
constexpr int SEQ    = 1024;
constexpr int DIM    = 768;
constexpr int NLAYER = 4;
constexpr int NHEAD  = 12;
constexpr int HDIM   = 64;
constexpr int NEXP   = 4;
constexpr int FFDIM  = 3072;
constexpr int VOCAB  = 50257;
constexpr int NDIM   = NEXP * DIM;   // 3072
constexpr int NC     = NEXP*NEXP + 2*NEXP; // 24
constexpr int NTOK   = BATCH * SEQ;  // 2048

using bf16x8 = __attribute__((ext_vector_type(8))) __bf16;
using f32x4  = __attribute__((ext_vector_type(4))) float;
using u16x8  = __attribute__((ext_vector_type(8))) unsigned short;

__device__ inline unsigned short f2bf(float f){
  unsigned u = __builtin_bit_cast(unsigned, f);
  u += 0x7fffu + ((u >> 16) & 1u);      // round-to-nearest-even
  return (unsigned short)(u >> 16);
}
__device__ inline bf16x8 as_bf(u16x8 v){ return __builtin_bit_cast(bf16x8, v); }

// ---- workspace layout (float units) ----
constexpr size_t SZ_X   = (size_t)NTOK * NEXP * DIM;   // 6291456
constexpr size_t SZ_T   = (size_t)NTOK * DIM;          // 1572864
constexpr size_t O_X    = 0;
constexpr size_t O_X2   = O_X  + SZ_X;                 //  6291456
constexpr size_t O_TMP  = O_X2 + SZ_X;                 // 12582912  y (f32)
constexpr size_t O_BIG  = O_TMP + SZ_T;                // 14155776  qkv/fc1-out bf16
constexpr size_t O_LNB  = O_BIG + (size_t)NTOK*2304;   // 16515072  bf16 NTOK*DIM
constexpr size_t O_T1B  = O_LNB + SZ_T/2;              // 17301504
constexpr size_t O_COEF = O_T1B + SZ_T/2;              // 18087936  NTOK*NC f32
constexpr size_t O_WT   = O_COEF + (size_t)NTOK*NC;    // 18137088  per-layer bf16 weights (3538944 f)
// tokbf overlays [0 .. 19298688) floats (all dead by the time it's written)
constexpr size_t O_LNF  = 19298688;                    // final-LN bf16 out (786432 f) — past tokbf
// total footprint: 21676032 floats = 86.7 MB

// ============================ fused mhc: [combine] + coef(sinkhorn) + pre-mix + LN ============================
// FIRST: x0 = tok_emb[ids]+pos broadcast to 4 streams (embed fused), no combine.
// else : x' = Hm_prev x + post_prev*y  (coef read in-place, then overwritten with new coef)
template<bool FIRST>
__global__ __launch_bounds__(256) void k_mhc(const int* __restrict__ ids,
                                             const float* __restrict__ tokf,
                                             const float* __restrict__ posf,
                                             const float* __restrict__ xin,
                                             const float* __restrict__ y,
                                             float* __restrict__ xout,
                                             const float* __restrict__ W,
                                             const float* __restrict__ bb,
                                             const float* __restrict__ alpha_p,
                                             const float* __restrict__ g,
                                             const float* __restrict__ lnb_,
                                             float* __restrict__ coef,
                                             unsigned short* __restrict__ lnout){
  const int t = blockIdx.x, tid = threadIdx.x;
  __shared__ float red[256], red2[256];
  __shared__ float accs[256][NC+1];
  __shared__ float cfl[NC];

  float xp[3][4];
  float ss = 0.f;

  if constexpr (FIRST){
    const float* te = tokf + (size_t)ids[t]*DIM;
    const float* pe = posf + (size_t)(t % SEQ)*DIM;
#pragma unroll
    for (int k=0;k<3;k++){
      int d = tid + k*256;
      float v = te[d] + pe[d];
#pragma unroll
      for (int n=0;n<4;n++){
        xp[k][n] = v;
        xout[(size_t)t*NDIM + n*DIM + d] = v;
      }
      ss += 4.f*v*v;
    }
  } else {
    float cfp[20];
    const float* cp = coef + (size_t)t*NC;
#pragma unroll
    for (int j=0;j<16;j++) cfp[j] = cp[j];
#pragma unroll
    for (int j=0;j<4;j++) cfp[16+j] = cp[20+j];
    const float* xt = xin + (size_t)t*NDIM;
#pragma unroll
    for (int k=0;k<3;k++){
      int d = tid + k*256;
      float xm[4];
#pragma unroll
      for (int m=0;m<4;m++) xm[m] = xt[m*DIM + d];
      float yv = y[(size_t)t*DIM + d];
#pragma unroll
      for (int n=0;n<4;n++){
        float o = cfp[16+n]*yv;
#pragma unroll
        for (int m=0;m<4;m++) o += cfp[n*4+m]*xm[m];
        xp[k][n] = o;
        xout[(size_t)t*NDIM + n*DIM + d] = o;
        ss += o*o;
      }
    }
  }

  // ---- RMS over 3072 ----
  red[tid]=ss; __syncthreads();
  for (int st=128; st>0; st>>=1){ if (tid<st) red[tid]+=red[tid+st]; __syncthreads(); }
  float rfac = rsqrtf(red[0]/(float)NDIM + 1e-6f);

  // ---- logits = (x*rfac) @ W * alpha + b ----
  float acc[NC];
#pragma unroll
  for (int j=0;j<NC;j++) acc[j]=0.f;
#pragma unroll
  for (int k=0;k<3;k++){
    int d = tid + k*256;
#pragma unroll
    for (int n=0;n<4;n++){
      float v = xp[k][n];
      const float* wr = W + (size_t)(n*DIM + d)*NC;
#pragma unroll
      for (int j=0;j<NC;j++) acc[j] += v*wr[j];
    }
  }
#pragma unroll
  for (int j=0;j<NC;j++) accs[tid][j]=acc[j];
  __syncthreads();
  for (int st=128; st>0; st>>=1){
    if (tid<st){ for (int j=0;j<NC;j++) accs[tid][j]+=accs[tid+st][j]; }
    __syncthreads();
  }

  // ---- sinkhorn on lanes 0..15 (j = n*4+m); raw pre/post logits stashed by lanes 16..23 ----
  const float alpha = alpha_p[0];
  float* cfg = coef + (size_t)t*NC;
  if (tid < 16){
    float lmv = accs[0][tid]*rfac*alpha + bb[tid];
#pragma unroll
    for (int it=0; it<10; ++it){
      float mx = fmaxf(lmv, __shfl_xor(lmv,1)); mx = fmaxf(mx, __shfl_xor(mx,2));
      float se = expf(lmv-mx); se += __shfl_xor(se,1); se += __shfl_xor(se,2);
      lmv -= mx + logf(se);
      mx = fmaxf(lmv, __shfl_xor(lmv,4)); mx = fmaxf(mx, __shfl_xor(mx,8));
      se = expf(lmv-mx); se += __shfl_xor(se,4); se += __shfl_xor(se,8);
      lmv -= mx + logf(se);
    }
    float hm = expf(lmv);
    cfl[tid] = hm;
    cfg[tid] = hm;
  } else if (tid < 24){
    cfl[tid] = accs[0][tid]*rfac*alpha + bb[tid];
  }
  __syncthreads();
  if (tid == 0){
    float l0=cfl[16], l1=cfl[17], l2=cfl[18], l3=cfl[19];
    float pm = fmaxf(fmaxf(l0,l1),fmaxf(l2,l3));
    float e0=expf(l0-pm), e1=expf(l1-pm), e2=expf(l2-pm), e3=expf(l3-pm);
    float es=e0+e1+e2+e3;
    cfl[16]=e0/es; cfl[17]=e1/es; cfl[18]=e2/es; cfl[19]=e3/es;
#pragma unroll
    for (int j=20;j<24;j++) cfl[j] = 1.f/(1.f+expf(-cfl[j]));
#pragma unroll
    for (int j=16;j<24;j++) cfg[j] = cfl[j];
  }
  __syncthreads();

  // ---- h = pre·x' ; LayerNorm -> bf16 ----
  float p0=cfl[16], p1=cfl[17], p2=cfl[18], p3=cfl[19];
  float h[3], s1=0.f, s2=0.f;
#pragma unroll
  for (int k=0;k<3;k++){
    float v = p0*xp[k][0] + p1*xp[k][1] + p2*xp[k][2] + p3*xp[k][3];
    h[k]=v; s1+=v; s2+=v*v;
  }
  red[tid]=s1; red2[tid]=s2; __syncthreads();
  for (int st=128; st>0; st>>=1){ if (tid<st){ red[tid]+=red[tid+st]; red2[tid]+=red2[tid+st]; } __syncthreads(); }
  float mu  = red[0]/(float)DIM;
  float var = red2[0]/(float)DIM - mu*mu;
  float inv = rsqrtf(var + 1e-5f);
#pragma unroll
  for (int k=0;k<3;k++){
    int d = tid + k*256;
    lnout[(size_t)t*DIM+d] = f2bf((h[k]-mu)*inv*g[d] + lnb_[d]);
  }
}

// ============================ tail: combine-sum + final LN -> bf16 ============================
__global__ __launch_bounds__(256) void k_csumln(const float* __restrict__ xin,
                                                const float* __restrict__ coef,
                                                const float* __restrict__ y,
                                                const float* __restrict__ g,
                                                const float* __restrict__ bb,
                                                unsigned short* __restrict__ out){
  const int t = blockIdx.x, tid = threadIdx.x;
  const float* cp = coef + (size_t)t*NC;
  float cs[4];
#pragma unroll
  for (int m=0;m<4;m++) cs[m] = cp[m] + cp[4+m] + cp[8+m] + cp[12+m];
  float ps = cp[20]+cp[21]+cp[22]+cp[23];
  const float* xt = xin + (size_t)t*NDIM;
  float h[3], s1=0.f, s2=0.f;
#pragma unroll
  for (int k=0;k<3;k++){
    int d = tid + k*256;
    float v = ps * y[(size_t)t*DIM + d];
#pragma unroll
    for (int m=0;m<4;m++) v += cs[m]*xt[m*DIM + d];
    h[k]=v; s1+=v; s2+=v*v;
  }
  __shared__ float r1[256], r2[256];
  r1[tid]=s1; r2[tid]=s2; __syncthreads();
  for (int st=128; st>0; st>>=1){ if (tid<st){ r1[tid]+=r1[tid+st]; r2[tid]+=r2[tid+st]; } __syncthreads(); }
  float mu  = r1[0]/(float)DIM;
  float var = r2[0]/(float)DIM - mu*mu;
  float inv = rsqrtf(var + 1e-5f);
#pragma unroll
  for (int k=0;k<3;k++){
    int d = tid + k*256;
    out[(size_t)t*DIM+d] = f2bf((h[k]-mu)*inv*g[d] + bb[d]);
  }
}

// ============================ flash attention (MFMA, bf16 qkv in, bf16 out) ============================
__global__ __launch_bounds__(256) void k_fattn(const unsigned short* __restrict__ qkv,
                                               unsigned short* __restrict__ out){
  const int qb = blockIdx.x, h = blockIdx.y, b = blockIdx.z;
  const int tid = threadIdx.x;
  const int l = tid & 63, w = tid >> 6;
  const int lr = l & 15, lh = l >> 4;
  const int qw = qb*64 + w*16;
  constexpr int LDV = 68;
  __shared__ unsigned short Vt[64*LDV];
  __shared__ unsigned short Pl[4*16*LDV];
  unsigned short* Pw = Pl + w*16*LDV;

  const unsigned short* base = qkv + (size_t)b*SEQ*2304;

  u16x8 qa[2];
  {
    const unsigned short* qp = base + (size_t)(qw + lr)*2304 + h*64 + lh*8;
    qa[0] = *(const u16x8*)qp;
    qa[1] = *(const u16x8*)(qp + 32);
  }

  f32x4 o[4];
#pragma unroll
  for (int df=0; df<4; df++) o[df] = (f32x4){0.f,0.f,0.f,0.f};
  float m_run[4], l_run[4];
#pragma unroll
  for (int r=0;r<4;r++){ m_run[r] = -1e30f; l_run[r] = 0.f; }

  const int kTiles = qb + 1;
  for (int t=0; t<kTiles; ++t){
    const int k0 = t*64;
    __syncthreads();
#pragma unroll
    for (int i=0;i<2;i++){
      int f = tid + i*256;
      int k = f >> 3;
      int d0 = (f & 7) * 8;
      u16x8 v = *(const u16x8*)(base + (size_t)(k0+k)*2304 + 1536 + h*64 + d0);
#pragma unroll
      for (int j=0;j<8;j++) Vt[(d0+j)*LDV + k] = v[j];
    }
    __syncthreads();

    f32x4 s[4];
#pragma unroll
    for (int kf=0;kf<4;kf++) s[kf] = (f32x4){0.f,0.f,0.f,0.f};
#pragma unroll
    for (int ks=0;ks<2;ks++){
#pragma unroll
      for (int kf=0;kf<4;kf++){
        u16x8 kb = *(const u16x8*)(base + (size_t)(k0 + kf*16 + lr)*2304 + 768 + h*64 + ks*32 + lh*8);
        s[kf] = __builtin_amdgcn_mfma_f32_16x16x32_bf16(as_bf(qa[ks]), as_bf(kb), s[kf], 0,0,0);
      }
    }

    float sc[4][4];
#pragma unroll
    for (int kf=0;kf<4;kf++){
      int kg = k0 + kf*16 + lr;
#pragma unroll
      for (int r=0;r<4;r++){
        int qg = qw + lh*4 + r;
        sc[kf][r] = (kg <= qg) ? s[kf][r]*0.125f : -1e30f;
      }
    }
    float mt[4];
#pragma unroll
    for (int r=0;r<4;r++)
      mt[r] = fmaxf(fmaxf(sc[0][r],sc[1][r]), fmaxf(sc[2][r],sc[3][r]));
#pragma unroll
    for (int msk=1; msk<16; msk<<=1)
#pragma unroll
      for (int r=0;r<4;r++) mt[r] = fmaxf(mt[r], __shfl_xor(mt[r], msk));
    float c[4], rs[4];
#pragma unroll
    for (int r=0;r<4;r++){
      float mn = fmaxf(m_run[r], mt[r]);
      c[r] = expf(m_run[r] - mn);
      m_run[r] = mn;
      rs[r] = 0.f;
    }
#pragma unroll
    for (int kf=0;kf<4;kf++)
#pragma unroll
      for (int r=0;r<4;r++){
        float p = expf(sc[kf][r] - m_run[r]);
        rs[r] += p;
        Pw[(lh*4+r)*LDV + kf*16 + lr] = f2bf(p);
      }
#pragma unroll
    for (int msk=1; msk<16; msk<<=1)
#pragma unroll
      for (int r=0;r<4;r++) rs[r] += __shfl_xor(rs[r], msk);
#pragma unroll
    for (int r=0;r<4;r++) l_run[r] = l_run[r]*c[r] + rs[r];
#pragma unroll
    for (int df=0;df<4;df++)
#pragma unroll
      for (int r=0;r<4;r++) o[df][r] *= c[r];

#pragma unroll
    for (int ks=0;ks<2;ks++){
      u16x8 pa = *(const u16x8*)&Pw[lr*LDV + ks*32 + lh*8];
#pragma unroll
      for (int df=0;df<4;df++){
        u16x8 vb = *(const u16x8*)&Vt[(df*16 + lr)*LDV + ks*32 + lh*8];
        o[df] = __builtin_amdgcn_mfma_f32_16x16x32_bf16(as_bf(pa), as_bf(vb), o[df], 0,0,0);
      }
    }
  }

  float inv[4];
#pragma unroll
  for (int r=0;r<4;r++) inv[r] = 1.f/l_run[r];
#pragma unroll
  for (int df=0;df<4;df++)
#pragma unroll
    for (int r=0;r<4;r++){
      int qg = qw + lh*4 + r;
      out[((size_t)b*SEQ + qg)*DIM + h*64 + df*16 + lr] = f2bf(o[df][r]*inv[r]);
    }
}

// ============================ fused per-layer weight transpose+convert ============================
// f32 [K][N] -> bf16 [N][K] for qkv/proj/fc1/fc2 in one dispatch (6912 tile-blocks)
__global__ __launch_bounds__(256) void k_wtrans4(const float* __restrict__ Wq, const float* __restrict__ Wp,
                                                 const float* __restrict__ W1, const float* __restrict__ W2,
                                                 unsigned short* __restrict__ dq, unsigned short* __restrict__ dp,
                                                 unsigned short* __restrict__ d1, unsigned short* __restrict__ d2){
  int bid = blockIdx.x;
  const float* src; unsigned short* dst; int K, N, local;
  if (bid < 1728)      { src=Wq; dst=dq; K=768;  N=2304; local=bid; }
  else if (bid < 2304) { src=Wp; dst=dp; K=768;  N=768;  local=bid-1728; }
  else if (bid < 4608) { src=W1; dst=d1; K=768;  N=3072; local=bid-2304; }
  else                 { src=W2; dst=d2; K=3072; N=768;  local=bid-4608; }
  int nx = N/32;
  int n0 = (local % nx)*32, k0 = (local / nx)*32;
  __shared__ float tile[32][33];
  int tx = threadIdx.x & 31, ty = threadIdx.x >> 5;
#pragma unroll
  for (int r=0;r<32;r+=8)
    tile[ty+r][tx] = src[(size_t)(k0+ty+r)*N + n0+tx];
  __syncthreads();
#pragma unroll
  for (int r=0;r<32;r+=8)
    dst[(size_t)(n0+ty+r)*K + k0+tx] = f2bf(tile[tx][ty+r]);
}

// ============================ f32 -> bf16 bulk convert (tok_emb) ============================
__global__ void k_cvt(const float* __restrict__ src, unsigned short* __restrict__ dst, int n8){
  int i = blockIdx.x*blockDim.x + threadIdx.x;
  for (; i < n8; i += gridDim.x*blockDim.x){
    float4 f0 = ((const float4*)src)[i*2];
    float4 f1 = ((const float4*)src)[i*2+1];
    u16x8 v;
    v[0]=f2bf(f0.x); v[1]=f2bf(f0.y); v[2]=f2bf(f0.z); v[3]=f2bf(f0.w);
    v[4]=f2bf(f1.x); v[5]=f2bf(f1.y); v[6]=f2bf(f1.z); v[7]=f2bf(f1.w);
    ((u16x8*)dst)[i] = v;
  }
}

// ============================ MFMA bf16 GEMM (m97 structure, BNT = 128 or 64) ============================
// C(MxN) = A(MxK bf16,row) * B^T(NxK bf16,row). ACT: 0=none,1=gelu. OUTBF: bf16 out.
// grid: x = M/128 (M-fastest), y = ceil(N/BNT); nwg % 8 == 0 required.
template<int ACT, bool OUTBF, int BNT>
__global__ __launch_bounds__(256) void k_mgemm(const unsigned short* __restrict__ A,
                                               const unsigned short* __restrict__ B,
                                               void* __restrict__ Cout,
                                               int M, int N, int K)
{
  constexpr int NF = BNT/64*2;          // n-fragments per wave (4 or 2)
  __shared__ __align__(16) unsigned short As[128*32];
  __shared__ __align__(16) unsigned short Bs[BNT*32];
  const int tid = threadIdx.x;
  const int l = tid & 63, w = tid >> 6;
  const int wr = w >> 1, wc = w & 1;

  const int nwg  = gridDim.x * gridDim.y;
  const int flat = blockIdx.y * gridDim.x + blockIdx.x;
  const int q8   = nwg >> 3;
  const int wk   = (flat & 7) * q8 + (flat >> 3);
  const int bm = (wk % gridDim.x) * 128;
  const int bn = (wk / gridDim.x) * BNT;

  const int srow = tid >> 2;
  const int scol = (tid & 3) * 8;

  f32x4 acc[4][NF];
#pragma unroll
  for (int i=0;i<4;i++)
#pragma unroll
    for (int j=0;j<NF;j++) acc[i][j] = (f32x4){0.f,0.f,0.f,0.f};

  for (int k0 = 0; k0 < K; k0 += 32){
#pragma unroll
    for (int c=0;c<2;++c){
      const unsigned short* ga = A + (size_t)(bm + c*64 + srow)*K + (k0 + scol);
      __builtin_amdgcn_global_load_lds(
          (const __attribute__((address_space(1))) void*)ga,
          (__attribute__((address_space(3))) void*)(As + c*2048 + w*512),
          16, 0, 0);
    }
#pragma unroll
    for (int c=0;c<BNT/64;++c){
      int gn = bn + c*64 + srow; if (gn >= N) gn = N-1;
      const unsigned short* gb = B + (size_t)gn*K + (k0 + scol);
      __builtin_amdgcn_global_load_lds(
          (const __attribute__((address_space(1))) void*)gb,
          (__attribute__((address_space(3))) void*)(Bs + c*2048 + w*512),
          16, 0, 0);
    }
    __syncthreads();

    bf16x8 af[4], bfr[NF];
#pragma unroll
    for (int i=0;i<4;i++)
      af[i]  = *(const bf16x8*)(As + ((wr*64 + i*16 + (l&15))*32 + (l>>4)*8));
#pragma unroll
    for (int j=0;j<NF;j++)
      bfr[j] = *(const bf16x8*)(Bs + ((wc*(BNT/2) + j*16 + (l&15))*32 + (l>>4)*8));
#pragma unroll
    for (int mi=0;mi<4;mi++)
#pragma unroll
      for (int ni=0;ni<NF;ni++)
        acc[mi][ni] = __builtin_amdgcn_mfma_f32_16x16x32_bf16(af[mi], bfr[ni], acc[mi][ni], 0,0,0);
    __syncthreads();
  }

#pragma unroll
  for (int mi=0;mi<4;mi++){
    const int gm0 = bm + wr*64 + mi*16 + (l>>4)*4;
#pragma unroll
    for (int ni=0;ni<NF;ni++){
      const int gn = bn + wc*(BNT/2) + ni*16 + (l&15);
      if (gn < N){
#pragma unroll
        for (int r=0;r<4;r++){
          float v = acc[mi][ni][r];
          if constexpr (ACT==1) v = 0.5f*v*(1.f + erff(v*0.70710678118654752f));
          if constexpr (OUTBF) ((unsigned short*)Cout)[(size_t)(gm0+r)*N + gn] = f2bf(v);
          else                 ((float*)Cout)[(size_t)(gm0+r)*N + gn] = v;
        }
      }
    }
  }
}

// ============================ host launch ============================
extern "C" void kernel_launch(void* const* d_in, const int* in_sizes, int n_in,
                              void* d_out, int out_size, void* d_ws, size_t ws_size,
                              hipStream_t stream) {
  const int*   ids   = (const int*)  d_in[0];
  const float* tok   = (const float*)d_in[1];
  const float* pos   = (const float*)d_in[2];
  const float* ln1g  = (const float*)d_in[3];
  const float* ln1b  = (const float*)d_in[4];
  const float* ln2g  = (const float*)d_in[5];
  const float* ln2b  = (const float*)d_in[6];
  const float* Wqkv  = (const float*)d_in[7];
  const float* Wproj = (const float*)d_in[8];
  const float* Wfc1  = (const float*)d_in[9];
  const float* Wfc2  = (const float*)d_in[10];
  const float* mAW   = (const float*)d_in[11];
  const float* mAb   = (const float*)d_in[12];
  const float* mAal  = (const float*)d_in[13];
  const float* mFW   = (const float*)d_in[14];
  const float* mFb   = (const float*)d_in[15];
  const float* mFal  = (const float*)d_in[16];
  const float* lnfg  = (const float*)d_in[17];
  const float* lnfb  = (const float*)d_in[18];
  float* out = (float*)d_out;

  float* ws   = (float*)d_ws;
  float* xA   = ws + O_X;
  float* xB   = ws + O_X2;
  float* tmpF = ws + O_TMP;                                // y f32
  unsigned short* bigBF = (unsigned short*)(ws + O_BIG);   // qkv / fc1-out bf16
  unsigned short* lnbf  = (unsigned short*)(ws + O_LNB);
  unsigned short* t1bf  = (unsigned short*)(ws + O_T1B);
  float* coef = ws + O_COEF;
  unsigned short* wT    = (unsigned short*)(ws + O_WT);
  unsigned short* wqkvT  = wT;
  unsigned short* wprojT = wT + (size_t)2304*768;
  unsigned short* wfc1T  = wprojT + (size_t)768*768;
  unsigned short* wfc2T  = wfc1T + (size_t)3072*768;
  unsigned short* tokbf  = (unsigned short*)(ws + O_X);    // overlays dead buffers at lm_head time
  unsigned short* lnfbf  = (unsigned short*)(ws + O_LNF);

  float* xc = xA; float* xn = xB;
  for (int l=0; l<NLAYER; l++){
    k_wtrans4<<<6912, 256, 0, stream>>>(Wqkv + (size_t)l*DIM*3*DIM, Wproj + (size_t)l*DIM*DIM,
                                        Wfc1 + (size_t)l*DIM*FFDIM, Wfc2 + (size_t)l*FFDIM*DIM,
                                        wqkvT, wprojT, wfc1T, wfc2T);
    // ---- attention sublayer ----
    if (l == 0){
      k_mhc<true><<<NTOK, 256, 0, stream>>>(ids, tok, pos, nullptr, nullptr, xA,
                                            mAW, mAb, mAal, ln1g, ln1b, coef, lnbf);
      // xc stays xA
    } else {
      k_mhc<false><<<NTOK, 256, 0, stream>>>(nullptr, nullptr, nullptr, xc, tmpF, xn,
                                             mAW + (size_t)l*NDIM*NC, mAb + (size_t)l*NC, mAal + l,
                                             ln1g + (size_t)l*DIM, ln1b + (size_t)l*DIM, coef, lnbf);
      { float* tmp = xc; xc = xn; xn = tmp; }
    }
    k_mgemm<0,true ,128><<<dim3(16, 2304/128), 256, 0, stream>>>(lnbf, wqkvT, (void*)bigBF, NTOK, 2304, 768);
    k_fattn<<<dim3(SEQ/64, NHEAD, BATCH), 256, 0, stream>>>(bigBF, t1bf);
    k_mgemm<0,false,64><<<dim3(16, 768/64), 256, 0, stream>>>(t1bf, wprojT, tmpF, NTOK, 768, 768);

    // ---- ffn sublayer ----
    k_mhc<false><<<NTOK, 256, 0, stream>>>(nullptr, nullptr, nullptr, xc, tmpF, xn,
                                           mFW + (size_t)l*NDIM*NC, mFb + (size_t)l*NC, mFal + l,
                                           ln2g + (size_t)l*DIM, ln2b + (size_t)l*DIM, coef, lnbf);
    { float* tmp = xc; xc = xn; xn = tmp; }
    k_mgemm<1,true ,128><<<dim3(16, 3072/128), 256, 0, stream>>>(lnbf, wfc1T, (void*)bigBF, NTOK, 3072, 768);
    k_mgemm<0,false,64><<<dim3(16, 768/64), 256, 0, stream>>>(bigBF, wfc2T, tmpF, NTOK, 768, 3072);
  }

  // tail: combine-sum + final LN, then lm_head on bf16 tok_emb
  k_csumln<<<NTOK, 256, 0, stream>>>(xc, coef, tmpF, lnfg, lnfb, lnfbf);
  k_cvt<<<2048, 256, 0, stream>>>(tok, tokbf, (VOCAB*DIM)/8);
  k_mgemm<0,false,128><<<dim3(16, (VOCAB+127)/128), 256, 0, stream>>>(lnfbf, tokbf, out, NTOK, VOCAB, 768);
}

// Round 6
// 1729.199 us; speedup vs baseline: 6.7996x; 1.1834x over previous
//
#include <hip/hip_runtime.h>
#include <math.h>

// ---- problem constants ----
constexpr int BATCH  = 2;
constexpr int SEQ    = 1024;
constexpr int DIM    = 768;
constexpr int NLAYER = 4;
constexpr int NHEAD  = 12;
constexpr int HDIM   = 64;
constexpr int NEXP   = 4;
constexpr int FFDIM  = 3072;
constexpr int VOCAB  = 50257;
constexpr int NDIM   = NEXP * DIM;   // 3072
constexpr int NC     = NEXP*NEXP + 2*NEXP; // 24
constexpr int NTOK   = BATCH * SEQ;  // 2048

using bf16x8 = __attribute__((ext_vector_type(8))) __bf16;
using f32x4  = __attribute__((ext_vector_type(4))) float;
using u16x8  = __attribute__((ext_vector_type(8))) unsigned short;

__device__ inline unsigned short f2bf(float f){
  unsigned u = __builtin_bit_cast(unsigned, f);
  u += 0x7fffu + ((u >> 16) & 1u);      // round-to-nearest-even
  return (unsigned short)(u >> 16);
}
__device__ inline bf16x8 as_bf(u16x8 v){ return __builtin_bit_cast(bf16x8, v); }

// ---- workspace layout (float units) ----
constexpr size_t SZ_X   = (size_t)NTOK * NEXP * DIM;   // 6291456
constexpr size_t SZ_T   = (size_t)NTOK * DIM;          // 1572864
constexpr size_t O_X    = 0;
constexpr size_t O_X2   = O_X  + SZ_X;                 //  6291456
constexpr size_t O_TMP  = O_X2 + SZ_X;                 // 12582912  y (f32)
constexpr size_t O_BIG  = O_TMP + SZ_T;                // 14155776  qkv/fc1-out bf16
constexpr size_t O_LNB  = O_BIG + (size_t)NTOK*2304;   // 16515072  bf16 NTOK*DIM
constexpr size_t O_T1B  = O_LNB + SZ_T/2;              // 17301504
constexpr size_t O_COEF = O_T1B + SZ_T/2;              // 18087936  NTOK*NC f32
constexpr size_t O_WT   = O_COEF + (size_t)NTOK*NC;    // 18137088  per-layer bf16 weights
// tokbf overlays [0 .. 19298688) floats (dead at lm_head time)
constexpr size_t O_LNF  = 19298688;                    // final-LN bf16 out

// ---- wave-level reduce (64 lanes) ----
__device__ inline float wred_sum(float v){
#pragma unroll
  for (int m=32;m>=1;m>>=1) v += __shfl_xor(v,m);
  return v;
}

// ============================ fused mhc: [combine] + coef(sinkhorn) + pre-mix + LN ============================
template<bool FIRST>
__global__ __launch_bounds__(256) void k_mhc(const int* __restrict__ ids,
                                             const float* __restrict__ tokf,
                                             const float* __restrict__ posf,
                                             const float* __restrict__ xin,
                                             const float* __restrict__ y,
                                             float* __restrict__ xout,
                                             const float* __restrict__ W,
                                             const float* __restrict__ bb,
                                             const float* __restrict__ alpha_p,
                                             const float* __restrict__ g,
                                             const float* __restrict__ lnb_,
                                             float* __restrict__ coef,
                                             unsigned short* __restrict__ lnout){
  const int t = blockIdx.x, tid = threadIdx.x;
  const int w = tid >> 6;
  __shared__ float wred[4], w2[4];
  __shared__ float accw[4][NC];
  __shared__ float cfl[NC];

  float xp[3][4];
  float ss = 0.f;

  if constexpr (FIRST){
    const float* te = tokf + (size_t)ids[t]*DIM;
    const float* pe = posf + (size_t)(t % SEQ)*DIM;
#pragma unroll
    for (int k=0;k<3;k++){
      int d = tid + k*256;
      float v = te[d] + pe[d];
#pragma unroll
      for (int n=0;n<4;n++){
        xp[k][n] = v;
        xout[(size_t)t*NDIM + n*DIM + d] = v;
      }
      ss += 4.f*v*v;
    }
  } else {
    float cfp[20];
    const float* cp = coef + (size_t)t*NC;
#pragma unroll
    for (int j=0;j<16;j++) cfp[j] = cp[j];
#pragma unroll
    for (int j=0;j<4;j++) cfp[16+j] = cp[20+j];
    const float* xt = xin + (size_t)t*NDIM;
#pragma unroll
    for (int k=0;k<3;k++){
      int d = tid + k*256;
      float xm[4];
#pragma unroll
      for (int m=0;m<4;m++) xm[m] = xt[m*DIM + d];
      float yv = y[(size_t)t*DIM + d];
#pragma unroll
      for (int n=0;n<4;n++){
        float o = cfp[16+n]*yv;
#pragma unroll
        for (int m=0;m<4;m++) o += cfp[n*4+m]*xm[m];
        xp[k][n] = o;
        xout[(size_t)t*NDIM + n*DIM + d] = o;
        ss += o*o;
      }
    }
  }

  // ---- RMS over 3072 + logits accumulate (wave shuffles, single barrier) ----
  ss = wred_sum(ss);
  float acc[NC];
#pragma unroll
  for (int j=0;j<NC;j++) acc[j]=0.f;
#pragma unroll
  for (int k=0;k<3;k++){
    int d = tid + k*256;
#pragma unroll
    for (int n=0;n<4;n++){
      float v = xp[k][n];
      const float* wr = W + (size_t)(n*DIM + d)*NC;
#pragma unroll
      for (int j=0;j<NC;j++) acc[j] += v*wr[j];
    }
  }
#pragma unroll
  for (int j=0;j<NC;j++){
#pragma unroll
    for (int m=32;m>=1;m>>=1) acc[j] += __shfl_xor(acc[j], m);
  }
  if ((tid&63)==0){
    wred[w] = ss;
#pragma unroll
    for (int j=0;j<NC;j++) accw[w][j] = acc[j];
  }
  __syncthreads();
  float rfac = rsqrtf((wred[0]+wred[1]+wred[2]+wred[3])/(float)NDIM + 1e-6f);

  // ---- sinkhorn on lanes 0..15; pre/post logits on 16..23 ----
  const float alpha = alpha_p[0];
  float* cfg = coef + (size_t)t*NC;
  if (tid < 16){
    float lmv = (accw[0][tid]+accw[1][tid]+accw[2][tid]+accw[3][tid])*rfac*alpha + bb[tid];
#pragma unroll
    for (int it=0; it<10; ++it){
      float mx = fmaxf(lmv, __shfl_xor(lmv,1)); mx = fmaxf(mx, __shfl_xor(mx,2));
      float se = expf(lmv-mx); se += __shfl_xor(se,1); se += __shfl_xor(se,2);
      lmv -= mx + logf(se);
      mx = fmaxf(lmv, __shfl_xor(lmv,4)); mx = fmaxf(mx, __shfl_xor(mx,8));
      se = expf(lmv-mx); se += __shfl_xor(se,4); se += __shfl_xor(se,8);
      lmv -= mx + logf(se);
    }
    float hm = expf(lmv);
    cfl[tid] = hm;
    cfg[tid] = hm;
  } else if (tid < 24){
    cfl[tid] = (accw[0][tid]+accw[1][tid]+accw[2][tid]+accw[3][tid])*rfac*alpha + bb[tid];
  }
  __syncthreads();
  if (tid == 0){
    float l0=cfl[16], l1=cfl[17], l2=cfl[18], l3=cfl[19];
    float pm = fmaxf(fmaxf(l0,l1),fmaxf(l2,l3));
    float e0=expf(l0-pm), e1=expf(l1-pm), e2=expf(l2-pm), e3=expf(l3-pm);
    float es=e0+e1+e2+e3;
    cfl[16]=e0/es; cfl[17]=e1/es; cfl[18]=e2/es; cfl[19]=e3/es;
#pragma unroll
    for (int j=20;j<24;j++) cfl[j] = 1.f/(1.f+expf(-cfl[j]));
#pragma unroll
    for (int j=16;j<24;j++) cfg[j] = cfl[j];
  }
  __syncthreads();

  // ---- h = pre·x' ; LayerNorm -> bf16 ----
  float p0=cfl[16], p1=cfl[17], p2=cfl[18], p3=cfl[19];
  float h[3], s1=0.f, s2=0.f;
#pragma unroll
  for (int k=0;k<3;k++){
    float v = p0*xp[k][0] + p1*xp[k][1] + p2*xp[k][2] + p3*xp[k][3];
    h[k]=v; s1+=v; s2+=v*v;
  }
  s1 = wred_sum(s1); s2 = wred_sum(s2);
  if ((tid&63)==0){ wred[w]=s1; w2[w]=s2; }
  __syncthreads();
  float mu  = (wred[0]+wred[1]+wred[2]+wred[3])/(float)DIM;
  float var = (w2[0]+w2[1]+w2[2]+w2[3])/(float)DIM - mu*mu;
  float inv = rsqrtf(var + 1e-5f);
#pragma unroll
  for (int k=0;k<3;k++){
    int d = tid + k*256;
    lnout[(size_t)t*DIM+d] = f2bf((h[k]-mu)*inv*g[d] + lnb_[d]);
  }
}

// ============================ tail: combine-sum + final LN -> bf16 ============================
__global__ __launch_bounds__(256) void k_csumln(const float* __restrict__ xin,
                                                const float* __restrict__ coef,
                                                const float* __restrict__ y,
                                                const float* __restrict__ g,
                                                const float* __restrict__ bb,
                                                unsigned short* __restrict__ out){
  const int t = blockIdx.x, tid = threadIdx.x;
  const int w = tid >> 6;
  const float* cp = coef + (size_t)t*NC;
  float cs[4];
#pragma unroll
  for (int m=0;m<4;m++) cs[m] = cp[m] + cp[4+m] + cp[8+m] + cp[12+m];
  float ps = cp[20]+cp[21]+cp[22]+cp[23];
  const float* xt = xin + (size_t)t*NDIM;
  float h[3], s1=0.f, s2=0.f;
#pragma unroll
  for (int k=0;k<3;k++){
    int d = tid + k*256;
    float v = ps * y[(size_t)t*DIM + d];
#pragma unroll
    for (int m=0;m<4;m++) v += cs[m]*xt[m*DIM + d];
    h[k]=v; s1+=v; s2+=v*v;
  }
  __shared__ float r1[4], r2[4];
  s1 = wred_sum(s1); s2 = wred_sum(s2);
  if ((tid&63)==0){ r1[w]=s1; r2[w]=s2; }
  __syncthreads();
  float mu  = (r1[0]+r1[1]+r1[2]+r1[3])/(float)DIM;
  float var = (r2[0]+r2[1]+r2[2]+r2[3])/(float)DIM - mu*mu;
  float inv = rsqrtf(var + 1e-5f);
#pragma unroll
  for (int k=0;k<3;k++){
    int d = tid + k*256;
    out[(size_t)t*DIM+d] = f2bf((h[k]-mu)*inv*g[d] + bb[d]);
  }
}

// ============================ flash attention (MFMA) — longest blocks first ============================
__global__ __launch_bounds__(256) void k_fattn(const unsigned short* __restrict__ qkv,
                                               unsigned short* __restrict__ out){
  const int qb = gridDim.x - 1 - blockIdx.x;   // reverse: qb=15 (16 tiles) dispatched first
  const int h = blockIdx.y, b = blockIdx.z;
  const int tid = threadIdx.x;
  const int l = tid & 63, w = tid >> 6;
  const int lr = l & 15, lh = l >> 4;
  const int qw = qb*64 + w*16;
  constexpr int LDV = 68;
  __shared__ unsigned short Vt[64*LDV];
  __shared__ unsigned short Pl[4*16*LDV];
  unsigned short* Pw = Pl + w*16*LDV;

  const unsigned short* base = qkv + (size_t)b*SEQ*2304;

  u16x8 qa[2];
  {
    const unsigned short* qp = base + (size_t)(qw + lr)*2304 + h*64 + lh*8;
    qa[0] = *(const u16x8*)qp;
    qa[1] = *(const u16x8*)(qp + 32);
  }

  f32x4 o[4];
#pragma unroll
  for (int df=0; df<4; df++) o[df] = (f32x4){0.f,0.f,0.f,0.f};
  float m_run[4], l_run[4];
#pragma unroll
  for (int r=0;r<4;r++){ m_run[r] = -1e30f; l_run[r] = 0.f; }

  const int kTiles = qb + 1;
  for (int t=0; t<kTiles; ++t){
    const int k0 = t*64;
    __syncthreads();
#pragma unroll
    for (int i=0;i<2;i++){
      int f = tid + i*256;
      int k = f >> 3;
      int d0 = (f & 7) * 8;
      u16x8 v = *(const u16x8*)(base + (size_t)(k0+k)*2304 + 1536 + h*64 + d0);
#pragma unroll
      for (int j=0;j<8;j++) Vt[(d0+j)*LDV + k] = v[j];
    }
    __syncthreads();

    f32x4 s[4];
#pragma unroll
    for (int kf=0;kf<4;kf++) s[kf] = (f32x4){0.f,0.f,0.f,0.f};
#pragma unroll
    for (int ks=0;ks<2;ks++){
#pragma unroll
      for (int kf=0;kf<4;kf++){
        u16x8 kb = *(const u16x8*)(base + (size_t)(k0 + kf*16 + lr)*2304 + 768 + h*64 + ks*32 + lh*8);
        s[kf] = __builtin_amdgcn_mfma_f32_16x16x32_bf16(as_bf(qa[ks]), as_bf(kb), s[kf], 0,0,0);
      }
    }

    float sc[4][4];
#pragma unroll
    for (int kf=0;kf<4;kf++){
      int kg = k0 + kf*16 + lr;
#pragma unroll
      for (int r=0;r<4;r++){
        int qg = qw + lh*4 + r;
        sc[kf][r] = (kg <= qg) ? s[kf][r]*0.125f : -1e30f;
      }
    }
    float mt[4];
#pragma unroll
    for (int r=0;r<4;r++)
      mt[r] = fmaxf(fmaxf(sc[0][r],sc[1][r]), fmaxf(sc[2][r],sc[3][r]));
#pragma unroll
    for (int msk=1; msk<16; msk<<=1)
#pragma unroll
      for (int r=0;r<4;r++) mt[r] = fmaxf(mt[r], __shfl_xor(mt[r], msk));
    float c[4], rs[4];
#pragma unroll
    for (int r=0;r<4;r++){
      float mn = fmaxf(m_run[r], mt[r]);
      c[r] = expf(m_run[r] - mn);
      m_run[r] = mn;
      rs[r] = 0.f;
    }
#pragma unroll
    for (int kf=0;kf<4;kf++)
#pragma unroll
      for (int r=0;r<4;r++){
        float p = expf(sc[kf][r] - m_run[r]);
        rs[r] += p;
        Pw[(lh*4+r)*LDV + kf*16 + lr] = f2bf(p);
      }
#pragma unroll
    for (int msk=1; msk<16; msk<<=1)
#pragma unroll
      for (int r=0;r<4;r++) rs[r] += __shfl_xor(rs[r], msk);
#pragma unroll
    for (int r=0;r<4;r++) l_run[r] = l_run[r]*c[r] + rs[r];
#pragma unroll
    for (int df=0;df<4;df++)
#pragma unroll
      for (int r=0;r<4;r++) o[df][r] *= c[r];

#pragma unroll
    for (int ks=0;ks<2;ks++){
      u16x8 pa = *(const u16x8*)&Pw[lr*LDV + ks*32 + lh*8];
#pragma unroll
      for (int df=0;df<4;df++){
        u16x8 vb = *(const u16x8*)&Vt[(df*16 + lr)*LDV + ks*32 + lh*8];
        o[df] = __builtin_amdgcn_mfma_f32_16x16x32_bf16(as_bf(pa), as_bf(vb), o[df], 0,0,0);
      }
    }
  }

  float inv[4];
#pragma unroll
  for (int r=0;r<4;r++) inv[r] = 1.f/l_run[r];
#pragma unroll
  for (int df=0;df<4;df++)
#pragma unroll
    for (int r=0;r<4;r++){
      int qg = qw + lh*4 + r;
      out[((size_t)b*SEQ + qg)*DIM + h*64 + df*16 + lr] = f2bf(o[df][r]*inv[r]);
    }
}

// ============================ fused per-layer weight transpose+convert ============================
__global__ __launch_bounds__(256) void k_wtrans4(const float* __restrict__ Wq, const float* __restrict__ Wp,
                                                 const float* __restrict__ W1, const float* __restrict__ W2,
                                                 unsigned short* __restrict__ dq, unsigned short* __restrict__ dp,
                                                 unsigned short* __restrict__ d1, unsigned short* __restrict__ d2){
  int bid = blockIdx.x;
  const float* src; unsigned short* dst; int K, N, local;
  if (bid < 1728)      { src=Wq; dst=dq; K=768;  N=2304; local=bid; }
  else if (bid < 2304) { src=Wp; dst=dp; K=768;  N=768;  local=bid-1728; }
  else if (bid < 4608) { src=W1; dst=d1; K=768;  N=3072; local=bid-2304; }
  else                 { src=W2; dst=d2; K=3072; N=768;  local=bid-4608; }
  int nx = N/32;
  int n0 = (local % nx)*32, k0 = (local / nx)*32;
  __shared__ float tile[32][33];
  int tx = threadIdx.x & 31, ty = threadIdx.x >> 5;
#pragma unroll
  for (int r=0;r<32;r+=8)
    tile[ty+r][tx] = src[(size_t)(k0+ty+r)*N + n0+tx];
  __syncthreads();
#pragma unroll
  for (int r=0;r<32;r+=8)
    dst[(size_t)(n0+ty+r)*K + k0+tx] = f2bf(tile[tx][ty+r]);
}

// ============================ f32 -> bf16 bulk convert (tok_emb) ============================
__global__ void k_cvt(const float* __restrict__ src, unsigned short* __restrict__ dst, int n8){
  int i = blockIdx.x*blockDim.x + threadIdx.x;
  for (; i < n8; i += gridDim.x*blockDim.x){
    float4 f0 = ((const float4*)src)[i*2];
    float4 f1 = ((const float4*)src)[i*2+1];
    u16x8 v;
    v[0]=f2bf(f0.x); v[1]=f2bf(f0.y); v[2]=f2bf(f0.z); v[3]=f2bf(f0.w);
    v[4]=f2bf(f1.x); v[5]=f2bf(f1.y); v[6]=f2bf(f1.z); v[7]=f2bf(f1.w);
    ((u16x8*)dst)[i] = v;
  }
}

// ============================ MFMA bf16 GEMM ============================
// C(MxN) = A(MxK bf16,row) * B^T(NxK bf16,row). ACT 0/1(gelu). OUTBF: bf16 out (per-lane stores).
// f32 out: LDS-band transpose epilogue -> f32x4 stores (NT: nontemporal).
// grid: x = M/BMT (M-fastest), y = ceil(N/BNT); nwg % 8 == 0 required.
template<int ACT, bool OUTBF, int BMT, int BNT, bool NT>
__global__ __launch_bounds__(256) void k_mgemm(const unsigned short* __restrict__ A,
                                               const unsigned short* __restrict__ B,
                                               void* __restrict__ Cout,
                                               int M, int N, int K)
{
  constexpr int MF = BMT/32;            // m-fragments per wave
  constexpr int NF = BNT/32;            // n-fragments per wave
  __shared__ __align__(16) unsigned short Sm[(BMT+BNT)*32];
  unsigned short* As = Sm;
  unsigned short* Bs = Sm + BMT*32;
  const int tid = threadIdx.x;
  const int l = tid & 63, w = tid >> 6;
  const int wr = w >> 1, wc = w & 1;

  const int nwg  = gridDim.x * gridDim.y;
  const int flat = blockIdx.y * gridDim.x + blockIdx.x;
  const int q8   = nwg >> 3;
  const int wk   = (flat & 7) * q8 + (flat >> 3);
  const int bm = (wk % gridDim.x) * BMT;
  const int bn = (wk / gridDim.x) * BNT;

  const int srow = tid >> 2;
  const int scol = (tid & 3) * 8;

  f32x4 acc[MF][NF];
#pragma unroll
  for (int i=0;i<MF;i++)
#pragma unroll
    for (int j=0;j<NF;j++) acc[i][j] = (f32x4){0.f,0.f,0.f,0.f};

  for (int k0 = 0; k0 < K; k0 += 32){
#pragma unroll
    for (int c=0;c<BMT/64;++c){
      const unsigned short* ga = A + (size_t)(bm + c*64 + srow)*K + (k0 + scol);
      __builtin_amdgcn_global_load_lds(
          (const __attribute__((address_space(1))) void*)ga,
          (__attribute__((address_space(3))) void*)(As + c*2048 + w*512),
          16, 0, 0);
    }
#pragma unroll
    for (int c=0;c<BNT/64;++c){
      int gn = bn + c*64 + srow; if (gn >= N) gn = N-1;
      const unsigned short* gb = B + (size_t)gn*K + (k0 + scol);
      __builtin_amdgcn_global_load_lds(
          (const __attribute__((address_space(1))) void*)gb,
          (__attribute__((address_space(3))) void*)(Bs + c*2048 + w*512),
          16, 0, 0);
    }
    __syncthreads();

    bf16x8 af[MF], bfr[NF];
#pragma unroll
    for (int i=0;i<MF;i++)
      af[i]  = *(const bf16x8*)(As + ((wr*(BMT/2) + i*16 + (l&15))*32 + (l>>4)*8));
#pragma unroll
    for (int j=0;j<NF;j++)
      bfr[j] = *(const bf16x8*)(Bs + ((wc*(BNT/2) + j*16 + (l&15))*32 + (l>>4)*8));
#pragma unroll
    for (int mi=0;mi<MF;mi++)
#pragma unroll
      for (int ni=0;ni<NF;ni++)
        acc[mi][ni] = __builtin_amdgcn_mfma_f32_16x16x32_bf16(af[mi], bfr[ni], acc[mi][ni], 0,0,0);
    __syncthreads();
  }

  if constexpr (OUTBF){
#pragma unroll
    for (int mi=0;mi<MF;mi++){
      const int gm0 = bm + wr*(BMT/2) + mi*16 + (l>>4)*4;
#pragma unroll
      for (int ni=0;ni<NF;ni++){
        const int gn = bn + wc*(BNT/2) + ni*16 + (l&15);
        if (gn < N){
#pragma unroll
          for (int r=0;r<4;r++){
            float v = acc[mi][ni][r];
            if constexpr (ACT==1) v = 0.5f*v*(1.f + erff(v*0.70710678118654752f));
            ((unsigned short*)Cout)[(size_t)(gm0+r)*N + gn] = f2bf(v);
          }
        }
      }
    }
  } else {
    // LDS-band transpose epilogue: 16-row bands, f32x4 coalesced stores
    float* band = (float*)Sm;
#pragma unroll
    for (int b=0; b<BMT/16; ++b){
      __syncthreads();
#pragma unroll
      for (int mi=0;mi<MF;mi++){
        if (b == wr*MF + mi){
#pragma unroll
          for (int ni=0;ni<NF;ni++){
#pragma unroll
            for (int r=0;r<4;r++){
              float v = acc[mi][ni][r];
              if constexpr (ACT==1) v = 0.5f*v*(1.f + erff(v*0.70710678118654752f));
              band[((l>>4)*4+r)*BNT + wc*(BNT/2) + ni*16 + (l&15)] = v;
            }
          }
        }
      }
      __syncthreads();
      const int row0 = bm + b*16;
#pragma unroll
      for (int p=0; p<(4*BNT)/256; ++p){
        int f = tid + p*256;
        int row = f/(BNT/4), c4 = f%(BNT/4);
        f32x4 v = *(const f32x4*)&band[row*BNT + c4*4];
        float* cp = (float*)Cout + (size_t)(row0+row)*N + bn + c4*4;
        if (bn + c4*4 + 3 < N){
          if constexpr (NT) __builtin_nontemporal_store(v, (f32x4*)cp);
          else *(f32x4*)cp = v;
        } else {
#pragma unroll
          for (int j=0;j<4;j++) if (bn + c4*4 + j < N) cp[j] = v[j];
        }
      }
    }
  }
}

// ============================ host launch ============================
extern "C" void kernel_launch(void* const* d_in, const int* in_sizes, int n_in,
                              void* d_out, int out_size, void* d_ws, size_t ws_size,
                              hipStream_t stream) {
  const int*   ids   = (const int*)  d_in[0];
  const float* tok   = (const float*)d_in[1];
  const float* pos   = (const float*)d_in[2];
  const float* ln1g  = (const float*)d_in[3];
  const float* ln1b  = (const float*)d_in[4];
  const float* ln2g  = (const float*)d_in[5];
  const float* ln2b  = (const float*)d_in[6];
  const float* Wqkv  = (const float*)d_in[7];
  const float* Wproj = (const float*)d_in[8];
  const float* Wfc1  = (const float*)d_in[9];
  const float* Wfc2  = (const float*)d_in[10];
  const float* mAW   = (const float*)d_in[11];
  const float* mAb   = (const float*)d_in[12];
  const float* mAal  = (const float*)d_in[13];
  const float* mFW   = (const float*)d_in[14];
  const float* mFb   = (const float*)d_in[15];
  const float* mFal  = (const float*)d_in[16];
  const float* lnfg  = (const float*)d_in[17];
  const float* lnfb  = (const float*)d_in[18];
  float* out = (float*)d_out;

  float* ws   = (float*)d_ws;
  float* xA   = ws + O_X;
  float* xB   = ws + O_X2;
  float* tmpF = ws + O_TMP;                                // y f32
  unsigned short* bigBF = (unsigned short*)(ws + O_BIG);   // qkv / fc1-out bf16
  unsigned short* lnbf  = (unsigned short*)(ws + O_LNB);
  unsigned short* t1bf  = (unsigned short*)(ws + O_T1B);
  float* coef = ws + O_COEF;
  unsigned short* wT    = (unsigned short*)(ws + O_WT);
  unsigned short* wqkvT  = wT;
  unsigned short* wprojT = wT + (size_t)2304*768;
  unsigned short* wfc1T  = wprojT + (size_t)768*768;
  unsigned short* wfc2T  = wfc1T + (size_t)3072*768;
  unsigned short* tokbf  = (unsigned short*)(ws + O_X);    // overlays dead buffers at lm_head time
  unsigned short* lnfbf  = (unsigned short*)(ws + O_LNF);

  float* xc = xA; float* xn = xB;
  for (int l=0; l<NLAYER; l++){
    k_wtrans4<<<6912, 256, 0, stream>>>(Wqkv + (size_t)l*DIM*3*DIM, Wproj + (size_t)l*DIM*DIM,
                                        Wfc1 + (size_t)l*DIM*FFDIM, Wfc2 + (size_t)l*FFDIM*DIM,
                                        wqkvT, wprojT, wfc1T, wfc2T);
    // ---- attention sublayer ----
    if (l == 0){
      k_mhc<true><<<NTOK, 256, 0, stream>>>(ids, tok, pos, nullptr, nullptr, xA,
                                            mAW, mAb, mAal, ln1g, ln1b, coef, lnbf);
    } else {
      k_mhc<false><<<NTOK, 256, 0, stream>>>(nullptr, nullptr, nullptr, xc, tmpF, xn,
                                             mAW + (size_t)l*NDIM*NC, mAb + (size_t)l*NC, mAal + l,
                                             ln1g + (size_t)l*DIM, ln1b + (size_t)l*DIM, coef, lnbf);
      { float* tmp = xc; xc = xn; xn = tmp; }
    }
    k_mgemm<0,true ,64,128,false><<<dim3(32, 2304/128), 256, 0, stream>>>(lnbf, wqkvT, (void*)bigBF, NTOK, 2304, 768);
    k_fattn<<<dim3(SEQ/64, NHEAD, BATCH), 256, 0, stream>>>(bigBF, t1bf);
    k_mgemm<0,false,64,64,false><<<dim3(32, 768/64), 256, 0, stream>>>(t1bf, wprojT, tmpF, NTOK, 768, 768);

    // ---- ffn sublayer ----
    k_mhc<false><<<NTOK, 256, 0, stream>>>(nullptr, nullptr, nullptr, xc, tmpF, xn,
                                           mFW + (size_t)l*NDIM*NC, mFb + (size_t)l*NC, mFal + l,
                                           ln2g + (size_t)l*DIM, ln2b + (size_t)l*DIM, coef, lnbf);
    { float* tmp = xc; xc = xn; xn = tmp; }
    k_mgemm<1,true ,64,128,false><<<dim3(32, 3072/128), 256, 0, stream>>>(lnbf, wfc1T, (void*)bigBF, NTOK, 3072, 768);
    k_mgemm<0,false,64,64,false><<<dim3(32, 768/64), 256, 0, stream>>>(bigBF, wfc2T, tmpF, NTOK, 768, 3072);
  }

  // tail: combine-sum + final LN, then lm_head on bf16 tok_emb
  k_csumln<<<NTOK, 256, 0, stream>>>(xc, coef, tmpF, lnfg, lnfb, lnfbf);
  k_cvt<<<2048, 256, 0, stream>>>(tok, tokbf, (VOCAB*DIM)/8);
  k_mgemm<0,false,128,128,true><<<dim3(16, (VOCAB+127)/128), 256, 0, stream>>>(lnfbf, tokbf, out, NTOK, VOCAB, 768);
}

// Round 8
// 1645.213 us; speedup vs baseline: 7.1467x; 1.0510x over previous
//
#include <hip/hip_runtime.h>
#include <math.h>

// ---- problem constants ----
constexpr int BATCH  = 2;
constexpr int SEQ    = 1024;
constexpr int DIM    = 768;
constexpr int NLAYER = 4;
constexpr int NHEAD  = 12;
constexpr int HDIM   = 64;
constexpr int NEXP   = 4;
constexpr int FFDIM  = 3072;
constexpr int VOCAB  = 50257;
constexpr int NDIM   = NEXP * DIM;   // 3072
constexpr int NC     = NEXP*NEXP + 2*NEXP; // 24
constexpr int NTOK   = BATCH * SEQ;  // 2048

using bf16x8 = __attribute__((ext_vector_type(8))) __bf16;
using f32x4  = __attribute__((ext_vector_type(4))) float;
using u16x8  = __attribute__((ext_vector_type(8))) unsigned short;
using u16x4  = __attribute__((ext_vector_type(4))) unsigned short;
using u32x4  = __attribute__((ext_vector_type(4))) unsigned int;

__device__ inline unsigned short f2bf(float f){
  unsigned u = __builtin_bit_cast(unsigned, f);
  u += 0x7fffu + ((u >> 16) & 1u);      // round-to-nearest-even
  return (unsigned short)(u >> 16);
}
__device__ inline bf16x8 as_bf(u16x8 v){ return __builtin_bit_cast(bf16x8, v); }

// ---- workspace layout (float units) ----
constexpr size_t SZ_X   = (size_t)NTOK * NEXP * DIM;   // 6291456
constexpr size_t SZ_T   = (size_t)NTOK * DIM;          // 1572864
constexpr size_t O_X    = 0;
constexpr size_t O_X2   = O_X  + SZ_X;
constexpr size_t O_TMP  = O_X2 + SZ_X;                 // y (f32)
constexpr size_t O_BIG  = O_TMP + SZ_T;                // qkv/fc1-out bf16
constexpr size_t O_LNB  = O_BIG + (size_t)NTOK*2304;
constexpr size_t O_T1B  = O_LNB + SZ_T/2;
constexpr size_t O_COEF = O_T1B + SZ_T/2;
constexpr size_t O_WT   = O_COEF + (size_t)NTOK*NC;
constexpr size_t O_LNF  = 19298688;                    // past tokbf overlay

// ---- wave-level reduce (64 lanes) ----
__device__ inline float wred_sum(float v){
#pragma unroll
  for (int m=32;m>=1;m>>=1) v += __shfl_xor(v,m);
  return v;
}

// ============================ fused mhc: [combine] + coef(sinkhorn) + pre-mix + LN ============================
template<bool FIRST>
__global__ __launch_bounds__(256) void k_mhc(const int* __restrict__ ids,
                                             const float* __restrict__ tokf,
                                             const float* __restrict__ posf,
                                             const float* __restrict__ xin,
                                             const float* __restrict__ y,
                                             float* __restrict__ xout,
                                             const float* __restrict__ W,
                                             const float* __restrict__ bb,
                                             const float* __restrict__ alpha_p,
                                             const float* __restrict__ g,
                                             const float* __restrict__ lnb_,
                                             float* __restrict__ coef,
                                             unsigned short* __restrict__ lnout){
  const int t = blockIdx.x, tid = threadIdx.x;
  const int w = tid >> 6;
  __shared__ float wred[4], w2[4];
  __shared__ float accw[4][NC];
  __shared__ float cfl[NC];

  float xp[3][4];
  float ss = 0.f;

  if constexpr (FIRST){
    const float* te = tokf + (size_t)ids[t]*DIM;
    const float* pe = posf + (size_t)(t % SEQ)*DIM;
#pragma unroll
    for (int k=0;k<3;k++){
      int d = tid + k*256;
      float v = te[d] + pe[d];
#pragma unroll
      for (int n=0;n<4;n++){
        xp[k][n] = v;
        xout[(size_t)t*NDIM + n*DIM + d] = v;
      }
      ss += 4.f*v*v;
    }
  } else {
    float cfp[20];
    const float* cp = coef + (size_t)t*NC;
#pragma unroll
    for (int j=0;j<16;j++) cfp[j] = cp[j];
#pragma unroll
    for (int j=0;j<4;j++) cfp[16+j] = cp[20+j];
    const float* xt = xin + (size_t)t*NDIM;
#pragma unroll
    for (int k=0;k<3;k++){
      int d = tid + k*256;
      float xm[4];
#pragma unroll
      for (int m=0;m<4;m++) xm[m] = xt[m*DIM + d];
      float yv = y[(size_t)t*DIM + d];
#pragma unroll
      for (int n=0;n<4;n++){
        float o = cfp[16+n]*yv;
#pragma unroll
        for (int m=0;m<4;m++) o += cfp[n*4+m]*xm[m];
        xp[k][n] = o;
        xout[(size_t)t*NDIM + n*DIM + d] = o;
        ss += o*o;
      }
    }
  }

  ss = wred_sum(ss);
  float acc[NC];
#pragma unroll
  for (int j=0;j<NC;j++) acc[j]=0.f;
#pragma unroll
  for (int k=0;k<3;k++){
    int d = tid + k*256;
#pragma unroll
    for (int n=0;n<4;n++){
      float v = xp[k][n];
      const float* wr = W + (size_t)(n*DIM + d)*NC;
#pragma unroll
      for (int j=0;j<NC;j++) acc[j] += v*wr[j];
    }
  }
#pragma unroll
  for (int j=0;j<NC;j++){
#pragma unroll
    for (int m=32;m>=1;m>>=1) acc[j] += __shfl_xor(acc[j], m);
  }
  if ((tid&63)==0){
    wred[w] = ss;
#pragma unroll
    for (int j=0;j<NC;j++) accw[w][j] = acc[j];
  }
  __syncthreads();
  float rfac = rsqrtf((wred[0]+wred[1]+wred[2]+wred[3])/(float)NDIM + 1e-6f);

  const float alpha = alpha_p[0];
  float* cfg = coef + (size_t)t*NC;
  if (tid < 16){
    float lmv = (accw[0][tid]+accw[1][tid]+accw[2][tid]+accw[3][tid])*rfac*alpha + bb[tid];
#pragma unroll
    for (int it=0; it<10; ++it){
      float mx = fmaxf(lmv, __shfl_xor(lmv,1)); mx = fmaxf(mx, __shfl_xor(mx,2));
      float se = expf(lmv-mx); se += __shfl_xor(se,1); se += __shfl_xor(se,2);
      lmv -= mx + logf(se);
      mx = fmaxf(lmv, __shfl_xor(lmv,4)); mx = fmaxf(mx, __shfl_xor(mx,8));
      se = expf(lmv-mx); se += __shfl_xor(se,4); se += __shfl_xor(se,8);
      lmv -= mx + logf(se);
    }
    float hm = expf(lmv);
    cfl[tid] = hm;
    cfg[tid] = hm;
  } else if (tid < 24){
    cfl[tid] = (accw[0][tid]+accw[1][tid]+accw[2][tid]+accw[3][tid])*rfac*alpha + bb[tid];
  }
  __syncthreads();
  if (tid == 0){
    float l0=cfl[16], l1=cfl[17], l2=cfl[18], l3=cfl[19];
    float pm = fmaxf(fmaxf(l0,l1),fmaxf(l2,l3));
    float e0=expf(l0-pm), e1=expf(l1-pm), e2=expf(l2-pm), e3=expf(l3-pm);
    float es=e0+e1+e2+e3;
    cfl[16]=e0/es; cfl[17]=e1/es; cfl[18]=e2/es; cfl[19]=e3/es;
#pragma unroll
    for (int j=20;j<24;j++) cfl[j] = 1.f/(1.f+expf(-cfl[j]));
#pragma unroll
    for (int j=16;j<24;j++) cfg[j] = cfl[j];
  }
  __syncthreads();

  float p0=cfl[16], p1=cfl[17], p2=cfl[18], p3=cfl[19];
  float h[3], s1=0.f, s2=0.f;
#pragma unroll
  for (int k=0;k<3;k++){
    float v = p0*xp[k][0] + p1*xp[k][1] + p2*xp[k][2] + p3*xp[k][3];
    h[k]=v; s1+=v; s2+=v*v;
  }
  s1 = wred_sum(s1); s2 = wred_sum(s2);
  if ((tid&63)==0){ wred[w]=s1; w2[w]=s2; }
  __syncthreads();
  float mu  = (wred[0]+wred[1]+wred[2]+wred[3])/(float)DIM;
  float var = (w2[0]+w2[1]+w2[2]+w2[3])/(float)DIM - mu*mu;
  float inv = rsqrtf(var + 1e-5f);
#pragma unroll
  for (int k=0;k<3;k++){
    int d = tid + k*256;
    lnout[(size_t)t*DIM+d] = f2bf((h[k]-mu)*inv*g[d] + lnb_[d]);
  }
}

// ============================ tail: combine-sum + final LN -> bf16 ============================
__global__ __launch_bounds__(256) void k_csumln(const float* __restrict__ xin,
                                                const float* __restrict__ coef,
                                                const float* __restrict__ y,
                                                const float* __restrict__ g,
                                                const float* __restrict__ bb,
                                                unsigned short* __restrict__ out){
  const int t = blockIdx.x, tid = threadIdx.x;
  const int w = tid >> 6;
  const float* cp = coef + (size_t)t*NC;
  float cs[4];
#pragma unroll
  for (int m=0;m<4;m++) cs[m] = cp[m] + cp[4+m] + cp[8+m] + cp[12+m];
  float ps = cp[20]+cp[21]+cp[22]+cp[23];
  const float* xt = xin + (size_t)t*NDIM;
  float h[3], s1=0.f, s2=0.f;
#pragma unroll
  for (int k=0;k<3;k++){
    int d = tid + k*256;
    float v = ps * y[(size_t)t*DIM + d];
#pragma unroll
    for (int m=0;m<4;m++) v += cs[m]*xt[m*DIM + d];
    h[k]=v; s1+=v; s2+=v*v;
  }
  __shared__ float r1[4], r2[4];
  s1 = wred_sum(s1); s2 = wred_sum(s2);
  if ((tid&63)==0){ r1[w]=s1; r2[w]=s2; }
  __syncthreads();
  float mu  = (r1[0]+r1[1]+r1[2]+r1[3])/(float)DIM;
  float var = (r2[0]+r2[1]+r2[2]+r2[3])/(float)DIM - mu*mu;
  float inv = rsqrtf(var + 1e-5f);
#pragma unroll
  for (int k=0;k<3;k++){
    int d = tid + k*256;
    out[(size_t)t*DIM+d] = f2bf((h[k]-mu)*inv*g[d] + bb[d]);
  }
}

// ============================ flash attention (MFMA, swapped QK^T -> S^T) ============================
// S^T = mfma(K, Q): lane (lr,lh) reg r holds S[q=qw+lr][k=k0+kf*16+lh*4+r]
// -> softmax row stats live per-lane (q = qw+lr fixed); reduce over lanes {lr,lr+16,lr+32,lr+48}.
// P packed to bf16 pairs with f2bf (bit-exact RNE), redistributed to the PV A-fragment
// layout (lane needs P[q=qw+lr][k=ks*32+lh*8+j]) via static shfl:
//   owner kf = ks*2 + (lh>>1); owner lane = lr + (lh&1)*32 (+16 for j>=4); r = j&3.
__global__ __launch_bounds__(256) void k_fattn(const unsigned short* __restrict__ qkv,
                                               unsigned short* __restrict__ out){
  const int qb = gridDim.x - 1 - blockIdx.x;   // longest blocks dispatched first
  const int h = blockIdx.y, b = blockIdx.z;
  const int tid = threadIdx.x;
  const int l = tid & 63, w = tid >> 6;
  const int lr = l & 15, lh = l >> 4;
  const int qw = qb*64 + w*16;
  constexpr int LDV = 68;
  __shared__ unsigned short Vt[64*LDV];        // V^T [d][k]

  const unsigned short* base = qkv + (size_t)b*SEQ*2304;

  // Q fragments (B-operand): Q[qw+lr][ks*32+lh*8+j]
  u16x8 qa[2];
  {
    const unsigned short* qp = base + (size_t)(qw + lr)*2304 + h*64 + lh*8;
    qa[0] = *(const u16x8*)qp;
    qa[1] = *(const u16x8*)(qp + 32);
  }

  f32x4 o[4];
#pragma unroll
  for (int df=0; df<4; df++) o[df] = (f32x4){0.f,0.f,0.f,0.f};
  float m_run = -1e30f, l_run = 0.f;
  const int qg = qw + lr;

  const int kTiles = qb + 1;
  for (int t=0; t<kTiles; ++t){
    const int k0 = t*64;
    __syncthreads();
    // ---- stage V^T: pack (V[k][d],V[k+1][d]) pairs -> ds_write_b32 ----
#pragma unroll
    for (int p=0;p<2;p++){
      int idx = p*256 + tid;
      int k  = (idx >> 4) * 2;
      int d0 = (idx & 15) * 4;
      const unsigned short* vp = base + (size_t)(k0+k)*2304 + 1536 + h*64 + d0;
      u16x4 v0 = *(const u16x4*)vp;
      u16x4 v1 = *(const u16x4*)(vp + 2304);
#pragma unroll
      for (int j=0;j<4;j++){
        unsigned pkv = (unsigned)v0[j] | ((unsigned)v1[j] << 16);
        *(unsigned*)&Vt[(d0+j)*LDV + k] = pkv;
      }
    }
    __syncthreads();

    // ---- QK^T swapped: A = K rows, B = Q rows -> S^T ----
    f32x4 s[4];
#pragma unroll
    for (int kf=0;kf<4;kf++) s[kf] = (f32x4){0.f,0.f,0.f,0.f};
#pragma unroll
    for (int ks=0;ks<2;ks++){
#pragma unroll
      for (int kf=0;kf<4;kf++){
        u16x8 kb = *(const u16x8*)(base + (size_t)(k0 + kf*16 + lr)*2304 + 768 + h*64 + ks*32 + lh*8);
        s[kf] = __builtin_amdgcn_mfma_f32_16x16x32_bf16(as_bf(kb), as_bf(qa[ks]), s[kf], 0,0,0);
      }
    }

    // ---- mask + scale: k = k0+kf*16+lh*4+r, q = qg ----
    float sc[4][4];
#pragma unroll
    for (int kf=0;kf<4;kf++){
      int kg0 = k0 + kf*16 + lh*4;
#pragma unroll
      for (int r=0;r<4;r++)
        sc[kf][r] = (kg0 + r <= qg) ? s[kf][r]*0.125f : -1e30f;
    }
    // ---- per-lane row softmax ----
    float mt = sc[0][0];
#pragma unroll
    for (int kf=0;kf<4;kf++)
#pragma unroll
      for (int r=0;r<4;r++) mt = fmaxf(mt, sc[kf][r]);
    mt = fmaxf(mt, __shfl_xor(mt, 16));
    mt = fmaxf(mt, __shfl_xor(mt, 32));
    float mn = fmaxf(m_run, mt);
    float c  = __expf(m_run - mn);
    m_run = mn;
    float p[4][4];
    float rs = 0.f;
#pragma unroll
    for (int kf=0;kf<4;kf++)
#pragma unroll
      for (int r=0;r<4;r++){
        float pv = __expf(sc[kf][r] - mn);
        p[kf][r] = pv;
        rs += pv;
      }
    rs += __shfl_xor(rs, 16);
    rs += __shfl_xor(rs, 32);
    l_run = l_run*c + rs;

    // ---- rescale o (rows q = qw + lh*4 + r; c lives at lane lr = q_local) ----
    float cq[4];
#pragma unroll
    for (int r=0;r<4;r++) cq[r] = __shfl(c, lh*4 + r);
#pragma unroll
    for (int df=0;df<4;df++)
#pragma unroll
      for (int r=0;r<4;r++) o[df][r] *= cq[r];

    // ---- pack P to bf16 pairs (bit-exact f2bf; low short = even r) ----
    unsigned pk[4][2];
#pragma unroll
    for (int kf=0;kf<4;kf++){
      pk[kf][0] = (unsigned)f2bf(p[kf][0]) | ((unsigned)f2bf(p[kf][1]) << 16);
      pk[kf][1] = (unsigned)f2bf(p[kf][2]) | ((unsigned)f2bf(p[kf][3]) << 16);
    }
    // ---- redistribute to PV A-layout ----
    const int srcA = lr + (lh&1)*32;   // owner lh_o = (lh&1)*2
    const int srcB = srcA + 16;        // owner lh_o = (lh&1)*2+1
    const bool hi = (lh>>1)&1;
#pragma unroll
    for (int ks=0;ks<2;ks++){
      unsigned s00 = __shfl(pk[ks*2  ][0], srcA), s01 = __shfl(pk[ks*2  ][1], srcA);
      unsigned s10 = __shfl(pk[ks*2+1][0], srcA), s11 = __shfl(pk[ks*2+1][1], srcA);
      unsigned t00 = __shfl(pk[ks*2  ][0], srcB), t01 = __shfl(pk[ks*2  ][1], srcB);
      unsigned t10 = __shfl(pk[ks*2+1][0], srcB), t11 = __shfl(pk[ks*2+1][1], srcB);
      u32x4 paw;
      paw[0] = hi ? s10 : s00;
      paw[1] = hi ? s11 : s01;
      paw[2] = hi ? t10 : t00;
      paw[3] = hi ? t11 : t01;
      bf16x8 pa = __builtin_bit_cast(bf16x8, paw);
#pragma unroll
      for (int df=0;df<4;df++){
        u16x8 vb = *(const u16x8*)&Vt[(df*16 + lr)*LDV + ks*32 + lh*8];
        o[df] = __builtin_amdgcn_mfma_f32_16x16x32_bf16(pa, as_bf(vb), o[df], 0,0,0);
      }
    }
  }

  // ---- epilogue: o rows q = qw + lh*4 + r ----
  float linv[4];
#pragma unroll
  for (int r=0;r<4;r++) linv[r] = 1.f/__shfl(l_run, lh*4 + r);
#pragma unroll
  for (int df=0;df<4;df++)
#pragma unroll
    for (int r=0;r<4;r++){
      int qrow = qw + lh*4 + r;
      out[((size_t)b*SEQ + qrow)*DIM + h*64 + df*16 + lr] = f2bf(o[df][r]*linv[r]);
    }
}

// ============================ fused per-layer weight transpose+convert ============================
__global__ __launch_bounds__(256) void k_wtrans4(const float* __restrict__ Wq, const float* __restrict__ Wp,
                                                 const float* __restrict__ W1, const float* __restrict__ W2,
                                                 unsigned short* __restrict__ dq, unsigned short* __restrict__ dp,
                                                 unsigned short* __restrict__ d1, unsigned short* __restrict__ d2){
  int bid = blockIdx.x;
  const float* src; unsigned short* dst; int K, N, local;
  if (bid < 1728)      { src=Wq; dst=dq; K=768;  N=2304; local=bid; }
  else if (bid < 2304) { src=Wp; dst=dp; K=768;  N=768;  local=bid-1728; }
  else if (bid < 4608) { src=W1; dst=d1; K=768;  N=3072; local=bid-2304; }
  else                 { src=W2; dst=d2; K=3072; N=768;  local=bid-4608; }
  int nx = N/32;
  int n0 = (local % nx)*32, k0 = (local / nx)*32;
  __shared__ float tile[32][33];
  int tx = threadIdx.x & 31, ty = threadIdx.x >> 5;
#pragma unroll
  for (int r=0;r<32;r+=8)
    tile[ty+r][tx] = src[(size_t)(k0+ty+r)*N + n0+tx];
  __syncthreads();
#pragma unroll
  for (int r=0;r<32;r+=8)
    dst[(size_t)(n0+ty+r)*K + k0+tx] = f2bf(tile[tx][ty+r]);
}

// ============================ f32 -> bf16 bulk convert (tok_emb) ============================
__global__ void k_cvt(const float* __restrict__ src, unsigned short* __restrict__ dst, int n8){
  int i = blockIdx.x*blockDim.x + threadIdx.x;
  for (; i < n8; i += gridDim.x*blockDim.x){
    float4 f0 = ((const float4*)src)[i*2];
    float4 f1 = ((const float4*)src)[i*2+1];
    u16x8 v;
    v[0]=f2bf(f0.x); v[1]=f2bf(f0.y); v[2]=f2bf(f0.z); v[3]=f2bf(f0.w);
    v[4]=f2bf(f1.x); v[5]=f2bf(f1.y); v[6]=f2bf(f1.z); v[7]=f2bf(f1.w);
    ((u16x8*)dst)[i] = v;
  }
}

// ============================ MFMA bf16 GEMM (R6-proven, BK=32) ============================
// C(MxN) = A(MxK bf16,row) * B^T(NxK bf16,row). ACT 0/1(gelu). OUTBF: bf16 out.
// f32 out: LDS-band transpose epilogue -> f32x4 stores (NT: nontemporal).
// grid: x = M/BMT (M-fastest), y = ceil(N/BNT); nwg % 8 == 0 required.
template<int ACT, bool OUTBF, int BMT, int BNT, bool NT>
__global__ __launch_bounds__(256) void k_mgemm(const unsigned short* __restrict__ A,
                                               const unsigned short* __restrict__ B,
                                               void* __restrict__ Cout,
                                               int M, int N, int K)
{
  constexpr int MF = BMT/32;
  constexpr int NF = BNT/32;
  __shared__ __align__(16) unsigned short Sm[(BMT+BNT)*32];
  unsigned short* As = Sm;
  unsigned short* Bs = Sm + BMT*32;
  const int tid = threadIdx.x;
  const int l = tid & 63, w = tid >> 6;
  const int wr = w >> 1, wc = w & 1;

  const int nwg  = gridDim.x * gridDim.y;
  const int flat = blockIdx.y * gridDim.x + blockIdx.x;
  const int q8   = nwg >> 3;
  const int wk   = (flat & 7) * q8 + (flat >> 3);
  const int bm = (wk % gridDim.x) * BMT;
  const int bn = (wk / gridDim.x) * BNT;

  const int srow = tid >> 2;
  const int scol = (tid & 3) * 8;

  f32x4 acc[MF][NF];
#pragma unroll
  for (int i=0;i<MF;i++)
#pragma unroll
    for (int j=0;j<NF;j++) acc[i][j] = (f32x4){0.f,0.f,0.f,0.f};

  for (int k0 = 0; k0 < K; k0 += 32){
#pragma unroll
    for (int c=0;c<BMT/64;++c){
      const unsigned short* ga = A + (size_t)(bm + c*64 + srow)*K + (k0 + scol);
      __builtin_amdgcn_global_load_lds(
          (const __attribute__((address_space(1))) void*)ga,
          (__attribute__((address_space(3))) void*)(As + c*2048 + w*512),
          16, 0, 0);
    }
#pragma unroll
    for (int c=0;c<BNT/64;++c){
      int gn = bn + c*64 + srow; if (gn >= N) gn = N-1;
      const unsigned short* gb = B + (size_t)gn*K + (k0 + scol);
      __builtin_amdgcn_global_load_lds(
          (const __attribute__((address_space(1))) void*)gb,
          (__attribute__((address_space(3))) void*)(Bs + c*2048 + w*512),
          16, 0, 0);
    }
    __syncthreads();

    bf16x8 af[MF], bfr[NF];
#pragma unroll
    for (int i=0;i<MF;i++)
      af[i]  = *(const bf16x8*)(As + ((wr*(BMT/2) + i*16 + (l&15))*32 + (l>>4)*8));
#pragma unroll
    for (int j=0;j<NF;j++)
      bfr[j] = *(const bf16x8*)(Bs + ((wc*(BNT/2) + j*16 + (l&15))*32 + (l>>4)*8));
#pragma unroll
    for (int mi=0;mi<MF;mi++)
#pragma unroll
      for (int ni=0;ni<NF;ni++)
        acc[mi][ni] = __builtin_amdgcn_mfma_f32_16x16x32_bf16(af[mi], bfr[ni], acc[mi][ni], 0,0,0);
    __syncthreads();
  }

  if constexpr (OUTBF){
#pragma unroll
    for (int mi=0;mi<MF;mi++){
      const int gm0 = bm + wr*(BMT/2) + mi*16 + (l>>4)*4;
#pragma unroll
      for (int ni=0;ni<NF;ni++){
        const int gn = bn + wc*(BNT/2) + ni*16 + (l&15);
        if (gn < N){
#pragma unroll
          for (int r=0;r<4;r++){
            float v = acc[mi][ni][r];
            if constexpr (ACT==1) v = 0.5f*v*(1.f + erff(v*0.70710678118654752f));
            ((unsigned short*)Cout)[(size_t)(gm0+r)*N + gn] = f2bf(v);
          }
        }
      }
    }
  } else {
    // LDS-band transpose epilogue: 16-row bands, f32x4 coalesced stores
    float* band = (float*)Sm;
#pragma unroll
    for (int b=0; b<BMT/16; ++b){
      __syncthreads();
#pragma unroll
      for (int mi=0;mi<MF;mi++){
        if (b == wr*MF + mi){
#pragma unroll
          for (int ni=0;ni<NF;ni++){
#pragma unroll
            for (int r=0;r<4;r++){
              float v = acc[mi][ni][r];
              if constexpr (ACT==1) v = 0.5f*v*(1.f + erff(v*0.70710678118654752f));
              band[((l>>4)*4+r)*BNT + wc*(BNT/2) + ni*16 + (l&15)] = v;
            }
          }
        }
      }
      __syncthreads();
      const int row0 = bm + b*16;
#pragma unroll
      for (int p=0; p<(4*BNT)/256; ++p){
        int f = tid + p*256;
        int row = f/(BNT/4), c4 = f%(BNT/4);
        f32x4 v = *(const f32x4*)&band[row*BNT + c4*4];
        float* cp = (float*)Cout + (size_t)(row0+row)*N + bn + c4*4;
        if (bn + c4*4 + 3 < N){
          if constexpr (NT) __builtin_nontemporal_store(v, (f32x4*)cp);
          else *(f32x4*)cp = v;
        } else {
#pragma unroll
          for (int j=0;j<4;j++) if (bn + c4*4 + j < N) cp[j] = v[j];
        }
      }
    }
  }
}

// ============================ host launch ============================
extern "C" void kernel_launch(void* const* d_in, const int* in_sizes, int n_in,
                              void* d_out, int out_size, void* d_ws, size_t ws_size,
                              hipStream_t stream) {
  const int*   ids   = (const int*)  d_in[0];
  const float* tok   = (const float*)d_in[1];
  const float* pos   = (const float*)d_in[2];
  const float* ln1g  = (const float*)d_in[3];
  const float* ln1b  = (const float*)d_in[4];
  const float* ln2g  = (const float*)d_in[5];
  const float* ln2b  = (const float*)d_in[6];
  const float* Wqkv  = (const float*)d_in[7];
  const float* Wproj = (const float*)d_in[8];
  const float* Wfc1  = (const float*)d_in[9];
  const float* Wfc2  = (const float*)d_in[10];
  const float* mAW   = (const float*)d_in[11];
  const float* mAb   = (const float*)d_in[12];
  const float* mAal  = (const float*)d_in[13];
  const float* mFW   = (const float*)d_in[14];
  const float* mFb   = (const float*)d_in[15];
  const float* mFal  = (const float*)d_in[16];
  const float* lnfg  = (const float*)d_in[17];
  const float* lnfb  = (const float*)d_in[18];
  float* out = (float*)d_out;

  float* ws   = (float*)d_ws;
  float* xA   = ws + O_X;
  float* xB   = ws + O_X2;
  float* tmpF = ws + O_TMP;                                // y f32
  unsigned short* bigBF = (unsigned short*)(ws + O_BIG);   // qkv / fc1-out bf16
  unsigned short* lnbf  = (unsigned short*)(ws + O_LNB);
  unsigned short* t1bf  = (unsigned short*)(ws + O_T1B);
  float* coef = ws + O_COEF;
  unsigned short* wT    = (unsigned short*)(ws + O_WT);
  unsigned short* wqkvT  = wT;
  unsigned short* wprojT = wT + (size_t)2304*768;
  unsigned short* wfc1T  = wprojT + (size_t)768*768;
  unsigned short* wfc2T  = wfc1T + (size_t)3072*768;
  unsigned short* tokbf  = (unsigned short*)(ws + O_X);    // overlays dead buffers at lm_head time
  unsigned short* lnfbf  = (unsigned short*)(ws + O_LNF);

  float* xc = xA; float* xn = xB;
  for (int l=0; l<NLAYER; l++){
    k_wtrans4<<<6912, 256, 0, stream>>>(Wqkv + (size_t)l*DIM*3*DIM, Wproj + (size_t)l*DIM*DIM,
                                        Wfc1 + (size_t)l*DIM*FFDIM, Wfc2 + (size_t)l*FFDIM*DIM,
                                        wqkvT, wprojT, wfc1T, wfc2T);
    // ---- attention sublayer ----
    if (l == 0){
      k_mhc<true><<<NTOK, 256, 0, stream>>>(ids, tok, pos, nullptr, nullptr, xA,
                                            mAW, mAb, mAal, ln1g, ln1b, coef, lnbf);
    } else {
      k_mhc<false><<<NTOK, 256, 0, stream>>>(nullptr, nullptr, nullptr, xc, tmpF, xn,
                                             mAW + (size_t)l*NDIM*NC, mAb + (size_t)l*NC, mAal + l,
                                             ln1g + (size_t)l*DIM, ln1b + (size_t)l*DIM, coef, lnbf);
      { float* tmp = xc; xc = xn; xn = tmp; }
    }
    k_mgemm<0,true ,64,128,false><<<dim3(32, 2304/128), 256, 0, stream>>>(lnbf, wqkvT, (void*)bigBF, NTOK, 2304, 768);
    k_fattn<<<dim3(SEQ/64, NHEAD, BATCH), 256, 0, stream>>>(bigBF, t1bf);
    k_mgemm<0,false,64,64,false><<<dim3(32, 768/64), 256, 0, stream>>>(t1bf, wprojT, tmpF, NTOK, 768, 768);

    // ---- ffn sublayer ----
    k_mhc<false><<<NTOK, 256, 0, stream>>>(nullptr, nullptr, nullptr, xc, tmpF, xn,
                                           mFW + (size_t)l*NDIM*NC, mFb + (size_t)l*NC, mFal + l,
                                           ln2g + (size_t)l*DIM, ln2b + (size_t)l*DIM, coef, lnbf);
    { float* tmp = xc; xc = xn; xn = tmp; }
    k_mgemm<1,true ,64,128,false><<<dim3(32, 3072/128), 256, 0, stream>>>(lnbf, wfc1T, (void*)bigBF, NTOK, 3072, 768);
    k_mgemm<0,false,64,64,false><<<dim3(32, 768/64), 256, 0, stream>>>(bigBF, wfc2T, tmpF, NTOK, 768, 3072);
  }

  // tail: combine-sum + final LN, then lm_head on bf16 tok_emb
  k_csumln<<<NTOK, 256, 0, stream>>>(xc, coef, tmpF, lnfg, lnfb, lnfbf);
  k_cvt<<<2048, 256, 0, stream>>>(tok, tokbf, (VOCAB*DIM)/8);
  k_mgemm<0,false,128,128,true><<<dim3(16, (VOCAB+127)/128), 256, 0, stream>>>(lnfbf, tokbf, out, NTOK, VOCAB, 768);
}

// Round 11
// 1611.402 us; speedup vs baseline: 7.2967x; 1.0210x over previous
//
#include <hip/hip_runtime.h>
#include <math.h>

// ---- problem constants ----
constexpr int BATCH  = 2;
constexpr int SEQ    = 1024;
constexpr int DIM    = 768;
constexpr int NLAYER = 4;
constexpr int NHEAD  = 12;
constexpr int HDIM   = 64;
constexpr int NEXP   = 4;
constexpr int FFDIM  = 3072;
constexpr int VOCAB  = 50257;
constexpr int NDIM   = NEXP * DIM;   // 3072
constexpr int NC     = NEXP*NEXP + 2*NEXP; // 24
constexpr int NTOK   = BATCH * SEQ;  // 2048

using bf16x8 = __attribute__((ext_vector_type(8))) __bf16;
using f32x4  = __attribute__((ext_vector_type(4))) float;
using u16x8  = __attribute__((ext_vector_type(8))) unsigned short;
using u16x4  = __attribute__((ext_vector_type(4))) unsigned short;
using u32x4  = __attribute__((ext_vector_type(4))) unsigned int;

__device__ inline unsigned short f2bf(float f){
  unsigned u = __builtin_bit_cast(unsigned, f);
  u += 0x7fffu + ((u >> 16) & 1u);      // round-to-nearest-even
  return (unsigned short)(u >> 16);
}
__device__ inline float bf2f(unsigned short v){
  return __builtin_bit_cast(float, ((unsigned)v) << 16);
}
__device__ inline bf16x8 as_bf(u16x8 v){ return __builtin_bit_cast(bf16x8, v); }

// ---- workspace layout (float units) — R8 layout ----
constexpr size_t SZ_X   = (size_t)NTOK * NEXP * DIM;   // 6291456
constexpr size_t SZ_T   = (size_t)NTOK * DIM;          // 1572864
constexpr size_t O_X    = 0;
constexpr size_t O_X2   = O_X  + SZ_X;
constexpr size_t O_TMP  = O_X2 + SZ_X;                 // y bf16 (u16 SZ_T)
constexpr size_t O_BIG  = O_TMP + SZ_T;                // qkv/fc1-out bf16
constexpr size_t O_LNB  = O_BIG + (size_t)NTOK*2304;
constexpr size_t O_T1B  = O_LNB + SZ_T/2;
constexpr size_t O_COEF = O_T1B + SZ_T/2;
constexpr size_t O_WT   = O_COEF + (size_t)NTOK*NC;    // per-layer bf16 weights (R8)
// tokbf overlays floats [0 .. 19298688) (dead at lm_head time)
constexpr size_t O_LNF  = 19298688;                    // final-LN bf16 (786432 f)

// ---- wave-level reduce (64 lanes) ----
__device__ inline float wred_sum(float v){
#pragma unroll
  for (int m=32;m>=1;m>>=1) v += __shfl_xor(v,m);
  return v;
}

// ============================ fused mhc: [combine] + coef(sinkhorn) + pre-mix + LN ============================
template<bool FIRST>
__global__ __launch_bounds__(256) void k_mhc(const int* __restrict__ ids,
                                             const float* __restrict__ tokf,
                                             const float* __restrict__ posf,
                                             const float* __restrict__ xin,
                                             const unsigned short* __restrict__ y,
                                             float* __restrict__ xout,
                                             const float* __restrict__ W,
                                             const float* __restrict__ bb,
                                             const float* __restrict__ alpha_p,
                                             const float* __restrict__ g,
                                             const float* __restrict__ lnb_,
                                             float* __restrict__ coef,
                                             unsigned short* __restrict__ lnout){
  const int t = blockIdx.x, tid = threadIdx.x;
  const int w = tid >> 6;
  __shared__ float wred[4], w2[4];
  __shared__ float accw[4][NC];
  __shared__ float cfl[NC];

  float xp[3][4];
  float ss = 0.f;

  if constexpr (FIRST){
    const float* te = tokf + (size_t)ids[t]*DIM;
    const float* pe = posf + (size_t)(t % SEQ)*DIM;
#pragma unroll
    for (int k=0;k<3;k++){
      int d = tid + k*256;
      float v = te[d] + pe[d];
#pragma unroll
      for (int n=0;n<4;n++){
        xp[k][n] = v;
        xout[(size_t)t*NDIM + n*DIM + d] = v;
      }
      ss += 4.f*v*v;
    }
  } else {
    float cfp[20];
    const float* cp = coef + (size_t)t*NC;
#pragma unroll
    for (int j=0;j<16;j++) cfp[j] = cp[j];
#pragma unroll
    for (int j=0;j<4;j++) cfp[16+j] = cp[20+j];
    const float* xt = xin + (size_t)t*NDIM;
#pragma unroll
    for (int k=0;k<3;k++){
      int d = tid + k*256;
      float xm[4];
#pragma unroll
      for (int m=0;m<4;m++) xm[m] = xt[m*DIM + d];
      float yv = bf2f(y[(size_t)t*DIM + d]);
#pragma unroll
      for (int n=0;n<4;n++){
        float o = cfp[16+n]*yv;
#pragma unroll
        for (int m=0;m<4;m++) o += cfp[n*4+m]*xm[m];
        xp[k][n] = o;
        xout[(size_t)t*NDIM + n*DIM + d] = o;
        ss += o*o;
      }
    }
  }

  ss = wred_sum(ss);
  float acc[NC];
#pragma unroll
  for (int j=0;j<NC;j++) acc[j]=0.f;
#pragma unroll
  for (int k=0;k<3;k++){
    int d = tid + k*256;
#pragma unroll
    for (int n=0;n<4;n++){
      float v = xp[k][n];
      const float* wr = W + (size_t)(n*DIM + d)*NC;
#pragma unroll
      for (int j=0;j<NC;j++) acc[j] += v*wr[j];
    }
  }
#pragma unroll
  for (int j=0;j<NC;j++){
#pragma unroll
    for (int m=32;m>=1;m>>=1) acc[j] += __shfl_xor(acc[j], m);
  }
  if ((tid&63)==0){
    wred[w] = ss;
#pragma unroll
    for (int j=0;j<NC;j++) accw[w][j] = acc[j];
  }
  __syncthreads();
  float rfac = rsqrtf((wred[0]+wred[1]+wred[2]+wred[3])/(float)NDIM + 1e-6f);

  const float alpha = alpha_p[0];
  float* cfg = coef + (size_t)t*NC;
  if (tid < 16){
    float lmv = (accw[0][tid]+accw[1][tid]+accw[2][tid]+accw[3][tid])*rfac*alpha + bb[tid];
#pragma unroll
    for (int it=0; it<10; ++it){
      float mx = fmaxf(lmv, __shfl_xor(lmv,1)); mx = fmaxf(mx, __shfl_xor(mx,2));
      float se = expf(lmv-mx); se += __shfl_xor(se,1); se += __shfl_xor(se,2);
      lmv -= mx + logf(se);
      mx = fmaxf(lmv, __shfl_xor(lmv,4)); mx = fmaxf(mx, __shfl_xor(mx,8));
      se = expf(lmv-mx); se += __shfl_xor(se,4); se += __shfl_xor(se,8);
      lmv -= mx + logf(se);
    }
    float hm = expf(lmv);
    cfl[tid] = hm;
    cfg[tid] = hm;
  } else if (tid < 24){
    cfl[tid] = (accw[0][tid]+accw[1][tid]+accw[2][tid]+accw[3][tid])*rfac*alpha + bb[tid];
  }
  __syncthreads();
  if (tid == 0){
    float l0=cfl[16], l1=cfl[17], l2=cfl[18], l3=cfl[19];
    float pm = fmaxf(fmaxf(l0,l1),fmaxf(l2,l3));
    float e0=expf(l0-pm), e1=expf(l1-pm), e2=expf(l2-pm), e3=expf(l3-pm);
    float es=e0+e1+e2+e3;
    cfl[16]=e0/es; cfl[17]=e1/es; cfl[18]=e2/es; cfl[19]=e3/es;
#pragma unroll
    for (int j=20;j<24;j++) cfl[j] = 1.f/(1.f+expf(-cfl[j]));
#pragma unroll
    for (int j=16;j<24;j++) cfg[j] = cfl[j];
  }
  __syncthreads();

  float p0=cfl[16], p1=cfl[17], p2=cfl[18], p3=cfl[19];
  float h[3], s1=0.f, s2=0.f;
#pragma unroll
  for (int k=0;k<3;k++){
    float v = p0*xp[k][0] + p1*xp[k][1] + p2*xp[k][2] + p3*xp[k][3];
    h[k]=v; s1+=v; s2+=v*v;
  }
  s1 = wred_sum(s1); s2 = wred_sum(s2);
  if ((tid&63)==0){ wred[w]=s1; w2[w]=s2; }
  __syncthreads();
  float mu  = (wred[0]+wred[1]+wred[2]+wred[3])/(float)DIM;
  float var = (w2[0]+w2[1]+w2[2]+w2[3])/(float)DIM - mu*mu;
  float inv = rsqrtf(var + 1e-5f);
#pragma unroll
  for (int k=0;k<3;k++){
    int d = tid + k*256;
    lnout[(size_t)t*DIM+d] = f2bf((h[k]-mu)*inv*g[d] + lnb_[d]);
  }
}

// ============================ tail: combine-sum + final LN -> bf16 ============================
__global__ __launch_bounds__(256) void k_csumln(const float* __restrict__ xin,
                                                const float* __restrict__ coef,
                                                const unsigned short* __restrict__ y,
                                                const float* __restrict__ g,
                                                const float* __restrict__ bb,
                                                unsigned short* __restrict__ out){
  const int t = blockIdx.x, tid = threadIdx.x;
  const int w = tid >> 6;
  const float* cp = coef + (size_t)t*NC;
  float cs[4];
#pragma unroll
  for (int m=0;m<4;m++) cs[m] = cp[m] + cp[4+m] + cp[8+m] + cp[12+m];
  float ps = cp[20]+cp[21]+cp[22]+cp[23];
  const float* xt = xin + (size_t)t*NDIM;
  float h[3], s1=0.f, s2=0.f;
#pragma unroll
  for (int k=0;k<3;k++){
    int d = tid + k*256;
    float v = ps * bf2f(y[(size_t)t*DIM + d]);
#pragma unroll
    for (int m=0;m<4;m++) v += cs[m]*xt[m*DIM + d];
    h[k]=v; s1+=v; s2+=v*v;
  }
  __shared__ float r1[4], r2[4];
  s1 = wred_sum(s1); s2 = wred_sum(s2);
  if ((tid&63)==0){ r1[w]=s1; r2[w]=s2; }
  __syncthreads();
  float mu  = (r1[0]+r1[1]+r1[2]+r1[3])/(float)DIM;
  float var = (r2[0]+r2[1]+r2[2]+r2[3])/(float)DIM - mu*mu;
  float inv = rsqrtf(var + 1e-5f);
#pragma unroll
  for (int k=0;k<3;k++){
    int d = tid + k*256;
    out[(size_t)t*DIM+d] = f2bf((h[k]-mu)*inv*g[d] + bb[d]);
  }
}

// ============================ flash attention (MFMA, swapped QK^T -> S^T) — R8-proven ============================
__global__ __launch_bounds__(256) void k_fattn(const unsigned short* __restrict__ qkv,
                                               unsigned short* __restrict__ out){
  const int qb = gridDim.x - 1 - blockIdx.x;   // longest blocks dispatched first
  const int h = blockIdx.y, b = blockIdx.z;
  const int tid = threadIdx.x;
  const int l = tid & 63, w = tid >> 6;
  const int lr = l & 15, lh = l >> 4;
  const int qw = qb*64 + w*16;
  constexpr int LDV = 68;
  __shared__ unsigned short Vt[64*LDV];        // V^T [d][k]

  const unsigned short* base = qkv + (size_t)b*SEQ*2304;

  u16x8 qa[2];
  {
    const unsigned short* qp = base + (size_t)(qw + lr)*2304 + h*64 + lh*8;
    qa[0] = *(const u16x8*)qp;
    qa[1] = *(const u16x8*)(qp + 32);
  }

  f32x4 o[4];
#pragma unroll
  for (int df=0; df<4; df++) o[df] = (f32x4){0.f,0.f,0.f,0.f};
  float m_run = -1e30f, l_run = 0.f;
  const int qg = qw + lr;

  const int kTiles = qb + 1;
  for (int t=0; t<kTiles; ++t){
    const int k0 = t*64;
    __syncthreads();
#pragma unroll
    for (int p=0;p<2;p++){
      int idx = p*256 + tid;
      int k  = (idx >> 4) * 2;
      int d0 = (idx & 15) * 4;
      const unsigned short* vp = base + (size_t)(k0+k)*2304 + 1536 + h*64 + d0;
      u16x4 v0 = *(const u16x4*)vp;
      u16x4 v1 = *(const u16x4*)(vp + 2304);
#pragma unroll
      for (int j=0;j<4;j++){
        unsigned pkv = (unsigned)v0[j] | ((unsigned)v1[j] << 16);
        *(unsigned*)&Vt[(d0+j)*LDV + k] = pkv;
      }
    }
    __syncthreads();

    f32x4 s[4];
#pragma unroll
    for (int kf=0;kf<4;kf++) s[kf] = (f32x4){0.f,0.f,0.f,0.f};
#pragma unroll
    for (int ks=0;ks<2;ks++){
#pragma unroll
      for (int kf=0;kf<4;kf++){
        u16x8 kb = *(const u16x8*)(base + (size_t)(k0 + kf*16 + lr)*2304 + 768 + h*64 + ks*32 + lh*8);
        s[kf] = __builtin_amdgcn_mfma_f32_16x16x32_bf16(as_bf(kb), as_bf(qa[ks]), s[kf], 0,0,0);
      }
    }

    float sc[4][4];
#pragma unroll
    for (int kf=0;kf<4;kf++){
      int kg0 = k0 + kf*16 + lh*4;
#pragma unroll
      for (int r=0;r<4;r++)
        sc[kf][r] = (kg0 + r <= qg) ? s[kf][r]*0.125f : -1e30f;
    }
    float mt = sc[0][0];
#pragma unroll
    for (int kf=0;kf<4;kf++)
#pragma unroll
      for (int r=0;r<4;r++) mt = fmaxf(mt, sc[kf][r]);
    mt = fmaxf(mt, __shfl_xor(mt, 16));
    mt = fmaxf(mt, __shfl_xor(mt, 32));
    float mn = fmaxf(m_run, mt);
    float c  = __expf(m_run - mn);
    m_run = mn;
    float p[4][4];
    float rs = 0.f;
#pragma unroll
    for (int kf=0;kf<4;kf++)
#pragma unroll
      for (int r=0;r<4;r++){
        float pv = __expf(sc[kf][r] - mn);
        p[kf][r] = pv;
        rs += pv;
      }
    rs += __shfl_xor(rs, 16);
    rs += __shfl_xor(rs, 32);
    l_run = l_run*c + rs;

    float cq[4];
#pragma unroll
    for (int r=0;r<4;r++) cq[r] = __shfl(c, lh*4 + r);
#pragma unroll
    for (int df=0;df<4;df++)
#pragma unroll
      for (int r=0;r<4;r++) o[df][r] *= cq[r];

    unsigned pk[4][2];
#pragma unroll
    for (int kf=0;kf<4;kf++){
      pk[kf][0] = (unsigned)f2bf(p[kf][0]) | ((unsigned)f2bf(p[kf][1]) << 16);
      pk[kf][1] = (unsigned)f2bf(p[kf][2]) | ((unsigned)f2bf(p[kf][3]) << 16);
    }
    const int srcA = lr + (lh&1)*32;
    const int srcB = srcA + 16;
    const bool hi = (lh>>1)&1;
#pragma unroll
    for (int ks=0;ks<2;ks++){
      unsigned s00 = __shfl(pk[ks*2  ][0], srcA), s01 = __shfl(pk[ks*2  ][1], srcA);
      unsigned s10 = __shfl(pk[ks*2+1][0], srcA), s11 = __shfl(pk[ks*2+1][1], srcA);
      unsigned t00 = __shfl(pk[ks*2  ][0], srcB), t01 = __shfl(pk[ks*2  ][1], srcB);
      unsigned t10 = __shfl(pk[ks*2+1][0], srcB), t11 = __shfl(pk[ks*2+1][1], srcB);
      u32x4 paw;
      paw[0] = hi ? s10 : s00;
      paw[1] = hi ? s11 : s01;
      paw[2] = hi ? t10 : t00;
      paw[3] = hi ? t11 : t01;
      bf16x8 pa = __builtin_bit_cast(bf16x8, paw);
#pragma unroll
      for (int df=0;df<4;df++){
        u16x8 vb = *(const u16x8*)&Vt[(df*16 + lr)*LDV + ks*32 + lh*8];
        o[df] = __builtin_amdgcn_mfma_f32_16x16x32_bf16(pa, as_bf(vb), o[df], 0,0,0);
      }
    }
  }

  float linv[4];
#pragma unroll
  for (int r=0;r<4;r++) linv[r] = 1.f/__shfl(l_run, lh*4 + r);
#pragma unroll
  for (int df=0;df<4;df++)
#pragma unroll
    for (int r=0;r<4;r++){
      int qrow = qw + lh*4 + r;
      out[((size_t)b*SEQ + qrow)*DIM + h*64 + df*16 + lr] = f2bf(o[df][r]*linv[r]);
    }
}

// ============================ fused per-layer weight transpose+convert (R8-proven) ============================
__global__ __launch_bounds__(256) void k_wtrans4(const float* __restrict__ Wq, const float* __restrict__ Wp,
                                                 const float* __restrict__ W1, const float* __restrict__ W2,
                                                 unsigned short* __restrict__ dq, unsigned short* __restrict__ dp,
                                                 unsigned short* __restrict__ d1, unsigned short* __restrict__ d2){
  int bid = blockIdx.x;
  const float* src; unsigned short* dst; int K, N, local;
  if (bid < 1728)      { src=Wq; dst=dq; K=768;  N=2304; local=bid; }
  else if (bid < 2304) { src=Wp; dst=dp; K=768;  N=768;  local=bid-1728; }
  else if (bid < 4608) { src=W1; dst=d1; K=768;  N=3072; local=bid-2304; }
  else                 { src=W2; dst=d2; K=3072; N=768;  local=bid-4608; }
  int nx = N/32;
  int n0 = (local % nx)*32, k0 = (local / nx)*32;
  __shared__ float tile[32][33];
  int tx = threadIdx.x & 31, ty = threadIdx.x >> 5;
#pragma unroll
  for (int r=0;r<32;r+=8)
    tile[ty+r][tx] = src[(size_t)(k0+ty+r)*N + n0+tx];
  __syncthreads();
#pragma unroll
  for (int r=0;r<32;r+=8)
    dst[(size_t)(n0+ty+r)*K + k0+tx] = f2bf(tile[tx][ty+r]);
}

// ============================ f32 -> bf16 bulk convert (tok_emb) ============================
__global__ void k_cvt(const float* __restrict__ src, unsigned short* __restrict__ dst, int n8){
  int i = blockIdx.x*blockDim.x + threadIdx.x;
  for (; i < n8; i += gridDim.x*blockDim.x){
    float4 f0 = ((const float4*)src)[i*2];
    float4 f1 = ((const float4*)src)[i*2+1];
    u16x8 v;
    v[0]=f2bf(f0.x); v[1]=f2bf(f0.y); v[2]=f2bf(f0.z); v[3]=f2bf(f0.w);
    v[4]=f2bf(f1.x); v[5]=f2bf(f1.y); v[6]=f2bf(f1.z); v[7]=f2bf(f1.w);
    ((u16x8*)dst)[i] = v;
  }
}

// ============================ MFMA bf16 GEMM (R8-proven, BK=32) ============================
// C(MxN) = A(MxK bf16,row) * B^T(NxK bf16,row). ACT 0/1(gelu). OUTBF: bf16 out.
// f32 out: LDS-band transpose epilogue -> f32x4 stores (NT: nontemporal).
// grid: x = M/BMT (M-fastest), y = ceil(N/BNT); nwg % 8 == 0 required.
template<int ACT, bool OUTBF, int BMT, int BNT, bool NT>
__global__ __launch_bounds__(256) void k_mgemm(const unsigned short* __restrict__ A,
                                               const unsigned short* __restrict__ B,
                                               void* __restrict__ Cout,
                                               int M, int N, int K)
{
  constexpr int MF = BMT/32;
  constexpr int NF = BNT/32;
  __shared__ __align__(16) unsigned short Sm[(BMT+BNT)*32];
  unsigned short* As = Sm;
  unsigned short* Bs = Sm + BMT*32;
  const int tid = threadIdx.x;
  const int l = tid & 63, w = tid >> 6;
  const int wr = w >> 1, wc = w & 1;

  const int nwg  = gridDim.x * gridDim.y;
  const int flat = blockIdx.y * gridDim.x + blockIdx.x;
  const int q8   = nwg >> 3;
  const int wk   = (flat & 7) * q8 + (flat >> 3);
  const int bm = (wk % gridDim.x) * BMT;
  const int bn = (wk / gridDim.x) * BNT;

  const int srow = tid >> 2;
  const int scol = (tid & 3) * 8;

  f32x4 acc[MF][NF];
#pragma unroll
  for (int i=0;i<MF;i++)
#pragma unroll
    for (int j=0;j<NF;j++) acc[i][j] = (f32x4){0.f,0.f,0.f,0.f};

  for (int k0 = 0; k0 < K; k0 += 32){
#pragma unroll
    for (int c=0;c<BMT/64;++c){
      const unsigned short* ga = A + (size_t)(bm + c*64 + srow)*K + (k0 + scol);
      __builtin_amdgcn_global_load_lds(
          (const __attribute__((address_space(1))) void*)ga,
          (__attribute__((address_space(3))) void*)(As + c*2048 + w*512),
          16, 0, 0);
    }
#pragma unroll
    for (int c=0;c<BNT/64;++c){
      int gn = bn + c*64 + srow; if (gn >= N) gn = N-1;
      const unsigned short* gb = B + (size_t)gn*K + (k0 + scol);
      __builtin_amdgcn_global_load_lds(
          (const __attribute__((address_space(1))) void*)gb,
          (__attribute__((address_space(3))) void*)(Bs + c*2048 + w*512),
          16, 0, 0);
    }
    __syncthreads();

    bf16x8 af[MF], bfr[NF];
#pragma unroll
    for (int i=0;i<MF;i++)
      af[i]  = *(const bf16x8*)(As + ((wr*(BMT/2) + i*16 + (l&15))*32 + (l>>4)*8));
#pragma unroll
    for (int j=0;j<NF;j++)
      bfr[j] = *(const bf16x8*)(Bs + ((wc*(BNT/2) + j*16 + (l&15))*32 + (l>>4)*8));
#pragma unroll
    for (int mi=0;mi<MF;mi++)
#pragma unroll
      for (int ni=0;ni<NF;ni++)
        acc[mi][ni] = __builtin_amdgcn_mfma_f32_16x16x32_bf16(af[mi], bfr[ni], acc[mi][ni], 0,0,0);
    __syncthreads();
  }

  if constexpr (OUTBF){
#pragma unroll
    for (int mi=0;mi<MF;mi++){
      const int gm0 = bm + wr*(BMT/2) + mi*16 + (l>>4)*4;
#pragma unroll
      for (int ni=0;ni<NF;ni++){
        const int gn = bn + wc*(BNT/2) + ni*16 + (l&15);
        if (gn < N){
#pragma unroll
          for (int r=0;r<4;r++){
            float v = acc[mi][ni][r];
            if constexpr (ACT==1) v = 0.5f*v*(1.f + erff(v*0.70710678118654752f));
            ((unsigned short*)Cout)[(size_t)(gm0+r)*N + gn] = f2bf(v);
          }
        }
      }
    }
  } else {
    // LDS-band transpose epilogue: 16-row bands, f32x4 coalesced stores
    float* band = (float*)Sm;
#pragma unroll
    for (int b=0; b<BMT/16; ++b){
      __syncthreads();
#pragma unroll
      for (int mi=0;mi<MF;mi++){
        if (b == wr*MF + mi){
#pragma unroll
          for (int ni=0;ni<NF;ni++){
#pragma unroll
            for (int r=0;r<4;r++){
              float v = acc[mi][ni][r];
              if constexpr (ACT==1) v = 0.5f*v*(1.f + erff(v*0.70710678118654752f));
              band[((l>>4)*4+r)*BNT + wc*(BNT/2) + ni*16 + (l&15)] = v;
            }
          }
        }
      }
      __syncthreads();
      const int row0 = bm + b*16;
#pragma unroll
      for (int p=0; p<(4*BNT)/256; ++p){
        int f = tid + p*256;
        int row = f/(BNT/4), c4 = f%(BNT/4);
        f32x4 v = *(const f32x4*)&band[row*BNT + c4*4];
        float* cp = (float*)Cout + (size_t)(row0+row)*N + bn + c4*4;
        if (bn + c4*4 + 3 < N){
          if constexpr (NT) __builtin_nontemporal_store(v, (f32x4*)cp);
          else *(f32x4*)cp = v;
        } else {
#pragma unroll
          for (int j=0;j<4;j++) if (bn + c4*4 + j < N) cp[j] = v[j];
        }
      }
    }
  }
}

// ============================ host launch ============================
extern "C" void kernel_launch(void* const* d_in, const int* in_sizes, int n_in,
                              void* d_out, int out_size, void* d_ws, size_t ws_size,
                              hipStream_t stream) {
  const int*   ids   = (const int*)  d_in[0];
  const float* tok   = (const float*)d_in[1];
  const float* pos   = (const float*)d_in[2];
  const float* ln1g  = (const float*)d_in[3];
  const float* ln1b  = (const float*)d_in[4];
  const float* ln2g  = (const float*)d_in[5];
  const float* ln2b  = (const float*)d_in[6];
  const float* Wqkv  = (const float*)d_in[7];
  const float* Wproj = (const float*)d_in[8];
  const float* Wfc1  = (const float*)d_in[9];
  const float* Wfc2  = (const float*)d_in[10];
  const float* mAW   = (const float*)d_in[11];
  const float* mAb   = (const float*)d_in[12];
  const float* mAal  = (const float*)d_in[13];
  const float* mFW   = (const float*)d_in[14];
  const float* mFb   = (const float*)d_in[15];
  const float* mFal  = (const float*)d_in[16];
  const float* lnfg  = (const float*)d_in[17];
  const float* lnfb  = (const float*)d_in[18];
  float* out = (float*)d_out;

  float* ws   = (float*)d_ws;
  float* xA   = ws + O_X;
  float* xB   = ws + O_X2;
  unsigned short* ybf   = (unsigned short*)(ws + O_TMP);   // y bf16
  unsigned short* bigBF = (unsigned short*)(ws + O_BIG);   // qkv / fc1-out bf16
  unsigned short* lnbf  = (unsigned short*)(ws + O_LNB);
  unsigned short* t1bf  = (unsigned short*)(ws + O_T1B);
  float* coef = ws + O_COEF;
  unsigned short* wT    = (unsigned short*)(ws + O_WT);
  unsigned short* wqkvT  = wT;
  unsigned short* wprojT = wT + (size_t)2304*768;
  unsigned short* wfc1T  = wprojT + (size_t)768*768;
  unsigned short* wfc2T  = wfc1T + (size_t)3072*768;
  unsigned short* tokbf  = (unsigned short*)(ws + O_X);    // overlays dead buffers at lm_head time
  unsigned short* lnfbf  = (unsigned short*)(ws + O_LNF);

  float* xc = xA; float* xn = xB;
  for (int l=0; l<NLAYER; l++){
    k_wtrans4<<<6912, 256, 0, stream>>>(Wqkv + (size_t)l*DIM*3*DIM, Wproj + (size_t)l*DIM*DIM,
                                        Wfc1 + (size_t)l*DIM*FFDIM, Wfc2 + (size_t)l*FFDIM*DIM,
                                        wqkvT, wprojT, wfc1T, wfc2T);
    // ---- attention sublayer ----
    if (l == 0){
      k_mhc<true><<<NTOK, 256, 0, stream>>>(ids, tok, pos, nullptr, nullptr, xA,
                                            mAW, mAb, mAal, ln1g, ln1b, coef, lnbf);
    } else {
      k_mhc<false><<<NTOK, 256, 0, stream>>>(nullptr, nullptr, nullptr, xc, ybf, xn,
                                             mAW + (size_t)l*NDIM*NC, mAb + (size_t)l*NC, mAal + l,
                                             ln1g + (size_t)l*DIM, ln1b + (size_t)l*DIM, coef, lnbf);
      { float* tmp = xc; xc = xn; xn = tmp; }
    }
    k_mgemm<0,true ,64,128,false><<<dim3(32, 2304/128), 256, 0, stream>>>(lnbf, wqkvT, (void*)bigBF, NTOK, 2304, 768);
    k_fattn<<<dim3(SEQ/64, NHEAD, BATCH), 256, 0, stream>>>(bigBF, t1bf);
    k_mgemm<0,true ,64,64,false><<<dim3(32, 768/64), 256, 0, stream>>>(t1bf, wprojT, (void*)ybf, NTOK, 768, 768);

    // ---- ffn sublayer ----
    k_mhc<false><<<NTOK, 256, 0, stream>>>(nullptr, nullptr, nullptr, xc, ybf, xn,
                                           mFW + (size_t)l*NDIM*NC, mFb + (size_t)l*NC, mFal + l,
                                           ln2g + (size_t)l*DIM, ln2b + (size_t)l*DIM, coef, lnbf);
    { float* tmp = xc; xc = xn; xn = tmp; }
    k_mgemm<1,true ,64,128,false><<<dim3(32, 3072/128), 256, 0, stream>>>(lnbf, wfc1T, (void*)bigBF, NTOK, 3072, 768);
    k_mgemm<0,true ,64,64,false><<<dim3(32, 768/64), 256, 0, stream>>>(bigBF, wfc2T, (void*)ybf, NTOK, 768, 3072);
  }

  // tail: combine-sum + final LN, then lm_head on bf16 tok_emb
  k_csumln<<<NTOK, 256, 0, stream>>>(xc, coef, ybf, lnfg, lnfb, lnfbf);
  k_cvt<<<2048, 256, 0, stream>>>(tok, tokbf, (VOCAB*DIM)/8);
  k_mgemm<0,false,128,128,true><<<dim3(16, (VOCAB+127)/128), 256, 0, stream>>>(lnfbf, tokbf, out, NTOK, VOCAB, 768);
}

// Round 12
// 1601.562 us; speedup vs baseline: 7.3415x; 1.0061x over previous
//
#include <hip/hip_runtime.h>
#include <math.h>

// ---- problem constants ----
constexpr int BATCH  = 2;
constexpr int SEQ    = 1024;
constexpr int DIM    = 768;
constexpr int NLAYER = 4;
constexpr int NHEAD  = 12;
constexpr int HDIM   = 64;
constexpr int NEXP   = 4;
constexpr int FFDIM  = 3072;
constexpr int VOCAB  = 50257;
constexpr int NDIM   = NEXP * DIM;   // 3072
constexpr int NC     = NEXP*NEXP + 2*NEXP; // 24
constexpr int NTOK   = BATCH * SEQ;  // 2048

using bf16x8 = __attribute__((ext_vector_type(8))) __bf16;
using f32x4  = __attribute__((ext_vector_type(4))) float;
using u16x8  = __attribute__((ext_vector_type(8))) unsigned short;
using u16x4  = __attribute__((ext_vector_type(4))) unsigned short;
using u32x4  = __attribute__((ext_vector_type(4))) unsigned int;

__device__ inline unsigned short f2bf(float f){
  unsigned u = __builtin_bit_cast(unsigned, f);
  u += 0x7fffu + ((u >> 16) & 1u);      // round-to-nearest-even
  return (unsigned short)(u >> 16);
}
__device__ inline float bf2f(unsigned short v){
  return __builtin_bit_cast(float, ((unsigned)v) << 16);
}
__device__ inline bf16x8 as_bf(u16x8 v){ return __builtin_bit_cast(bf16x8, v); }

// ---- workspace layout (float units) — R8 layout ----
constexpr size_t SZ_X   = (size_t)NTOK * NEXP * DIM;   // 6291456
constexpr size_t SZ_T   = (size_t)NTOK * DIM;          // 1572864
constexpr size_t O_X    = 0;
constexpr size_t O_X2   = O_X  + SZ_X;
constexpr size_t O_TMP  = O_X2 + SZ_X;                 // y bf16 (u16 SZ_T)
constexpr size_t O_BIG  = O_TMP + SZ_T;                // qkv/fc1-out bf16
constexpr size_t O_LNB  = O_BIG + (size_t)NTOK*2304;
constexpr size_t O_T1B  = O_LNB + SZ_T/2;
constexpr size_t O_COEF = O_T1B + SZ_T/2;
constexpr size_t O_WT   = O_COEF + (size_t)NTOK*NC;    // per-layer bf16 weights
// tokbf overlays floats [0 .. 19298688) (dead at lm_head time)
constexpr size_t O_LNF  = 19298688;                    // final-LN bf16 (786432 f)

// ---- wave-level reduce (64 lanes) ----
__device__ inline float wred_sum(float v){
#pragma unroll
  for (int m=32;m>=1;m>>=1) v += __shfl_xor(v,m);
  return v;
}

// ============================ fused mhc: [combine] + coef(sinkhorn) + pre-mix + LN ============================
template<bool FIRST>
__global__ __launch_bounds__(256) void k_mhc(const int* __restrict__ ids,
                                             const float* __restrict__ tokf,
                                             const float* __restrict__ posf,
                                             const float* __restrict__ xin,
                                             const unsigned short* __restrict__ y,
                                             float* __restrict__ xout,
                                             const float* __restrict__ W,
                                             const float* __restrict__ bb,
                                             const float* __restrict__ alpha_p,
                                             const float* __restrict__ g,
                                             const float* __restrict__ lnb_,
                                             float* __restrict__ coef,
                                             unsigned short* __restrict__ lnout){
  const int t = blockIdx.x, tid = threadIdx.x;
  const int w = tid >> 6;
  __shared__ float wred[4], w2[4];
  __shared__ float accw[4][NC];
  __shared__ float cfl[NC];

  float xp[3][4];
  float ss = 0.f;

  if constexpr (FIRST){
    const float* te = tokf + (size_t)ids[t]*DIM;
    const float* pe = posf + (size_t)(t % SEQ)*DIM;
#pragma unroll
    for (int k=0;k<3;k++){
      int d = tid + k*256;
      float v = te[d] + pe[d];
#pragma unroll
      for (int n=0;n<4;n++){
        xp[k][n] = v;
        xout[(size_t)t*NDIM + n*DIM + d] = v;
      }
      ss += 4.f*v*v;
    }
  } else {
    float cfp[20];
    const float* cp = coef + (size_t)t*NC;
#pragma unroll
    for (int j=0;j<16;j++) cfp[j] = cp[j];
#pragma unroll
    for (int j=0;j<4;j++) cfp[16+j] = cp[20+j];
    const float* xt = xin + (size_t)t*NDIM;
#pragma unroll
    for (int k=0;k<3;k++){
      int d = tid + k*256;
      float xm[4];
#pragma unroll
      for (int m=0;m<4;m++) xm[m] = xt[m*DIM + d];
      float yv = bf2f(y[(size_t)t*DIM + d]);
#pragma unroll
      for (int n=0;n<4;n++){
        float o = cfp[16+n]*yv;
#pragma unroll
        for (int m=0;m<4;m++) o += cfp[n*4+m]*xm[m];
        xp[k][n] = o;
        xout[(size_t)t*NDIM + n*DIM + d] = o;
        ss += o*o;
      }
    }
  }

  ss = wred_sum(ss);
  float acc[NC];
#pragma unroll
  for (int j=0;j<NC;j++) acc[j]=0.f;
#pragma unroll
  for (int k=0;k<3;k++){
    int d = tid + k*256;
#pragma unroll
    for (int n=0;n<4;n++){
      float v = xp[k][n];
      const float* wr = W + (size_t)(n*DIM + d)*NC;
#pragma unroll
      for (int j=0;j<NC;j++) acc[j] += v*wr[j];
    }
  }
#pragma unroll
  for (int j=0;j<NC;j++){
#pragma unroll
    for (int m=32;m>=1;m>>=1) acc[j] += __shfl_xor(acc[j], m);
  }
  if ((tid&63)==0){
    wred[w] = ss;
#pragma unroll
    for (int j=0;j<NC;j++) accw[w][j] = acc[j];
  }
  __syncthreads();
  float rfac = rsqrtf((wred[0]+wred[1]+wred[2]+wred[3])/(float)NDIM + 1e-6f);

  const float alpha = alpha_p[0];
  float* cfg = coef + (size_t)t*NC;
  if (tid < 16){
    float lmv = (accw[0][tid]+accw[1][tid]+accw[2][tid]+accw[3][tid])*rfac*alpha + bb[tid];
#pragma unroll
    for (int it=0; it<10; ++it){
      float mx = fmaxf(lmv, __shfl_xor(lmv,1)); mx = fmaxf(mx, __shfl_xor(mx,2));
      float se = expf(lmv-mx); se += __shfl_xor(se,1); se += __shfl_xor(se,2);
      lmv -= mx + logf(se);
      mx = fmaxf(lmv, __shfl_xor(lmv,4)); mx = fmaxf(mx, __shfl_xor(mx,8));
      se = expf(lmv-mx); se += __shfl_xor(se,4); se += __shfl_xor(se,8);
      lmv -= mx + logf(se);
    }
    float hm = expf(lmv);
    cfl[tid] = hm;
    cfg[tid] = hm;
  } else if (tid < 24){
    cfl[tid] = (accw[0][tid]+accw[1][tid]+accw[2][tid]+accw[3][tid])*rfac*alpha + bb[tid];
  }
  __syncthreads();
  if (tid == 0){
    float l0=cfl[16], l1=cfl[17], l2=cfl[18], l3=cfl[19];
    float pm = fmaxf(fmaxf(l0,l1),fmaxf(l2,l3));
    float e0=expf(l0-pm), e1=expf(l1-pm), e2=expf(l2-pm), e3=expf(l3-pm);
    float es=e0+e1+e2+e3;
    cfl[16]=e0/es; cfl[17]=e1/es; cfl[18]=e2/es; cfl[19]=e3/es;
#pragma unroll
    for (int j=20;j<24;j++) cfl[j] = 1.f/(1.f+expf(-cfl[j]));
#pragma unroll
    for (int j=16;j<24;j++) cfg[j] = cfl[j];
  }
  __syncthreads();

  float p0=cfl[16], p1=cfl[17], p2=cfl[18], p3=cfl[19];
  float h[3], s1=0.f, s2=0.f;
#pragma unroll
  for (int k=0;k<3;k++){
    float v = p0*xp[k][0] + p1*xp[k][1] + p2*xp[k][2] + p3*xp[k][3];
    h[k]=v; s1+=v; s2+=v*v;
  }
  s1 = wred_sum(s1); s2 = wred_sum(s2);
  if ((tid&63)==0){ wred[w]=s1; w2[w]=s2; }
  __syncthreads();
  float mu  = (wred[0]+wred[1]+wred[2]+wred[3])/(float)DIM;
  float var = (w2[0]+w2[1]+w2[2]+w2[3])/(float)DIM - mu*mu;
  float inv = rsqrtf(var + 1e-5f);
#pragma unroll
  for (int k=0;k<3;k++){
    int d = tid + k*256;
    lnout[(size_t)t*DIM+d] = f2bf((h[k]-mu)*inv*g[d] + lnb_[d]);
  }
}

// ============================ tail: combine-sum + final LN -> bf16 ============================
__global__ __launch_bounds__(256) void k_csumln(const float* __restrict__ xin,
                                                const float* __restrict__ coef,
                                                const unsigned short* __restrict__ y,
                                                const float* __restrict__ g,
                                                const float* __restrict__ bb,
                                                unsigned short* __restrict__ out){
  const int t = blockIdx.x, tid = threadIdx.x;
  const int w = tid >> 6;
  const float* cp = coef + (size_t)t*NC;
  float cs[4];
#pragma unroll
  for (int m=0;m<4;m++) cs[m] = cp[m] + cp[4+m] + cp[8+m] + cp[12+m];
  float ps = cp[20]+cp[21]+cp[22]+cp[23];
  const float* xt = xin + (size_t)t*NDIM;
  float h[3], s1=0.f, s2=0.f;
#pragma unroll
  for (int k=0;k<3;k++){
    int d = tid + k*256;
    float v = ps * bf2f(y[(size_t)t*DIM + d]);
#pragma unroll
    for (int m=0;m<4;m++) v += cs[m]*xt[m*DIM + d];
    h[k]=v; s1+=v; s2+=v*v;
  }
  __shared__ float r1[4], r2[4];
  s1 = wred_sum(s1); s2 = wred_sum(s2);
  if ((tid&63)==0){ r1[w]=s1; r2[w]=s2; }
  __syncthreads();
  float mu  = (r1[0]+r1[1]+r1[2]+r1[3])/(float)DIM;
  float var = (r2[0]+r2[1]+r2[2]+r2[3])/(float)DIM - mu*mu;
  float inv = rsqrtf(var + 1e-5f);
#pragma unroll
  for (int k=0;k<3;k++){
    int d = tid + k*256;
    out[(size_t)t*DIM+d] = f2bf((h[k]-mu)*inv*g[d] + bb[d]);
  }
}

// ============================ flash attention (MFMA, swapped QK^T -> S^T) — R8-proven ============================
__global__ __launch_bounds__(256) void k_fattn(const unsigned short* __restrict__ qkv,
                                               unsigned short* __restrict__ out){
  const int qb = gridDim.x - 1 - blockIdx.x;   // longest blocks dispatched first
  const int h = blockIdx.y, b = blockIdx.z;
  const int tid = threadIdx.x;
  const int l = tid & 63, w = tid >> 6;
  const int lr = l & 15, lh = l >> 4;
  const int qw = qb*64 + w*16;
  constexpr int LDV = 68;
  __shared__ unsigned short Vt[64*LDV];        // V^T [d][k]

  const unsigned short* base = qkv + (size_t)b*SEQ*2304;

  u16x8 qa[2];
  {
    const unsigned short* qp = base + (size_t)(qw + lr)*2304 + h*64 + lh*8;
    qa[0] = *(const u16x8*)qp;
    qa[1] = *(const u16x8*)(qp + 32);
  }

  f32x4 o[4];
#pragma unroll
  for (int df=0; df<4; df++) o[df] = (f32x4){0.f,0.f,0.f,0.f};
  float m_run = -1e30f, l_run = 0.f;
  const int qg = qw + lr;

  const int kTiles = qb + 1;
  for (int t=0; t<kTiles; ++t){
    const int k0 = t*64;
    __syncthreads();
#pragma unroll
    for (int p=0;p<2;p++){
      int idx = p*256 + tid;
      int k  = (idx >> 4) * 2;
      int d0 = (idx & 15) * 4;
      const unsigned short* vp = base + (size_t)(k0+k)*2304 + 1536 + h*64 + d0;
      u16x4 v0 = *(const u16x4*)vp;
      u16x4 v1 = *(const u16x4*)(vp + 2304);
#pragma unroll
      for (int j=0;j<4;j++){
        unsigned pkv = (unsigned)v0[j] | ((unsigned)v1[j] << 16);
        *(unsigned*)&Vt[(d0+j)*LDV + k] = pkv;
      }
    }
    __syncthreads();

    f32x4 s[4];
#pragma unroll
    for (int kf=0;kf<4;kf++) s[kf] = (f32x4){0.f,0.f,0.f,0.f};
#pragma unroll
    for (int ks=0;ks<2;ks++){
#pragma unroll
      for (int kf=0;kf<4;kf++){
        u16x8 kb = *(const u16x8*)(base + (size_t)(k0 + kf*16 + lr)*2304 + 768 + h*64 + ks*32 + lh*8);
        s[kf] = __builtin_amdgcn_mfma_f32_16x16x32_bf16(as_bf(kb), as_bf(qa[ks]), s[kf], 0,0,0);
      }
    }

    float sc[4][4];
#pragma unroll
    for (int kf=0;kf<4;kf++){
      int kg0 = k0 + kf*16 + lh*4;
#pragma unroll
      for (int r=0;r<4;r++)
        sc[kf][r] = (kg0 + r <= qg) ? s[kf][r]*0.125f : -1e30f;
    }
    float mt = sc[0][0];
#pragma unroll
    for (int kf=0;kf<4;kf++)
#pragma unroll
      for (int r=0;r<4;r++) mt = fmaxf(mt, sc[kf][r]);
    mt = fmaxf(mt, __shfl_xor(mt, 16));
    mt = fmaxf(mt, __shfl_xor(mt, 32));
    float mn = fmaxf(m_run, mt);
    float c  = __expf(m_run - mn);
    m_run = mn;
    float p[4][4];
    float rs = 0.f;
#pragma unroll
    for (int kf=0;kf<4;kf++)
#pragma unroll
      for (int r=0;r<4;r++){
        float pv = __expf(sc[kf][r] - mn);
        p[kf][r] = pv;
        rs += pv;
      }
    rs += __shfl_xor(rs, 16);
    rs += __shfl_xor(rs, 32);
    l_run = l_run*c + rs;

    float cq[4];
#pragma unroll
    for (int r=0;r<4;r++) cq[r] = __shfl(c, lh*4 + r);
#pragma unroll
    for (int df=0;df<4;df++)
#pragma unroll
      for (int r=0;r<4;r++) o[df][r] *= cq[r];

    unsigned pk[4][2];
#pragma unroll
    for (int kf=0;kf<4;kf++){
      pk[kf][0] = (unsigned)f2bf(p[kf][0]) | ((unsigned)f2bf(p[kf][1]) << 16);
      pk[kf][1] = (unsigned)f2bf(p[kf][2]) | ((unsigned)f2bf(p[kf][3]) << 16);
    }
    const int srcA = lr + (lh&1)*32;
    const int srcB = srcA + 16;
    const bool hi = (lh>>1)&1;
#pragma unroll
    for (int ks=0;ks<2;ks++){
      unsigned s00 = __shfl(pk[ks*2  ][0], srcA), s01 = __shfl(pk[ks*2  ][1], srcA);
      unsigned s10 = __shfl(pk[ks*2+1][0], srcA), s11 = __shfl(pk[ks*2+1][1], srcA);
      unsigned t00 = __shfl(pk[ks*2  ][0], srcB), t01 = __shfl(pk[ks*2  ][1], srcB);
      unsigned t10 = __shfl(pk[ks*2+1][0], srcB), t11 = __shfl(pk[ks*2+1][1], srcB);
      u32x4 paw;
      paw[0] = hi ? s10 : s00;
      paw[1] = hi ? s11 : s01;
      paw[2] = hi ? t10 : t00;
      paw[3] = hi ? t11 : t01;
      bf16x8 pa = __builtin_bit_cast(bf16x8, paw);
#pragma unroll
      for (int df=0;df<4;df++){
        u16x8 vb = *(const u16x8*)&Vt[(df*16 + lr)*LDV + ks*32 + lh*8];
        o[df] = __builtin_amdgcn_mfma_f32_16x16x32_bf16(pa, as_bf(vb), o[df], 0,0,0);
      }
    }
  }

  float linv[4];
#pragma unroll
  for (int r=0;r<4;r++) linv[r] = 1.f/__shfl(l_run, lh*4 + r);
#pragma unroll
  for (int df=0;df<4;df++)
#pragma unroll
    for (int r=0;r<4;r++){
      int qrow = qw + lh*4 + r;
      out[((size_t)b*SEQ + qrow)*DIM + h*64 + df*16 + lr] = f2bf(o[df][r]*linv[r]);
    }
}

// ============================ fused per-layer weight transpose+convert (R8-proven) ============================
__global__ __launch_bounds__(256) void k_wtrans4(const float* __restrict__ Wq, const float* __restrict__ Wp,
                                                 const float* __restrict__ W1, const float* __restrict__ W2,
                                                 unsigned short* __restrict__ dq, unsigned short* __restrict__ dp,
                                                 unsigned short* __restrict__ d1, unsigned short* __restrict__ d2){
  int bid = blockIdx.x;
  const float* src; unsigned short* dst; int K, N, local;
  if (bid < 1728)      { src=Wq; dst=dq; K=768;  N=2304; local=bid; }
  else if (bid < 2304) { src=Wp; dst=dp; K=768;  N=768;  local=bid-1728; }
  else if (bid < 4608) { src=W1; dst=d1; K=768;  N=3072; local=bid-2304; }
  else                 { src=W2; dst=d2; K=3072; N=768;  local=bid-4608; }
  int nx = N/32;
  int n0 = (local % nx)*32, k0 = (local / nx)*32;
  __shared__ float tile[32][33];
  int tx = threadIdx.x & 31, ty = threadIdx.x >> 5;
#pragma unroll
  for (int r=0;r<32;r+=8)
    tile[ty+r][tx] = src[(size_t)(k0+ty+r)*N + n0+tx];
  __syncthreads();
#pragma unroll
  for (int r=0;r<32;r+=8)
    dst[(size_t)(n0+ty+r)*K + k0+tx] = f2bf(tile[tx][ty+r]);
}

// ============================ f32 -> bf16 bulk convert (tok_emb) ============================
__global__ void k_cvt(const float* __restrict__ src, unsigned short* __restrict__ dst, int n8){
  int i = blockIdx.x*blockDim.x + threadIdx.x;
  for (; i < n8; i += gridDim.x*blockDim.x){
    float4 f0 = ((const float4*)src)[i*2];
    float4 f1 = ((const float4*)src)[i*2+1];
    u16x8 v;
    v[0]=f2bf(f0.x); v[1]=f2bf(f0.y); v[2]=f2bf(f0.z); v[3]=f2bf(f0.w);
    v[4]=f2bf(f1.x); v[5]=f2bf(f1.y); v[6]=f2bf(f1.z); v[7]=f2bf(f1.w);
    ((u16x8*)dst)[i] = v;
  }
}

// ============================ MFMA bf16 GEMM (BK=32, 16B-slot XOR swizzle) ============================
// C(MxN) = A(MxK bf16,row) * B^T(NxK bf16,row). ACT 0/1(gelu). OUTBF: bf16 out.
// LDS [row][32] rows of 4x16B slots; physical slot p of row r holds LOGICAL slot p^((r>>1)&3).
// Applied via pre-swizzled per-lane GLOBAL col on global_load_lds (dest stays linear, m173),
// and the same XOR on fragment reads -> lanes 0..15 spread over 8 bank-groups (2-way, free).
// grid: x = M/BMT (M-fastest), y = ceil(N/BNT); nwg % 8 == 0 required.
template<int ACT, bool OUTBF, int BMT, int BNT, bool NT>
__global__ __launch_bounds__(256) void k_mgemm(const unsigned short* __restrict__ A,
                                               const unsigned short* __restrict__ B,
                                               void* __restrict__ Cout,
                                               int M, int N, int K)
{
  constexpr int MF = BMT/32;
  constexpr int NF = BNT/32;
  __shared__ __align__(16) unsigned short Sm[(BMT+BNT)*32];
  unsigned short* As = Sm;
  unsigned short* Bs = Sm + BMT*32;
  const int tid = threadIdx.x;
  const int l = tid & 63, w = tid >> 6;
  const int wr = w >> 1, wc = w & 1;

  const int nwg  = gridDim.x * gridDim.y;
  const int flat = blockIdx.y * gridDim.x + blockIdx.x;
  const int q8   = nwg >> 3;
  const int wk   = (flat & 7) * q8 + (flat >> 3);
  const int bm = (wk % gridDim.x) * BMT;
  const int bn = (wk / gridDim.x) * BNT;

  const int srow = tid >> 2;                              // 0..63 (row within 64-row chunk)
  const int scol = (((tid & 3) ^ ((srow >> 1) & 3))) * 8; // inverse-swizzled global col

  f32x4 acc[MF][NF];
#pragma unroll
  for (int i=0;i<MF;i++)
#pragma unroll
    for (int j=0;j<NF;j++) acc[i][j] = (f32x4){0.f,0.f,0.f,0.f};

  for (int k0 = 0; k0 < K; k0 += 32){
#pragma unroll
    for (int c=0;c<BMT/64;++c){
      const unsigned short* ga = A + (size_t)(bm + c*64 + srow)*K + (k0 + scol);
      __builtin_amdgcn_global_load_lds(
          (const __attribute__((address_space(1))) void*)ga,
          (__attribute__((address_space(3))) void*)(As + c*2048 + w*512),
          16, 0, 0);
    }
#pragma unroll
    for (int c=0;c<BNT/64;++c){
      int gn = bn + c*64 + srow; if (gn >= N) gn = N-1;
      const unsigned short* gb = B + (size_t)gn*K + (k0 + scol);
      __builtin_amdgcn_global_load_lds(
          (const __attribute__((address_space(1))) void*)gb,
          (__attribute__((address_space(3))) void*)(Bs + c*2048 + w*512),
          16, 0, 0);
    }
    __syncthreads();

    bf16x8 af[MF], bfr[NF];
#pragma unroll
    for (int i=0;i<MF;i++){
      int row  = wr*(BMT/2) + i*16 + (l&15);
      int slot = (l>>4) ^ ((row>>1)&3);
      af[i]  = *(const bf16x8*)(As + (row*32 + slot*8));
    }
#pragma unroll
    for (int j=0;j<NF;j++){
      int row  = wc*(BNT/2) + j*16 + (l&15);
      int slot = (l>>4) ^ ((row>>1)&3);
      bfr[j] = *(const bf16x8*)(Bs + (row*32 + slot*8));
    }
#pragma unroll
    for (int mi=0;mi<MF;mi++)
#pragma unroll
      for (int ni=0;ni<NF;ni++)
        acc[mi][ni] = __builtin_amdgcn_mfma_f32_16x16x32_bf16(af[mi], bfr[ni], acc[mi][ni], 0,0,0);
    __syncthreads();
  }

  if constexpr (OUTBF){
#pragma unroll
    for (int mi=0;mi<MF;mi++){
      const int gm0 = bm + wr*(BMT/2) + mi*16 + (l>>4)*4;
#pragma unroll
      for (int ni=0;ni<NF;ni++){
        const int gn = bn + wc*(BNT/2) + ni*16 + (l&15);
        if (gn < N){
#pragma unroll
          for (int r=0;r<4;r++){
            float v = acc[mi][ni][r];
            if constexpr (ACT==1) v = 0.5f*v*(1.f + erff(v*0.70710678118654752f));
            ((unsigned short*)Cout)[(size_t)(gm0+r)*N + gn] = f2bf(v);
          }
        }
      }
    }
  } else {
    // LDS-band transpose epilogue: 16-row bands, f32x4 coalesced stores
    float* band = (float*)Sm;
#pragma unroll
    for (int b=0; b<BMT/16; ++b){
      __syncthreads();
#pragma unroll
      for (int mi=0;mi<MF;mi++){
        if (b == wr*MF + mi){
#pragma unroll
          for (int ni=0;ni<NF;ni++){
#pragma unroll
            for (int r=0;r<4;r++){
              float v = acc[mi][ni][r];
              if constexpr (ACT==1) v = 0.5f*v*(1.f + erff(v*0.70710678118654752f));
              band[((l>>4)*4+r)*BNT + wc*(BNT/2) + ni*16 + (l&15)] = v;
            }
          }
        }
      }
      __syncthreads();
      const int row0 = bm + b*16;
#pragma unroll
      for (int p=0; p<(4*BNT)/256; ++p){
        int f = tid + p*256;
        int row = f/(BNT/4), c4 = f%(BNT/4);
        f32x4 v = *(const f32x4*)&band[row*BNT + c4*4];
        float* cp = (float*)Cout + (size_t)(row0+row)*N + bn + c4*4;
        if (bn + c4*4 + 3 < N){
          if constexpr (NT) __builtin_nontemporal_store(v, (f32x4*)cp);
          else *(f32x4*)cp = v;
        } else {
#pragma unroll
          for (int j=0;j<4;j++) if (bn + c4*4 + j < N) cp[j] = v[j];
        }
      }
    }
  }
}

// ============================ host launch ============================
extern "C" void kernel_launch(void* const* d_in, const int* in_sizes, int n_in,
                              void* d_out, int out_size, void* d_ws, size_t ws_size,
                              hipStream_t stream) {
  const int*   ids   = (const int*)  d_in[0];
  const float* tok   = (const float*)d_in[1];
  const float* pos   = (const float*)d_in[2];
  const float* ln1g  = (const float*)d_in[3];
  const float* ln1b  = (const float*)d_in[4];
  const float* ln2g  = (const float*)d_in[5];
  const float* ln2b  = (const float*)d_in[6];
  const float* Wqkv  = (const float*)d_in[7];
  const float* Wproj = (const float*)d_in[8];
  const float* Wfc1  = (const float*)d_in[9];
  const float* Wfc2  = (const float*)d_in[10];
  const float* mAW   = (const float*)d_in[11];
  const float* mAb   = (const float*)d_in[12];
  const float* mAal  = (const float*)d_in[13];
  const float* mFW   = (const float*)d_in[14];
  const float* mFb   = (const float*)d_in[15];
  const float* mFal  = (const float*)d_in[16];
  const float* lnfg  = (const float*)d_in[17];
  const float* lnfb  = (const float*)d_in[18];
  float* out = (float*)d_out;

  float* ws   = (float*)d_ws;
  float* xA   = ws + O_X;
  float* xB   = ws + O_X2;
  unsigned short* ybf   = (unsigned short*)(ws + O_TMP);   // y bf16
  unsigned short* bigBF = (unsigned short*)(ws + O_BIG);   // qkv / fc1-out bf16
  unsigned short* lnbf  = (unsigned short*)(ws + O_LNB);
  unsigned short* t1bf  = (unsigned short*)(ws + O_T1B);
  float* coef = ws + O_COEF;
  unsigned short* wT    = (unsigned short*)(ws + O_WT);
  unsigned short* wqkvT  = wT;
  unsigned short* wprojT = wT + (size_t)2304*768;
  unsigned short* wfc1T  = wprojT + (size_t)768*768;
  unsigned short* wfc2T  = wfc1T + (size_t)3072*768;
  unsigned short* tokbf  = (unsigned short*)(ws + O_X);    // overlays dead buffers at lm_head time
  unsigned short* lnfbf  = (unsigned short*)(ws + O_LNF);

  float* xc = xA; float* xn = xB;
  for (int l=0; l<NLAYER; l++){
    k_wtrans4<<<6912, 256, 0, stream>>>(Wqkv + (size_t)l*DIM*3*DIM, Wproj + (size_t)l*DIM*DIM,
                                        Wfc1 + (size_t)l*DIM*FFDIM, Wfc2 + (size_t)l*FFDIM*DIM,
                                        wqkvT, wprojT, wfc1T, wfc2T);
    // ---- attention sublayer ----
    if (l == 0){
      k_mhc<true><<<NTOK, 256, 0, stream>>>(ids, tok, pos, nullptr, nullptr, xA,
                                            mAW, mAb, mAal, ln1g, ln1b, coef, lnbf);
    } else {
      k_mhc<false><<<NTOK, 256, 0, stream>>>(nullptr, nullptr, nullptr, xc, ybf, xn,
                                             mAW + (size_t)l*NDIM*NC, mAb + (size_t)l*NC, mAal + l,
                                             ln1g + (size_t)l*DIM, ln1b + (size_t)l*DIM, coef, lnbf);
      { float* tmp = xc; xc = xn; xn = tmp; }
    }
    k_mgemm<0,true ,64,128,false><<<dim3(32, 2304/128), 256, 0, stream>>>(lnbf, wqkvT, (void*)bigBF, NTOK, 2304, 768);
    k_fattn<<<dim3(SEQ/64, NHEAD, BATCH), 256, 0, stream>>>(bigBF, t1bf);
    k_mgemm<0,true ,64,64,false><<<dim3(32, 768/64), 256, 0, stream>>>(t1bf, wprojT, (void*)ybf, NTOK, 768, 768);

    // ---- ffn sublayer ----
    k_mhc<false><<<NTOK, 256, 0, stream>>>(nullptr, nullptr, nullptr, xc, ybf, xn,
                                           mFW + (size_t)l*NDIM*NC, mFb + (size_t)l*NC, mFal + l,
                                           ln2g + (size_t)l*DIM, ln2b + (size_t)l*DIM, coef, lnbf);
    { float* tmp = xc; xc = xn; xn = tmp; }
    k_mgemm<1,true ,64,128,false><<<dim3(32, 3072/128), 256, 0, stream>>>(lnbf, wfc1T, (void*)bigBF, NTOK, 3072, 768);
    k_mgemm<0,true ,64,64,false><<<dim3(32, 768/64), 256, 0, stream>>>(bigBF, wfc2T, (void*)ybf, NTOK, 768, 3072);
  }

  // tail: combine-sum + final LN, then lm_head on bf16 tok_emb
  k_csumln<<<NTOK, 256, 0, stream>>>(xc, coef, ybf, lnfg, lnfb, lnfbf);
  k_cvt<<<2048, 256, 0, stream>>>(tok, tokbf, (VOCAB*DIM)/8);
  k_mgemm<0,false,128,128,true><<<dim3(16, (VOCAB+127)/128), 256, 0, stream>>>(lnfbf, tokbf, out, NTOK, VOCAB, 768);
}

// Round 13
// 1572.429 us; speedup vs baseline: 7.4775x; 1.0185x over previous
//
#include <hip/hip_runtime.h>
#include <math.h>

// ---- problem constants ----
constexpr int BATCH  = 2;
constexpr int SEQ    = 1024;
constexpr int DIM    = 768;
constexpr int NLAYER = 4;
constexpr int NHEAD  = 12;
constexpr int HDIM   = 64;
constexpr int NEXP   = 4;
constexpr int FFDIM  = 3072;
constexpr int VOCAB  = 50257;
constexpr int NDIM   = NEXP * DIM;   // 3072
constexpr int NC     = NEXP*NEXP + 2*NEXP; // 24
constexpr int NTOK   = BATCH * SEQ;  // 2048

using bf16x8 = __attribute__((ext_vector_type(8))) __bf16;
using f32x4  = __attribute__((ext_vector_type(4))) float;
using u16x8  = __attribute__((ext_vector_type(8))) unsigned short;
using u16x4  = __attribute__((ext_vector_type(4))) unsigned short;
using u32x4  = __attribute__((ext_vector_type(4))) unsigned int;

__device__ inline unsigned short f2bf(float f){
  unsigned u = __builtin_bit_cast(unsigned, f);
  u += 0x7fffu + ((u >> 16) & 1u);      // round-to-nearest-even
  return (unsigned short)(u >> 16);
}
__device__ inline float bf2f(unsigned short v){
  return __builtin_bit_cast(float, ((unsigned)v) << 16);
}
__device__ inline bf16x8 as_bf(u16x8 v){ return __builtin_bit_cast(bf16x8, v); }

// ---- workspace layout (float units) — R8 layout ----
constexpr size_t SZ_X   = (size_t)NTOK * NEXP * DIM;   // 6291456
constexpr size_t SZ_T   = (size_t)NTOK * DIM;          // 1572864
constexpr size_t O_X    = 0;
constexpr size_t O_X2   = O_X  + SZ_X;
constexpr size_t O_TMP  = O_X2 + SZ_X;                 // y bf16 (u16 SZ_T)
constexpr size_t O_BIG  = O_TMP + SZ_T;                // qkv/fc1-out bf16
constexpr size_t O_LNB  = O_BIG + (size_t)NTOK*2304;
constexpr size_t O_T1B  = O_LNB + SZ_T/2;
constexpr size_t O_COEF = O_T1B + SZ_T/2;
constexpr size_t O_WT   = O_COEF + (size_t)NTOK*NC;    // per-layer bf16 weights
// tokbf overlays floats [0 .. 19298688) (dead at lm_head time)
constexpr size_t O_LNF  = 19298688;                    // final-LN bf16 (786432 f)

// ---- wave-level reduce (64 lanes) ----
__device__ inline float wred_sum(float v){
#pragma unroll
  for (int m=32;m>=1;m>>=1) v += __shfl_xor(v,m);
  return v;
}

// ============================ fused mhc: [combine] + coef(sinkhorn) + pre-mix + LN ============================
template<bool FIRST>
__global__ __launch_bounds__(256) void k_mhc(const int* __restrict__ ids,
                                             const float* __restrict__ tokf,
                                             const float* __restrict__ posf,
                                             const float* __restrict__ xin,
                                             const unsigned short* __restrict__ y,
                                             float* __restrict__ xout,
                                             const float* __restrict__ W,
                                             const float* __restrict__ bb,
                                             const float* __restrict__ alpha_p,
                                             const float* __restrict__ g,
                                             const float* __restrict__ lnb_,
                                             float* __restrict__ coef,
                                             unsigned short* __restrict__ lnout){
  const int t = blockIdx.x, tid = threadIdx.x;
  const int w = tid >> 6;
  __shared__ float wred[4], w2[4];
  __shared__ float accw[4][NC];
  __shared__ float cfl[NC];

  float xp[3][4];
  float ss = 0.f;

  if constexpr (FIRST){
    const float* te = tokf + (size_t)ids[t]*DIM;
    const float* pe = posf + (size_t)(t % SEQ)*DIM;
#pragma unroll
    for (int k=0;k<3;k++){
      int d = tid + k*256;
      float v = te[d] + pe[d];
#pragma unroll
      for (int n=0;n<4;n++){
        xp[k][n] = v;
        xout[(size_t)t*NDIM + n*DIM + d] = v;
      }
      ss += 4.f*v*v;
    }
  } else {
    float cfp[20];
    const float* cp = coef + (size_t)t*NC;
#pragma unroll
    for (int j=0;j<16;j++) cfp[j] = cp[j];
#pragma unroll
    for (int j=0;j<4;j++) cfp[16+j] = cp[20+j];
    const float* xt = xin + (size_t)t*NDIM;
#pragma unroll
    for (int k=0;k<3;k++){
      int d = tid + k*256;
      float xm[4];
#pragma unroll
      for (int m=0;m<4;m++) xm[m] = xt[m*DIM + d];
      float yv = bf2f(y[(size_t)t*DIM + d]);
#pragma unroll
      for (int n=0;n<4;n++){
        float o = cfp[16+n]*yv;
#pragma unroll
        for (int m=0;m<4;m++) o += cfp[n*4+m]*xm[m];
        xp[k][n] = o;
        xout[(size_t)t*NDIM + n*DIM + d] = o;
        ss += o*o;
      }
    }
  }

  ss = wred_sum(ss);
  float acc[NC];
#pragma unroll
  for (int j=0;j<NC;j++) acc[j]=0.f;
#pragma unroll
  for (int k=0;k<3;k++){
    int d = tid + k*256;
#pragma unroll
    for (int n=0;n<4;n++){
      float v = xp[k][n];
      const float* wr = W + (size_t)(n*DIM + d)*NC;
#pragma unroll
      for (int j=0;j<NC;j++) acc[j] += v*wr[j];
    }
  }
#pragma unroll
  for (int j=0;j<NC;j++){
#pragma unroll
    for (int m=32;m>=1;m>>=1) acc[j] += __shfl_xor(acc[j], m);
  }
  if ((tid&63)==0){
    wred[w] = ss;
#pragma unroll
    for (int j=0;j<NC;j++) accw[w][j] = acc[j];
  }
  __syncthreads();
  float rfac = rsqrtf((wred[0]+wred[1]+wred[2]+wred[3])/(float)NDIM + 1e-6f);

  const float alpha = alpha_p[0];
  float* cfg = coef + (size_t)t*NC;
  if (tid < 16){
    float lmv = (accw[0][tid]+accw[1][tid]+accw[2][tid]+accw[3][tid])*rfac*alpha + bb[tid];
#pragma unroll
    for (int it=0; it<10; ++it){
      float mx = fmaxf(lmv, __shfl_xor(lmv,1)); mx = fmaxf(mx, __shfl_xor(mx,2));
      float se = expf(lmv-mx); se += __shfl_xor(se,1); se += __shfl_xor(se,2);
      lmv -= mx + logf(se);
      mx = fmaxf(lmv, __shfl_xor(lmv,4)); mx = fmaxf(mx, __shfl_xor(mx,8));
      se = expf(lmv-mx); se += __shfl_xor(se,4); se += __shfl_xor(se,8);
      lmv -= mx + logf(se);
    }
    float hm = expf(lmv);
    cfl[tid] = hm;
    cfg[tid] = hm;
  } else if (tid < 24){
    cfl[tid] = (accw[0][tid]+accw[1][tid]+accw[2][tid]+accw[3][tid])*rfac*alpha + bb[tid];
  }
  __syncthreads();
  if (tid == 0){
    float l0=cfl[16], l1=cfl[17], l2=cfl[18], l3=cfl[19];
    float pm = fmaxf(fmaxf(l0,l1),fmaxf(l2,l3));
    float e0=expf(l0-pm), e1=expf(l1-pm), e2=expf(l2-pm), e3=expf(l3-pm);
    float es=e0+e1+e2+e3;
    cfl[16]=e0/es; cfl[17]=e1/es; cfl[18]=e2/es; cfl[19]=e3/es;
#pragma unroll
    for (int j=20;j<24;j++) cfl[j] = 1.f/(1.f+expf(-cfl[j]));
#pragma unroll
    for (int j=16;j<24;j++) cfg[j] = cfl[j];
  }
  __syncthreads();

  float p0=cfl[16], p1=cfl[17], p2=cfl[18], p3=cfl[19];
  float h[3], s1=0.f, s2=0.f;
#pragma unroll
  for (int k=0;k<3;k++){
    float v = p0*xp[k][0] + p1*xp[k][1] + p2*xp[k][2] + p3*xp[k][3];
    h[k]=v; s1+=v; s2+=v*v;
  }
  s1 = wred_sum(s1); s2 = wred_sum(s2);
  if ((tid&63)==0){ wred[w]=s1; w2[w]=s2; }
  __syncthreads();
  float mu  = (wred[0]+wred[1]+wred[2]+wred[3])/(float)DIM;
  float var = (w2[0]+w2[1]+w2[2]+w2[3])/(float)DIM - mu*mu;
  float inv = rsqrtf(var + 1e-5f);
#pragma unroll
  for (int k=0;k<3;k++){
    int d = tid + k*256;
    lnout[(size_t)t*DIM+d] = f2bf((h[k]-mu)*inv*g[d] + lnb_[d]);
  }
}

// ============================ tail: combine-sum + final LN -> bf16 ============================
__global__ __launch_bounds__(256) void k_csumln(const float* __restrict__ xin,
                                                const float* __restrict__ coef,
                                                const unsigned short* __restrict__ y,
                                                const float* __restrict__ g,
                                                const float* __restrict__ bb,
                                                unsigned short* __restrict__ out){
  const int t = blockIdx.x, tid = threadIdx.x;
  const int w = tid >> 6;
  const float* cp = coef + (size_t)t*NC;
  float cs[4];
#pragma unroll
  for (int m=0;m<4;m++) cs[m] = cp[m] + cp[4+m] + cp[8+m] + cp[12+m];
  float ps = cp[20]+cp[21]+cp[22]+cp[23];
  const float* xt = xin + (size_t)t*NDIM;
  float h[3], s1=0.f, s2=0.f;
#pragma unroll
  for (int k=0;k<3;k++){
    int d = tid + k*256;
    float v = ps * bf2f(y[(size_t)t*DIM + d]);
#pragma unroll
    for (int m=0;m<4;m++) v += cs[m]*xt[m*DIM + d];
    h[k]=v; s1+=v; s2+=v*v;
  }
  __shared__ float r1[4], r2[4];
  s1 = wred_sum(s1); s2 = wred_sum(s2);
  if ((tid&63)==0){ r1[w]=s1; r2[w]=s2; }
  __syncthreads();
  float mu  = (r1[0]+r1[1]+r1[2]+r1[3])/(float)DIM;
  float var = (r2[0]+r2[1]+r2[2]+r2[3])/(float)DIM - mu*mu;
  float inv = rsqrtf(var + 1e-5f);
#pragma unroll
  for (int k=0;k<3;k++){
    int d = tid + k*256;
    out[(size_t)t*DIM+d] = f2bf((h[k]-mu)*inv*g[d] + bb[d]);
  }
}

// ============================ flash attention (MFMA, swapped QK^T -> S^T) — R8-proven ============================
__global__ __launch_bounds__(256) void k_fattn(const unsigned short* __restrict__ qkv,
                                               unsigned short* __restrict__ out){
  const int qb = gridDim.x - 1 - blockIdx.x;   // longest blocks dispatched first
  const int h = blockIdx.y, b = blockIdx.z;
  const int tid = threadIdx.x;
  const int l = tid & 63, w = tid >> 6;
  const int lr = l & 15, lh = l >> 4;
  const int qw = qb*64 + w*16;
  constexpr int LDV = 68;
  __shared__ unsigned short Vt[64*LDV];        // V^T [d][k]

  const unsigned short* base = qkv + (size_t)b*SEQ*2304;

  u16x8 qa[2];
  {
    const unsigned short* qp = base + (size_t)(qw + lr)*2304 + h*64 + lh*8;
    qa[0] = *(const u16x8*)qp;
    qa[1] = *(const u16x8*)(qp + 32);
  }

  f32x4 o[4];
#pragma unroll
  for (int df=0; df<4; df++) o[df] = (f32x4){0.f,0.f,0.f,0.f};
  float m_run = -1e30f, l_run = 0.f;
  const int qg = qw + lr;

  const int kTiles = qb + 1;
  for (int t=0; t<kTiles; ++t){
    const int k0 = t*64;
    __syncthreads();
#pragma unroll
    for (int p=0;p<2;p++){
      int idx = p*256 + tid;
      int k  = (idx >> 4) * 2;
      int d0 = (idx & 15) * 4;
      const unsigned short* vp = base + (size_t)(k0+k)*2304 + 1536 + h*64 + d0;
      u16x4 v0 = *(const u16x4*)vp;
      u16x4 v1 = *(const u16x4*)(vp + 2304);
#pragma unroll
      for (int j=0;j<4;j++){
        unsigned pkv = (unsigned)v0[j] | ((unsigned)v1[j] << 16);
        *(unsigned*)&Vt[(d0+j)*LDV + k] = pkv;
      }
    }
    __syncthreads();

    f32x4 s[4];
#pragma unroll
    for (int kf=0;kf<4;kf++) s[kf] = (f32x4){0.f,0.f,0.f,0.f};
#pragma unroll
    for (int ks=0;ks<2;ks++){
#pragma unroll
      for (int kf=0;kf<4;kf++){
        u16x8 kb = *(const u16x8*)(base + (size_t)(k0 + kf*16 + lr)*2304 + 768 + h*64 + ks*32 + lh*8);
        s[kf] = __builtin_amdgcn_mfma_f32_16x16x32_bf16(as_bf(kb), as_bf(qa[ks]), s[kf], 0,0,0);
      }
    }

    float sc[4][4];
#pragma unroll
    for (int kf=0;kf<4;kf++){
      int kg0 = k0 + kf*16 + lh*4;
#pragma unroll
      for (int r=0;r<4;r++)
        sc[kf][r] = (kg0 + r <= qg) ? s[kf][r]*0.125f : -1e30f;
    }
    float mt = sc[0][0];
#pragma unroll
    for (int kf=0;kf<4;kf++)
#pragma unroll
      for (int r=0;r<4;r++) mt = fmaxf(mt, sc[kf][r]);
    mt = fmaxf(mt, __shfl_xor(mt, 16));
    mt = fmaxf(mt, __shfl_xor(mt, 32));
    float mn = fmaxf(m_run, mt);
    float c  = __expf(m_run - mn);
    m_run = mn;
    float p[4][4];
    float rs = 0.f;
#pragma unroll
    for (int kf=0;kf<4;kf++)
#pragma unroll
      for (int r=0;r<4;r++){
        float pv = __expf(sc[kf][r] - mn);
        p[kf][r] = pv;
        rs += pv;
      }
    rs += __shfl_xor(rs, 16);
    rs += __shfl_xor(rs, 32);
    l_run = l_run*c + rs;

    float cq[4];
#pragma unroll
    for (int r=0;r<4;r++) cq[r] = __shfl(c, lh*4 + r);
#pragma unroll
    for (int df=0;df<4;df++)
#pragma unroll
      for (int r=0;r<4;r++) o[df][r] *= cq[r];

    unsigned pk[4][2];
#pragma unroll
    for (int kf=0;kf<4;kf++){
      pk[kf][0] = (unsigned)f2bf(p[kf][0]) | ((unsigned)f2bf(p[kf][1]) << 16);
      pk[kf][1] = (unsigned)f2bf(p[kf][2]) | ((unsigned)f2bf(p[kf][3]) << 16);
    }
    const int srcA = lr + (lh&1)*32;
    const int srcB = srcA + 16;
    const bool hi = (lh>>1)&1;
#pragma unroll
    for (int ks=0;ks<2;ks++){
      unsigned s00 = __shfl(pk[ks*2  ][0], srcA), s01 = __shfl(pk[ks*2  ][1], srcA);
      unsigned s10 = __shfl(pk[ks*2+1][0], srcA), s11 = __shfl(pk[ks*2+1][1], srcA);
      unsigned t00 = __shfl(pk[ks*2  ][0], srcB), t01 = __shfl(pk[ks*2  ][1], srcB);
      unsigned t10 = __shfl(pk[ks*2+1][0], srcB), t11 = __shfl(pk[ks*2+1][1], srcB);
      u32x4 paw;
      paw[0] = hi ? s10 : s00;
      paw[1] = hi ? s11 : s01;
      paw[2] = hi ? t10 : t00;
      paw[3] = hi ? t11 : t01;
      bf16x8 pa = __builtin_bit_cast(bf16x8, paw);
#pragma unroll
      for (int df=0;df<4;df++){
        u16x8 vb = *(const u16x8*)&Vt[(df*16 + lr)*LDV + ks*32 + lh*8];
        o[df] = __builtin_amdgcn_mfma_f32_16x16x32_bf16(pa, as_bf(vb), o[df], 0,0,0);
      }
    }
  }

  float linv[4];
#pragma unroll
  for (int r=0;r<4;r++) linv[r] = 1.f/__shfl(l_run, lh*4 + r);
#pragma unroll
  for (int df=0;df<4;df++)
#pragma unroll
    for (int r=0;r<4;r++){
      int qrow = qw + lh*4 + r;
      out[((size_t)b*SEQ + qrow)*DIM + h*64 + df*16 + lr] = f2bf(o[df][r]*linv[r]);
    }
}

// ============================ fused per-layer weight transpose+convert (R8-proven) ============================
__global__ __launch_bounds__(256) void k_wtrans4(const float* __restrict__ Wq, const float* __restrict__ Wp,
                                                 const float* __restrict__ W1, const float* __restrict__ W2,
                                                 unsigned short* __restrict__ dq, unsigned short* __restrict__ dp,
                                                 unsigned short* __restrict__ d1, unsigned short* __restrict__ d2){
  int bid = blockIdx.x;
  const float* src; unsigned short* dst; int K, N, local;
  if (bid < 1728)      { src=Wq; dst=dq; K=768;  N=2304; local=bid; }
  else if (bid < 2304) { src=Wp; dst=dp; K=768;  N=768;  local=bid-1728; }
  else if (bid < 4608) { src=W1; dst=d1; K=768;  N=3072; local=bid-2304; }
  else                 { src=W2; dst=d2; K=3072; N=768;  local=bid-4608; }
  int nx = N/32;
  int n0 = (local % nx)*32, k0 = (local / nx)*32;
  __shared__ float tile[32][33];
  int tx = threadIdx.x & 31, ty = threadIdx.x >> 5;
#pragma unroll
  for (int r=0;r<32;r+=8)
    tile[ty+r][tx] = src[(size_t)(k0+ty+r)*N + n0+tx];
  __syncthreads();
#pragma unroll
  for (int r=0;r<32;r+=8)
    dst[(size_t)(n0+ty+r)*K + k0+tx] = f2bf(tile[tx][ty+r]);
}

// ============================ f32 -> bf16 bulk convert (tok_emb) ============================
__global__ void k_cvt(const float* __restrict__ src, unsigned short* __restrict__ dst, int n8){
  int i = blockIdx.x*blockDim.x + threadIdx.x;
  for (; i < n8; i += gridDim.x*blockDim.x){
    float4 f0 = ((const float4*)src)[i*2];
    float4 f1 = ((const float4*)src)[i*2+1];
    u16x8 v;
    v[0]=f2bf(f0.x); v[1]=f2bf(f0.y); v[2]=f2bf(f0.z); v[3]=f2bf(f0.w);
    v[4]=f2bf(f1.x); v[5]=f2bf(f1.y); v[6]=f2bf(f1.z); v[7]=f2bf(f1.w);
    ((u16x8*)dst)[i] = v;
  }
}

// ============================ MFMA bf16 GEMM (BK=32, XOR swizzle, LDS DOUBLE-BUFFER) ============================
// C(MxN) = A(MxK bf16,row) * B^T(NxK bf16,row). ACT 0/1(gelu). OUTBF: bf16 out.
// 2-phase schedule (catalog T3-minimum): stage tile k+1 into buf^1 BEFORE computing buf,
// then ONE __syncthreads per K-step (carries vmcnt/lgkm drain). global_load_lds latency
// hides under ds_read+MFMA of the current tile. Staging addressing identical to R12.
// grid: x = M/BMT (M-fastest), y = ceil(N/BNT); nwg % 8 == 0 required.
template<int ACT, bool OUTBF, int BMT, int BNT, bool NT>
__global__ __launch_bounds__(256) void k_mgemm(const unsigned short* __restrict__ A,
                                               const unsigned short* __restrict__ B,
                                               void* __restrict__ Cout,
                                               int M, int N, int K)
{
  constexpr int MF = BMT/32;
  constexpr int NF = BNT/32;
  constexpr int TILE = (BMT+BNT)*32;              // u16 per buffer
  __shared__ __align__(16) unsigned short Sm[2*TILE];
  const int tid = threadIdx.x;
  const int l = tid & 63, w = tid >> 6;
  const int wr = w >> 1, wc = w & 1;

  const int nwg  = gridDim.x * gridDim.y;
  const int flat = blockIdx.y * gridDim.x + blockIdx.x;
  const int q8   = nwg >> 3;
  const int wk   = (flat & 7) * q8 + (flat >> 3);
  const int bm = (wk % gridDim.x) * BMT;
  const int bn = (wk / gridDim.x) * BNT;

  const int srow = tid >> 2;                              // 0..63 (row within 64-row chunk)
  const int scol = (((tid & 3) ^ ((srow >> 1) & 3))) * 8; // inverse-swizzled global col

  f32x4 acc[MF][NF];
#pragma unroll
  for (int i=0;i<MF;i++)
#pragma unroll
    for (int j=0;j<NF;j++) acc[i][j] = (f32x4){0.f,0.f,0.f,0.f};

  auto STAGE = [&](int bufb, int k0){
    unsigned short* As = Sm + bufb*TILE;
    unsigned short* Bs = As + BMT*32;
#pragma unroll
    for (int c=0;c<BMT/64;++c){
      const unsigned short* ga = A + (size_t)(bm + c*64 + srow)*K + (k0 + scol);
      __builtin_amdgcn_global_load_lds(
          (const __attribute__((address_space(1))) void*)ga,
          (__attribute__((address_space(3))) void*)(As + c*2048 + w*512),
          16, 0, 0);
    }
#pragma unroll
    for (int c=0;c<BNT/64;++c){
      int gn = bn + c*64 + srow; if (gn >= N) gn = N-1;
      const unsigned short* gb = B + (size_t)gn*K + (k0 + scol);
      __builtin_amdgcn_global_load_lds(
          (const __attribute__((address_space(1))) void*)gb,
          (__attribute__((address_space(3))) void*)(Bs + c*2048 + w*512),
          16, 0, 0);
    }
  };

  auto COMPUTE = [&](int bufb){
    const unsigned short* As = Sm + bufb*TILE;
    const unsigned short* Bs = As + BMT*32;
    bf16x8 af[MF], bfr[NF];
#pragma unroll
    for (int i=0;i<MF;i++){
      int row  = wr*(BMT/2) + i*16 + (l&15);
      int slot = (l>>4) ^ ((row>>1)&3);
      af[i]  = *(const bf16x8*)(As + (row*32 + slot*8));
    }
#pragma unroll
    for (int j=0;j<NF;j++){
      int row  = wc*(BNT/2) + j*16 + (l&15);
      int slot = (l>>4) ^ ((row>>1)&3);
      bfr[j] = *(const bf16x8*)(Bs + (row*32 + slot*8));
    }
#pragma unroll
    for (int mi=0;mi<MF;mi++)
#pragma unroll
      for (int ni=0;ni<NF;ni++)
        acc[mi][ni] = __builtin_amdgcn_mfma_f32_16x16x32_bf16(af[mi], bfr[ni], acc[mi][ni], 0,0,0);
  };

  // ---- double-buffered K loop: one barrier per step ----
  STAGE(0, 0);
  __syncthreads();                 // drain prologue stage
  int cur = 0;
  for (int k0 = 32; k0 < K; k0 += 32){
    STAGE(cur^1, k0);              // issue next tile (vmcnt, no wait)
    COMPUTE(cur);                  // ds_read+MFMA current (lgkm waits only)
    __syncthreads();               // drain: next tile ready, all reads of cur done
    cur ^= 1;
  }
  COMPUTE(cur);                    // last tile (no prefetch)

  if constexpr (OUTBF){
#pragma unroll
    for (int mi=0;mi<MF;mi++){
      const int gm0 = bm + wr*(BMT/2) + mi*16 + (l>>4)*4;
#pragma unroll
      for (int ni=0;ni<NF;ni++){
        const int gn = bn + wc*(BNT/2) + ni*16 + (l&15);
        if (gn < N){
#pragma unroll
          for (int r=0;r<4;r++){
            float v = acc[mi][ni][r];
            if constexpr (ACT==1) v = 0.5f*v*(1.f + erff(v*0.70710678118654752f));
            ((unsigned short*)Cout)[(size_t)(gm0+r)*N + gn] = f2bf(v);
          }
        }
      }
    }
  } else {
    // LDS-band transpose epilogue: 16-row bands, f32x4 coalesced stores
    float* band = (float*)Sm;
#pragma unroll
    for (int b=0; b<BMT/16; ++b){
      __syncthreads();
#pragma unroll
      for (int mi=0;mi<MF;mi++){
        if (b == wr*MF + mi){
#pragma unroll
          for (int ni=0;ni<NF;ni++){
#pragma unroll
            for (int r=0;r<4;r++){
              float v = acc[mi][ni][r];
              if constexpr (ACT==1) v = 0.5f*v*(1.f + erff(v*0.70710678118654752f));
              band[((l>>4)*4+r)*BNT + wc*(BNT/2) + ni*16 + (l&15)] = v;
            }
          }
        }
      }
      __syncthreads();
      const int row0 = bm + b*16;
#pragma unroll
      for (int p=0; p<(4*BNT)/256; ++p){
        int f = tid + p*256;
        int row = f/(BNT/4), c4 = f%(BNT/4);
        f32x4 v = *(const f32x4*)&band[row*BNT + c4*4];
        float* cp = (float*)Cout + (size_t)(row0+row)*N + bn + c4*4;
        if (bn + c4*4 + 3 < N){
          if constexpr (NT) __builtin_nontemporal_store(v, (f32x4*)cp);
          else *(f32x4*)cp = v;
        } else {
#pragma unroll
          for (int j=0;j<4;j++) if (bn + c4*4 + j < N) cp[j] = v[j];
        }
      }
    }
  }
}

// ============================ host launch ============================
extern "C" void kernel_launch(void* const* d_in, const int* in_sizes, int n_in,
                              void* d_out, int out_size, void* d_ws, size_t ws_size,
                              hipStream_t stream) {
  const int*   ids   = (const int*)  d_in[0];
  const float* tok   = (const float*)d_in[1];
  const float* pos   = (const float*)d_in[2];
  const float* ln1g  = (const float*)d_in[3];
  const float* ln1b  = (const float*)d_in[4];
  const float* ln2g  = (const float*)d_in[5];
  const float* ln2b  = (const float*)d_in[6];
  const float* Wqkv  = (const float*)d_in[7];
  const float* Wproj = (const float*)d_in[8];
  const float* Wfc1  = (const float*)d_in[9];
  const float* Wfc2  = (const float*)d_in[10];
  const float* mAW   = (const float*)d_in[11];
  const float* mAb   = (const float*)d_in[12];
  const float* mAal  = (const float*)d_in[13];
  const float* mFW   = (const float*)d_in[14];
  const float* mFb   = (const float*)d_in[15];
  const float* mFal  = (const float*)d_in[16];
  const float* lnfg  = (const float*)d_in[17];
  const float* lnfb  = (const float*)d_in[18];
  float* out = (float*)d_out;

  float* ws   = (float*)d_ws;
  float* xA   = ws + O_X;
  float* xB   = ws + O_X2;
  unsigned short* ybf   = (unsigned short*)(ws + O_TMP);   // y bf16
  unsigned short* bigBF = (unsigned short*)(ws + O_BIG);   // qkv / fc1-out bf16
  unsigned short* lnbf  = (unsigned short*)(ws + O_LNB);
  unsigned short* t1bf  = (unsigned short*)(ws + O_T1B);
  float* coef = ws + O_COEF;
  unsigned short* wT    = (unsigned short*)(ws + O_WT);
  unsigned short* wqkvT  = wT;
  unsigned short* wprojT = wT + (size_t)2304*768;
  unsigned short* wfc1T  = wprojT + (size_t)768*768;
  unsigned short* wfc2T  = wfc1T + (size_t)3072*768;
  unsigned short* tokbf  = (unsigned short*)(ws + O_X);    // overlays dead buffers at lm_head time
  unsigned short* lnfbf  = (unsigned short*)(ws + O_LNF);

  float* xc = xA; float* xn = xB;
  for (int l=0; l<NLAYER; l++){
    k_wtrans4<<<6912, 256, 0, stream>>>(Wqkv + (size_t)l*DIM*3*DIM, Wproj + (size_t)l*DIM*DIM,
                                        Wfc1 + (size_t)l*DIM*FFDIM, Wfc2 + (size_t)l*FFDIM*DIM,
                                        wqkvT, wprojT, wfc1T, wfc2T);
    // ---- attention sublayer ----
    if (l == 0){
      k_mhc<true><<<NTOK, 256, 0, stream>>>(ids, tok, pos, nullptr, nullptr, xA,
                                            mAW, mAb, mAal, ln1g, ln1b, coef, lnbf);
    } else {
      k_mhc<false><<<NTOK, 256, 0, stream>>>(nullptr, nullptr, nullptr, xc, ybf, xn,
                                             mAW + (size_t)l*NDIM*NC, mAb + (size_t)l*NC, mAal + l,
                                             ln1g + (size_t)l*DIM, ln1b + (size_t)l*DIM, coef, lnbf);
      { float* tmp = xc; xc = xn; xn = tmp; }
    }
    k_mgemm<0,true ,64,128,false><<<dim3(32, 2304/128), 256, 0, stream>>>(lnbf, wqkvT, (void*)bigBF, NTOK, 2304, 768);
    k_fattn<<<dim3(SEQ/64, NHEAD, BATCH), 256, 0, stream>>>(bigBF, t1bf);
    k_mgemm<0,true ,64,64,false><<<dim3(32, 768/64), 256, 0, stream>>>(t1bf, wprojT, (void*)ybf, NTOK, 768, 768);

    // ---- ffn sublayer ----
    k_mhc<false><<<NTOK, 256, 0, stream>>>(nullptr, nullptr, nullptr, xc, ybf, xn,
                                           mFW + (size_t)l*NDIM*NC, mFb + (size_t)l*NC, mFal + l,
                                           ln2g + (size_t)l*DIM, ln2b + (size_t)l*DIM, coef, lnbf);
    { float* tmp = xc; xc = xn; xn = tmp; }
    k_mgemm<1,true ,64,128,false><<<dim3(32, 3072/128), 256, 0, stream>>>(lnbf, wfc1T, (void*)bigBF, NTOK, 3072, 768);
    k_mgemm<0,true ,64,64,false><<<dim3(32, 768/64), 256, 0, stream>>>(bigBF, wfc2T, (void*)ybf, NTOK, 768, 3072);
  }

  // tail: combine-sum + final LN, then lm_head on bf16 tok_emb
  k_csumln<<<NTOK, 256, 0, stream>>>(xc, coef, ybf, lnfg, lnfb, lnfbf);
  k_cvt<<<2048, 256, 0, stream>>>(tok, tokbf, (VOCAB*DIM)/8);
  k_mgemm<0,false,128,128,true><<<dim3(16, (VOCAB+127)/128), 256, 0, stream>>>(lnfbf, tokbf, out, NTOK, VOCAB, 768);
}